// Round 12
// baseline (399.211 us; speedup 1.0000x reference)
//
#include <hip/hip_runtime.h>

// ---------------------------------------------------------------------------
// GAT_4733053960619: SAGEConv(mean) -> ELU -> GAT(2 heads,64) -> ELU -> GAT(1,47)
// N=50000, E=800000, IN_FEATS=256. All fp32.
//
// R11 = R10 + scatter fix: (a) cursor pre-filled with row_start (D2D copy) so
// atomicAdd returns the absolute slot (one fewer dependent random load);
// (b) csr_src written via atomicExch -> device-coherent atomic path, avoiding
// per-XCD partial-line RMW (R10: 55MB HBM writes for 3.2MB of data);
// (c) 2 edges per thread for atomic MLP.
// ---------------------------------------------------------------------------

typedef __attribute__((ext_vector_type(8))) short bf16x8;
typedef __attribute__((ext_vector_type(4))) float f32x4;

__device__ __forceinline__ float wave_sum(float v) {
#pragma unroll
  for (int o = 32; o > 0; o >>= 1) v += __shfl_xor(v, o, 64);
  return v;
}

__device__ __forceinline__ int wave_sum_i(int v) {
#pragma unroll
  for (int o = 32; o > 0; o >>= 1) v += __shfl_xor(v, o, 64);
  return v;
}

__device__ __forceinline__ float elu_f(float v) {
  return v > 0.f ? v : __expf(v) - 1.0f;
}

__device__ __forceinline__ unsigned short f2bf(float x) {
  union { float f; unsigned u; } v;
  v.f = x;
  unsigned r = v.u + 0x7FFFu + ((v.u >> 16) & 1u);
  return (unsigned short)(r >> 16);
}

__device__ __forceinline__ float bf2f(unsigned short h) {
  union { unsigned u; float f; } v;
  v.u = ((unsigned)h) << 16;
  return v.f;
}

// packed 2xbf16 (lo=head0, hi=head1) -> (f0, f1)
__device__ __forceinline__ float2 unpk(unsigned v) {
  union { unsigned u; float f; } a, b;
  a.u = v << 16;
  b.u = v & 0xFFFF0000u;
  return make_float2(a.f, b.f);
}

// ---------------- CSR build ----------------
__global__ __launch_bounds__(256) void deg_kernel(const int* __restrict__ dst,
                                                  int* __restrict__ deg, int E) {
  int i = blockIdx.x * 256 + threadIdx.x;
  if (i < E) atomicAdd(&deg[dst[i]], 1);
}

// phase 1: per-1024-chunk sums
__global__ __launch_bounds__(256) void scan_partial(const int* __restrict__ deg,
                                                    int* __restrict__ psum, int n) {
  __shared__ int red[4];
  const int t = threadIdx.x;
  const int base = blockIdx.x * 1024;
  int s = 0;
#pragma unroll
  for (int j = 0; j < 4; ++j) {
    int idx = base + t + j * 256;
    s += (idx < n) ? deg[idx] : 0;
  }
  s = wave_sum_i(s);
  const int lane = t & 63, w = t >> 6;
  if (lane == 0) red[w] = s;
  __syncthreads();
  if (t == 0) psum[blockIdx.x] = red[0] + red[1] + red[2] + red[3];
}

// phase 2: exclusive scan of partials (single wave, carry loop)
__global__ __launch_bounds__(64) void scan_psum(int* __restrict__ psum, int PB) {
  const int lane = threadIdx.x;
  int carry = 0;
  for (int base = 0; base < PB; base += 64) {
    int v = (base + lane < PB) ? psum[base + lane] : 0;
    int inc = v;
#pragma unroll
    for (int o = 1; o < 64; o <<= 1) {
      int u = __shfl_up(inc, o, 64);
      if (lane >= o) inc += u;
    }
    if (base + lane < PB) psum[base + lane] = carry + inc - v;
    carry += __shfl(inc, 63, 64);
  }
}

// phase 3: per-chunk exclusive scan + block offset -> row_start
__global__ __launch_bounds__(256) void scan_final(const int* __restrict__ deg,
                                                  const int* __restrict__ psum,
                                                  int* __restrict__ row_start,
                                                  int n, int E) {
  __shared__ int woff[4];
  const int t = threadIdx.x;
  const int lane = t & 63, w = t >> 6;
  const int base = blockIdx.x * 1024 + t * 4;
  int d0 = (base + 0 < n) ? deg[base + 0] : 0;
  int d1 = (base + 1 < n) ? deg[base + 1] : 0;
  int d2 = (base + 2 < n) ? deg[base + 2] : 0;
  int d3 = (base + 3 < n) ? deg[base + 3] : 0;
  int l0 = d0, l1 = l0 + d1, l2 = l1 + d2, l3 = l2 + d3;
  int inc = l3;
#pragma unroll
  for (int o = 1; o < 64; o <<= 1) {
    int u = __shfl_up(inc, o, 64);
    if (lane >= o) inc += u;
  }
  int texc = inc - l3;  // exclusive within wave
  if (lane == 63) woff[w] = inc;
  __syncthreads();
  int wo = 0;
  if (w == 0 && lane < 4) {
    int s = woff[lane];
    int p = s;
#pragma unroll
    for (int o = 1; o < 4; o <<= 1) {
      int u = __shfl_up(p, o, 64);
      if (lane >= o) p += u;
    }
    woff[lane] = p - s;  // exclusive wave offsets
  }
  __syncthreads();
  wo = woff[w];
  const int boff = psum[blockIdx.x] + wo + texc;
  if (base + 0 < n) row_start[base + 0] = boff;
  if (base + 1 < n) row_start[base + 1] = boff + l0;
  if (base + 2 < n) row_start[base + 2] = boff + l1;
  if (base + 3 < n) row_start[base + 3] = boff + l2;
  if (blockIdx.x == 0 && t == 0) row_start[n] = E;
}

// cursor pre-filled with row_start; atomicAdd -> absolute slot; atomicExch
// store routes through the device-coherent atomic path (no per-XCD line RMW).
__global__ __launch_bounds__(256) void scatter_kernel(const int* __restrict__ src,
                                                      const int* __restrict__ dst,
                                                      int* __restrict__ cursor,
                                                      int* __restrict__ csr_src, int E) {
  int i = blockIdx.x * 512 + threadIdx.x;
  int i2 = i + 256;
  int d0 = (i < E) ? dst[i] : 0;
  int d1 = (i2 < E) ? dst[i2] : 0;
  int s0 = (i < E) ? src[i] : 0;
  int s1 = (i2 < E) ? src[i2] : 0;
  int p0 = 0, p1 = 0;
  if (i < E) p0 = atomicAdd(&cursor[d0], 1);
  if (i2 < E) p1 = atomicAdd(&cursor[d1], 1);
  if (i < E) atomicExch(&csr_src[p0], s0);
  if (i2 < E) atomicExch(&csr_src[p1], s1);
}

// ---------------- fp32 -> bf16 hi/lo split (x input) ----------------
__global__ __launch_bounds__(256) void split_x(const float* __restrict__ x,
                                               unsigned short* __restrict__ xh,
                                               unsigned short* __restrict__ xl, int n4) {
  int i = blockIdx.x * 256 + threadIdx.x;
  int stride = gridDim.x * 256;
  for (; i < n4; i += stride) {
    float4 v = ((const float4*)x)[i];
    ushort4 h, l;
    h.x = f2bf(v.x); l.x = f2bf(v.x - bf2f(h.x));
    h.y = f2bf(v.y); l.y = f2bf(v.y - bf2f(h.y));
    h.z = f2bf(v.z); l.z = f2bf(v.z - bf2f(h.z));
    h.w = f2bf(v.w); l.w = f2bf(v.w - bf2f(h.w));
    ((ushort4*)xh)[i] = h;
    ((ushort4*)xl)[i] = l;
  }
}

// ---------------- weight prep: W[K][N] f32 -> W^T hi/lo [Npad][K] bf16 ------
__global__ __launch_bounds__(256) void prep_w(const float* __restrict__ W, int N, int K,
                                              int Npad, unsigned short* __restrict__ th,
                                              unsigned short* __restrict__ tl) {
  int i = blockIdx.x * 256 + threadIdx.x;
  if (i >= Npad * K) return;
  int n = i / K, k = i - n * K;
  float v = (n < N) ? W[(size_t)k * N + n] : 0.f;
  unsigned short h = f2bf(v);
  th[i] = h;
  tl[i] = f2bf(v - bf2f(h));
}

// ---------------- MFMA GEMM: C = A @ B, split-bf16, LDS-staged B ----------
// A as hi/lo bf16 [M][K]; B^T as hi/lo bf16 [Npad][K]; Npad = NT*16.
// Block = 4 waves = 128 rows; wave = 32 rows (2 fragments) x NT*16 cols.
// omode: 0 = f32 std (ldc floats); 1 = packed-bf16 head-interleave, uint
// stride ldu = ldc>>1; 2 = bf16 std (ldc ushorts).
template <int K, int NT>
__global__ __launch_bounds__(256) void gemm_mfma(
    const unsigned short* __restrict__ Ah, const unsigned short* __restrict__ Al,
    const unsigned short* __restrict__ BTh0, const unsigned short* __restrict__ BTl0,
    const unsigned short* __restrict__ BTh1, const unsigned short* __restrict__ BTl1,
    void* __restrict__ C0, void* __restrict__ C1,
    int ldc, int M, int Ncols, int omode0, int omode1) {
  constexpr int K2 = K * 2;    // bytes per B^T row
  constexpr int NKT = K / 32;  // k-tiles
  __shared__ unsigned short Bs[2][2][NT * 512];  // [buf][hi/lo][nt*512 + kg*128 + lrow*8]

  const unsigned short* BTh = blockIdx.y ? BTh1 : BTh0;
  const unsigned short* BTl = blockIdx.y ? BTl1 : BTl0;
  void* Cv = blockIdx.y ? C1 : C0;
  const int omode = blockIdx.y ? omode1 : omode0;

  const int wid = threadIdx.x >> 6;
  const int lane = threadIdx.x & 63;
  const int lrow = lane & 15;
  const int kg = lane >> 4;
  const int row0 = blockIdx.x * 128 + wid * 32;
  const int ra = min(row0 + lrow, M - 1);
  const int rb = min(row0 + 16 + lrow, M - 1);
  const size_t aoffA = (size_t)ra * K + kg * 8;
  const size_t aoffB = (size_t)rb * K + kg * 8;

  auto stage = [&](int buf, int kt) {
    for (int j = wid; j < 2 * NT; j += 4) {
      const int h = (j >= NT) ? 1 : 0;
      const int nt = h ? j - NT : j;
      const unsigned short* src = h ? BTl : BTh;
      const char* g = (const char*)src + (size_t)(nt * 16 + lrow) * K2 + kt * 64 + kg * 16;
      unsigned short* l = &Bs[buf][h][nt * 512];
      __builtin_amdgcn_global_load_lds(
          (const __attribute__((address_space(1))) unsigned*)g,
          (__attribute__((address_space(3))) unsigned*)l, 16, 0, 0);
    }
  };

  f32x4 accA[NT] = {};
  f32x4 accB[NT] = {};

  stage(0, 0);
  bf16x8 cahA = *(const bf16x8*)(Ah + aoffA);
  bf16x8 calA = *(const bf16x8*)(Al + aoffA);
  bf16x8 cahB = *(const bf16x8*)(Ah + aoffB);
  bf16x8 calB = *(const bf16x8*)(Al + aoffB);

  for (int kt = 0; kt < NKT; ++kt) {
    __syncthreads();  // buf[kt&1] staged
    if (kt + 1 < NKT) stage((kt + 1) & 1, kt + 1);
    const int kn = (kt + 1 < NKT) ? (kt + 1) * 32 : kt * 32;
    bf16x8 nahA = *(const bf16x8*)(Ah + aoffA + kn);
    bf16x8 nalA = *(const bf16x8*)(Al + aoffA + kn);
    bf16x8 nahB = *(const bf16x8*)(Ah + aoffB + kn);
    bf16x8 nalB = *(const bf16x8*)(Al + aoffB + kn);
    const int buf = kt & 1;
#pragma unroll
    for (int nt = 0; nt < NT; ++nt) {
      bf16x8 bh = ((const bf16x8*)&Bs[buf][0][nt * 512])[lane];
      bf16x8 bl = ((const bf16x8*)&Bs[buf][1][nt * 512])[lane];
      accA[nt] = __builtin_amdgcn_mfma_f32_16x16x32_bf16(cahA, bh, accA[nt], 0, 0, 0);
      accA[nt] = __builtin_amdgcn_mfma_f32_16x16x32_bf16(cahA, bl, accA[nt], 0, 0, 0);
      accA[nt] = __builtin_amdgcn_mfma_f32_16x16x32_bf16(calA, bh, accA[nt], 0, 0, 0);
      accB[nt] = __builtin_amdgcn_mfma_f32_16x16x32_bf16(cahB, bh, accB[nt], 0, 0, 0);
      accB[nt] = __builtin_amdgcn_mfma_f32_16x16x32_bf16(cahB, bl, accB[nt], 0, 0, 0);
      accB[nt] = __builtin_amdgcn_mfma_f32_16x16x32_bf16(calB, bh, accB[nt], 0, 0, 0);
    }
    cahA = nahA; calA = nalA; cahB = nahB; calB = nalB;
  }

  if (omode == 1) {
    // packed-bf16 head-interleave: uint stride = ldc/2
    unsigned* Cu = (unsigned*)Cv;
    const int ldu = ldc >> 1;
#pragma unroll
    for (int nt = 0; nt < NT / 2; ++nt) {
      int d = nt * 16 + lrow;
#pragma unroll
      for (int r = 0; r < 4; ++r) {
        int g0 = row0 + kg * 4 + r;
        if (g0 < M) {
          unsigned p = (unsigned)f2bf(accA[nt][r]) |
                       ((unsigned)f2bf(accA[nt + NT / 2][r]) << 16);
          Cu[(size_t)g0 * ldu + d] = p;
        }
        int g1 = row0 + 16 + kg * 4 + r;
        if (g1 < M) {
          unsigned p = (unsigned)f2bf(accB[nt][r]) |
                       ((unsigned)f2bf(accB[nt + NT / 2][r]) << 16);
          Cu[(size_t)g1 * ldu + d] = p;
        }
      }
    }
  } else if (omode == 2) {
    unsigned short* Cs = (unsigned short*)Cv;
#pragma unroll
    for (int nt = 0; nt < NT; ++nt) {
      int gc = nt * 16 + lrow;
      if (gc >= Ncols) continue;
#pragma unroll
      for (int r = 0; r < 4; ++r) {
        int g0 = row0 + kg * 4 + r;
        if (g0 < M) Cs[(size_t)g0 * ldc + gc] = f2bf(accA[nt][r]);
        int g1 = row0 + 16 + kg * 4 + r;
        if (g1 < M) Cs[(size_t)g1 * ldc + gc] = f2bf(accB[nt][r]);
      }
    }
  } else {
    float* C = (float*)Cv;
#pragma unroll
    for (int nt = 0; nt < NT; ++nt) {
      int gc = nt * 16 + lrow;
      if (gc >= Ncols) continue;
#pragma unroll
      for (int r = 0; r < 4; ++r) {
        int g0 = row0 + kg * 4 + r;
        if (g0 < M) C[(size_t)g0 * ldc + gc] = accA[nt][r];
        int g1 = row0 + 16 + kg * 4 + r;
        if (g1 < M) C[(size_t)g1 * ldc + gc] = accB[nt][r];
      }
    }
  }
}

// ---------------- SAGE aggregation (wave per node) -> h0 bf16 hi/lo --------
// yI: packed 2xbf16 per (node, d) uint. 8-wide unrolled gathers (MLP).
__global__ __launch_bounds__(256) void sage_agg(const float* __restrict__ z,
                                                const unsigned* __restrict__ yI,
                                                const int* __restrict__ row_start,
                                                const int* __restrict__ csr_src,
                                                const float* __restrict__ b,
                                                unsigned short* __restrict__ h0h,
                                                unsigned short* __restrict__ h0l, int N) {
  int wid = threadIdx.x >> 6;
  int lane = threadIdx.x & 63;
  int n = blockIdx.x * 4 + wid;
  if (n >= N) return;
  int s = row_start[n], e = row_start[n + 1];
  float a0 = 0.f, a1 = 0.f;
  int i = s;
  for (; i + 7 < e; i += 8) {
    unsigned v0 = yI[(size_t)csr_src[i] * 64 + lane];
    unsigned v1 = yI[(size_t)csr_src[i + 1] * 64 + lane];
    unsigned v2 = yI[(size_t)csr_src[i + 2] * 64 + lane];
    unsigned v3 = yI[(size_t)csr_src[i + 3] * 64 + lane];
    unsigned v4 = yI[(size_t)csr_src[i + 4] * 64 + lane];
    unsigned v5 = yI[(size_t)csr_src[i + 5] * 64 + lane];
    unsigned v6 = yI[(size_t)csr_src[i + 6] * 64 + lane];
    unsigned v7 = yI[(size_t)csr_src[i + 7] * 64 + lane];
    float2 f0 = unpk(v0), f1 = unpk(v1), f2 = unpk(v2), f3 = unpk(v3);
    float2 f4 = unpk(v4), f5 = unpk(v5), f6 = unpk(v6), f7 = unpk(v7);
    a0 += f0.x + f1.x + f2.x + f3.x + f4.x + f5.x + f6.x + f7.x;
    a1 += f0.y + f1.y + f2.y + f3.y + f4.y + f5.y + f6.y + f7.y;
  }
  for (; i < e; ++i) {
    float2 f = unpk(yI[(size_t)csr_src[i] * 64 + lane]);
    a0 += f.x;
    a1 += f.y;
  }
  float inv = 1.0f / fmaxf((float)(e - s), 1.0f);
  size_t base = (size_t)n * 128;
  float v0 = elu_f(z[base + lane] + a0 * inv + b[lane]);
  float v1 = elu_f(z[base + 64 + lane] + a1 * inv + b[64 + lane]);
  unsigned short hh0 = f2bf(v0), hh1 = f2bf(v1);
  h0h[base + lane] = hh0;
  h0l[base + lane] = f2bf(v0 - bf2f(hh0));
  h0h[base + 64 + lane] = hh1;
  h0l[base + 64 + lane] = f2bf(v1 - bf2f(hh1));
}

// ---------------- per-node attention logits (layer 1) ----------------------
__global__ __launch_bounds__(256) void elr1_kernel(const unsigned* __restrict__ featI,
                                                   const float* __restrict__ al,
                                                   const float* __restrict__ ar,
                                                   float2* __restrict__ el,
                                                   float2* __restrict__ er, int N) {
  int wid = threadIdx.x >> 6;
  int lane = threadIdx.x & 63;
  int n = blockIdx.x * 4 + wid;
  if (n >= N) return;
  float2 f = unpk(featI[(size_t)n * 64 + lane]);
  float e0 = wave_sum(f.x * al[lane]);
  float e1 = wave_sum(f.y * al[64 + lane]);
  float r0 = wave_sum(f.x * ar[lane]);
  float r1 = wave_sum(f.y * ar[64 + lane]);
  if (lane == 0) {
    el[n] = make_float2(e0, e1);
    er[n] = make_float2(r0, r1);
  }
}

// ---------------- attn1: thread per node, softmax weights ------------------
__global__ __launch_bounds__(256) void attn1_kernel(const float2* __restrict__ el,
                                                    const float2* __restrict__ er,
                                                    const int* __restrict__ row_start,
                                                    const int* __restrict__ csr_src,
                                                    float2* __restrict__ alpha,
                                                    float2* __restrict__ inv_s, int N) {
  int n = blockIdx.x * 256 + threadIdx.x;
  if (n >= N) return;
  int beg = row_start[n], end = row_start[n + 1];
  float2 r = er[n];
  float m0 = -INFINITY, m1 = -INFINITY;
  for (int i = beg; i < end; ++i) {
    float2 l = el[csr_src[i]];
    float e0 = l.x + r.x;
    e0 = e0 > 0.f ? e0 : 0.2f * e0;
    float e1 = l.y + r.y;
    e1 = e1 > 0.f ? e1 : 0.2f * e1;
    alpha[i] = make_float2(e0, e1);
    m0 = fmaxf(m0, e0);
    m1 = fmaxf(m1, e1);
  }
  float s0 = 0.f, s1 = 0.f;
  for (int i = beg; i < end; ++i) {
    float2 a = alpha[i];
    float p0 = __expf(a.x - m0);
    float p1 = __expf(a.y - m1);
    s0 += p0;
    s1 += p1;
    alpha[i] = make_float2(p0, p1);
  }
  inv_s[n] = make_float2(1.0f / fmaxf(s0, 1e-9f), 1.0f / fmaxf(s1, 1e-9f));
}

// ---------------- fused GAT layer 1 aggregation -> h1 bf16 hi/lo -----------
// 8-wide unrolled gathers (MLP).
__global__ __launch_bounds__(256) void gat1_agg(const unsigned* __restrict__ featI,
                                                const float2* __restrict__ alpha,
                                                const float2* __restrict__ inv_s,
                                                const int* __restrict__ row_start,
                                                const int* __restrict__ csr_src,
                                                const float* __restrict__ b,
                                                unsigned short* __restrict__ h1h,
                                                unsigned short* __restrict__ h1l, int N) {
  int wid = threadIdx.x >> 6;
  int lane = threadIdx.x & 63;
  int n = blockIdx.x * 4 + wid;
  if (n >= N) return;
  int beg = row_start[n], end = row_start[n + 1];
  float a0 = 0.f, a1 = 0.f;
  int i = beg;
  for (; i + 7 < end; i += 8) {
    unsigned v0 = featI[(size_t)csr_src[i] * 64 + lane];
    unsigned v1 = featI[(size_t)csr_src[i + 1] * 64 + lane];
    unsigned v2 = featI[(size_t)csr_src[i + 2] * 64 + lane];
    unsigned v3 = featI[(size_t)csr_src[i + 3] * 64 + lane];
    unsigned v4 = featI[(size_t)csr_src[i + 4] * 64 + lane];
    unsigned v5 = featI[(size_t)csr_src[i + 5] * 64 + lane];
    unsigned v6 = featI[(size_t)csr_src[i + 6] * 64 + lane];
    unsigned v7 = featI[(size_t)csr_src[i + 7] * 64 + lane];
    float2 p0 = alpha[i], p1 = alpha[i + 1], p2 = alpha[i + 2], p3 = alpha[i + 3];
    float2 p4 = alpha[i + 4], p5 = alpha[i + 5], p6 = alpha[i + 6], p7 = alpha[i + 7];
    float2 f0 = unpk(v0), f1 = unpk(v1), f2 = unpk(v2), f3 = unpk(v3);
    float2 f4 = unpk(v4), f5 = unpk(v5), f6 = unpk(v6), f7 = unpk(v7);
    a0 = fmaf(p0.x, f0.x, a0); a1 = fmaf(p0.y, f0.y, a1);
    a0 = fmaf(p1.x, f1.x, a0); a1 = fmaf(p1.y, f1.y, a1);
    a0 = fmaf(p2.x, f2.x, a0); a1 = fmaf(p2.y, f2.y, a1);
    a0 = fmaf(p3.x, f3.x, a0); a1 = fmaf(p3.y, f3.y, a1);
    a0 = fmaf(p4.x, f4.x, a0); a1 = fmaf(p4.y, f4.y, a1);
    a0 = fmaf(p5.x, f5.x, a0); a1 = fmaf(p5.y, f5.y, a1);
    a0 = fmaf(p6.x, f6.x, a0); a1 = fmaf(p6.y, f6.y, a1);
    a0 = fmaf(p7.x, f7.x, a0); a1 = fmaf(p7.y, f7.y, a1);
  }
  for (; i < end; ++i) {
    float2 p = alpha[i];
    float2 f = unpk(featI[(size_t)csr_src[i] * 64 + lane]);
    a0 = fmaf(p.x, f.x, a0);
    a1 = fmaf(p.y, f.y, a1);
  }
  float2 is = inv_s[n];
  float o0 = elu_f(a0 * is.x + b[lane]);
  float o1 = elu_f(a1 * is.y + b[64 + lane]);
  size_t base = (size_t)n * 128;
  unsigned short hh0 = f2bf(o0), hh1 = f2bf(o1);
  h1h[base + lane] = hh0;
  h1l[base + lane] = f2bf(o0 - bf2f(hh0));
  h1h[base + 64 + lane] = hh1;
  h1l[base + 64 + lane] = f2bf(o1 - bf2f(hh1));
}

// ---------------- per-node attention logits (layer 2) ----------------------
__global__ __launch_bounds__(256) void elr2_kernel(const unsigned short* __restrict__ feat,  // bf16 ld48
                                                   const float* __restrict__ al,
                                                   const float* __restrict__ ar,
                                                   float* __restrict__ el,
                                                   float* __restrict__ er, int N) {
  int wid = threadIdx.x >> 6;
  int lane = threadIdx.x & 63;
  int n = blockIdx.x * 4 + wid;
  if (n >= N) return;
  float f = 0.f, a = 0.f, r = 0.f;
  if (lane < 47) {
    f = bf2f(feat[(size_t)n * 48 + lane]);
    a = al[lane];
    r = ar[lane];
  }
  float e = wave_sum(f * a);
  float rr = wave_sum(f * r);
  if (lane == 0) {
    el[n] = e;
    er[n] = rr;
  }
}

// ---------------- attn2: thread per node ----------------------------------
__global__ __launch_bounds__(256) void attn2_kernel(const float* __restrict__ el,
                                                    const float* __restrict__ er,
                                                    const int* __restrict__ row_start,
                                                    const int* __restrict__ csr_src,
                                                    float* __restrict__ alpha,
                                                    float* __restrict__ inv_s, int N) {
  int n = blockIdx.x * 256 + threadIdx.x;
  if (n >= N) return;
  int beg = row_start[n], end = row_start[n + 1];
  float r = er[n];
  float m = -INFINITY;
  for (int i = beg; i < end; ++i) {
    float e = el[csr_src[i]] + r;
    e = e > 0.f ? e : 0.2f * e;
    alpha[i] = e;
    m = fmaxf(m, e);
  }
  float s = 0.f;
  for (int i = beg; i < end; ++i) {
    float p = __expf(alpha[i] - m);
    s += p;
    alpha[i] = p;
  }
  inv_s[n] = 1.0f / fmaxf(s, 1e-9f);
}

// ---------------- fused GAT layer 2 aggregation -> d_out ------------------
// 8-wide unrolled gathers (MLP).
__global__ __launch_bounds__(256) void gat2_agg(const unsigned short* __restrict__ feat,  // bf16 ld48
                                                const float* __restrict__ alpha,
                                                const float* __restrict__ inv_s,
                                                const int* __restrict__ row_start,
                                                const int* __restrict__ csr_src,
                                                const float* __restrict__ b,
                                                float* __restrict__ out, int N) {
  int wid = threadIdx.x >> 6;
  int lane = threadIdx.x & 63;
  int n = blockIdx.x * 4 + wid;
  if (n >= N) return;
  int beg = row_start[n], end = row_start[n + 1];
  int lidx = lane < 47 ? lane : 0;
  float acc = 0.f;
  int i = beg;
  for (; i + 7 < end; i += 8) {
    float g0 = bf2f(feat[(size_t)csr_src[i] * 48 + lidx]);
    float g1 = bf2f(feat[(size_t)csr_src[i + 1] * 48 + lidx]);
    float g2 = bf2f(feat[(size_t)csr_src[i + 2] * 48 + lidx]);
    float g3 = bf2f(feat[(size_t)csr_src[i + 3] * 48 + lidx]);
    float g4 = bf2f(feat[(size_t)csr_src[i + 4] * 48 + lidx]);
    float g5 = bf2f(feat[(size_t)csr_src[i + 5] * 48 + lidx]);
    float g6 = bf2f(feat[(size_t)csr_src[i + 6] * 48 + lidx]);
    float g7 = bf2f(feat[(size_t)csr_src[i + 7] * 48 + lidx]);
    float p0 = alpha[i], p1 = alpha[i + 1], p2 = alpha[i + 2], p3 = alpha[i + 3];
    float p4 = alpha[i + 4], p5 = alpha[i + 5], p6 = alpha[i + 6], p7 = alpha[i + 7];
    acc = fmaf(p0, g0, acc);
    acc = fmaf(p1, g1, acc);
    acc = fmaf(p2, g2, acc);
    acc = fmaf(p3, g3, acc);
    acc = fmaf(p4, g4, acc);
    acc = fmaf(p5, g5, acc);
    acc = fmaf(p6, g6, acc);
    acc = fmaf(p7, g7, acc);
  }
  for (; i < end; ++i) {
    acc = fmaf(alpha[i], bf2f(feat[(size_t)csr_src[i] * 48 + lidx]), acc);
  }
  if (lane < 47) {
    out[(size_t)n * 47 + lane] = acc * inv_s[n] + b[lane];
  }
}

// ---------------------------------------------------------------------------
extern "C" void kernel_launch(void* const* d_in, const int* in_sizes, int n_in,
                              void* d_out, int out_size, void* d_ws, size_t ws_size,
                              hipStream_t stream) {
  const float* x = (const float*)d_in[0];
  const int* src = (const int*)d_in[1];
  const int* dst = (const int*)d_in[2];
  const float* sage_w_self = (const float*)d_in[3];
  const float* sage_w_neigh = (const float*)d_in[4];
  const float* sage_b = (const float*)d_in[5];
  const float* gat1_w = (const float*)d_in[6];
  const float* gat1_al = (const float*)d_in[7];
  const float* gat1_ar = (const float*)d_in[8];
  const float* gat1_b = (const float*)d_in[9];
  const float* gat2_w = (const float*)d_in[10];
  const float* gat2_al = (const float*)d_in[11];
  const float* gat2_ar = (const float*)d_in[12];
  const float* gat2_b = (const float*)d_in[13];
  float* out = (float*)d_out;

  const int N = in_sizes[0] / 256;
  const int E = in_sizes[1];

  char* ws = (char*)d_ws;
  size_t off = 0;
  auto alloc = [&](size_t bytes) {
    size_t o = off;
    off += (bytes + 255) & ~(size_t)255;
    return o;
  };
  int* deg_i = (int*)(ws + alloc((size_t)N * 4));
  int* row_start = (int*)(ws + alloc((size_t)(N + 1) * 4));
  int* cursor = (int*)(ws + alloc((size_t)N * 4));
  int* csr_src = (int*)(ws + alloc((size_t)E * 4));
  int* psum = (int*)(ws + alloc(((size_t)N / 1024 + 2) * 4));
  float* bufA = (float*)(ws + alloc((size_t)N * 128 * 4));       // z; later alpha1/alpha2
  unsigned* bufG = (unsigned*)(ws + alloc((size_t)N * 64 * 4));  // yI -> feat1I -> feat2b
  unsigned short* bufX = (unsigned short*)(ws + alloc((size_t)N * 256 * 2 * 2));  // xh|xl
  unsigned short* wt_sh = (unsigned short*)(ws + alloc(128 * 256 * 2));
  unsigned short* wt_sl = (unsigned short*)(ws + alloc(128 * 256 * 2));
  unsigned short* wt_nh = (unsigned short*)(ws + alloc(128 * 256 * 2));
  unsigned short* wt_nl = (unsigned short*)(ws + alloc(128 * 256 * 2));
  unsigned short* wt_1h = (unsigned short*)(ws + alloc(128 * 128 * 2));
  unsigned short* wt_1l = (unsigned short*)(ws + alloc(128 * 128 * 2));
  unsigned short* wt_2h = (unsigned short*)(ws + alloc(48 * 128 * 2));
  unsigned short* wt_2l = (unsigned short*)(ws + alloc(48 * 128 * 2));
  float2* el1 = (float2*)(ws + alloc((size_t)N * 8));
  float2* er1 = (float2*)(ws + alloc((size_t)N * 8));
  float* el2 = (float*)(ws + alloc((size_t)N * 4));
  float* er2 = (float*)(ws + alloc((size_t)N * 4));
  float2* inv_s1 = (float2*)(ws + alloc((size_t)N * 8));
  float* inv_s2 = (float*)(ws + alloc((size_t)N * 4));
  (void)ws_size;
  (void)n_in;
  (void)out_size;

  // lifetimes:
  unsigned short* xh = (unsigned short*)bufX;       // dead after L0 gemm
  unsigned short* xl = bufX + (size_t)N * 256;      // dead after L0 gemm
  float* z = bufA;                                  // dead after sage_agg
  unsigned* yI = bufG;                              // dead after sage_agg
  unsigned short* h0h = bufX;                       // reuse xh region
  unsigned short* h0l = bufX + (size_t)N * 128;
  unsigned* feat1I = bufG;                          // reuse yI; dead after gat1_agg
  float2* alpha1 = (float2*)bufA;                   // reuse z; dead after gat1_agg
  unsigned short* h1h = bufX + (size_t)N * 256;     // reuse xl region
  unsigned short* h1l = bufX + (size_t)N * 256 + (size_t)N * 128;
  unsigned short* feat2b = (unsigned short*)bufG;   // reuse feat1I
  float* alpha2 = bufA;                             // reuse alpha1

  hipMemsetAsync(deg_i, 0, (size_t)N * 4, stream);

  const int eb = (E + 255) / 256;
  const int eb2 = (E + 511) / 512;
  const int nb4 = (N + 3) / 4;
  const int nb256 = (N + 255) / 256;
  const int gx = (N + 127) / 128;
  const int PB = (N + 1023) / 1024;

  split_x<<<2048, 256, 0, stream>>>(x, xh, xl, N * 64);
  prep_w<<<(128 * 256 + 255) / 256, 256, 0, stream>>>(sage_w_self, 128, 256, 128, wt_sh, wt_sl);
  prep_w<<<(128 * 256 + 255) / 256, 256, 0, stream>>>(sage_w_neigh, 128, 256, 128, wt_nh, wt_nl);
  prep_w<<<(128 * 128 + 255) / 256, 256, 0, stream>>>(gat1_w, 128, 128, 128, wt_1h, wt_1l);
  prep_w<<<(48 * 128 + 255) / 256, 256, 0, stream>>>(gat2_w, 47, 128, 48, wt_2h, wt_2l);

  deg_kernel<<<eb, 256, 0, stream>>>(dst, deg_i, E);
  scan_partial<<<PB, 256, 0, stream>>>(deg_i, psum, N);
  scan_psum<<<1, 64, 0, stream>>>(psum, PB);
  scan_final<<<PB, 256, 0, stream>>>(deg_i, psum, row_start, N, E);
  hipMemcpyAsync(cursor, row_start, (size_t)N * 4, hipMemcpyDeviceToDevice, stream);
  scatter_kernel<<<eb2, 256, 0, stream>>>(src, dst, cursor, csr_src, E);

  // layer 0: y=0 -> z = x@W_self (f32, ldc=128 floats),
  //          y=1 -> yI = x@W_neigh (packed bf16 ilv, ldu=64 uints)
  {
    dim3 grid(gx, 2);
    gemm_mfma<256, 8><<<grid, 256, 0, stream>>>(xh, xl, wt_sh, wt_sl, wt_nh, wt_nl,
                                                z, yI, 128, N, 128, 0, 1);
  }
  sage_agg<<<nb4, 256, 0, stream>>>(z, yI, row_start, csr_src, sage_b, h0h, h0l, N);

  // GAT layer 1: feat1I = h0 @ gat1_w (packed bf16 ilv, ldc=128 -> ldu=64 uints)
  {
    dim3 grid(gx, 1);
    gemm_mfma<128, 8><<<grid, 256, 0, stream>>>(h0h, h0l, wt_1h, wt_1l, wt_1h, wt_1l,
                                                feat1I, feat1I, 128, N, 128, 1, 1);
  }
  elr1_kernel<<<nb4, 256, 0, stream>>>(feat1I, gat1_al, gat1_ar, el1, er1, N);
  attn1_kernel<<<nb256, 256, 0, stream>>>(el1, er1, row_start, csr_src, alpha1, inv_s1, N);
  gat1_agg<<<nb4, 256, 0, stream>>>(feat1I, alpha1, inv_s1, row_start, csr_src, gat1_b,
                                    h1h, h1l, N);

  // GAT layer 2: feat2b = h1 @ gat2_w (bf16 std, ldc=48 ushorts)
  {
    dim3 grid(gx, 1);
    gemm_mfma<128, 3><<<grid, 256, 0, stream>>>(h1h, h1l, wt_2h, wt_2l, wt_2h, wt_2l,
                                                feat2b, feat2b, 48, N, 47, 2, 2);
  }
  elr2_kernel<<<nb4, 256, 0, stream>>>(feat2b, gat2_al, gat2_ar, el2, er2, N);
  attn2_kernel<<<nb256, 256, 0, stream>>>(el2, er2, row_start, csr_src, alpha2, inv_s2, N);
  gat2_agg<<<nb4, 256, 0, stream>>>(feat2b, alpha2, inv_s2, row_start, csr_src, gat2_b, out, N);
}

// Round 13
// 365.459 us; speedup vs baseline: 1.0924x; 1.0924x over previous
//
#include <hip/hip_runtime.h>

// ---------------------------------------------------------------------------
// GAT_4733053960619: SAGEConv(mean) -> ELU -> GAT(2 heads,64) -> ELU -> GAT(1,47)
// N=50000, E=800000, IN_FEATS=256. All fp32.
//
// R12: scatter revert+shrink. R11's atomicExch REGRESSED (83us; device-scope
// atomics serialize, WRITE_SIZE unchanged ~50MB). Now: plain stores again,
// csr_src stored as USHORT (N<65536) -> dirtied lines halve -> write traffic
// ~halves; cursor prefilled with row_start (absolute slot from atomicAdd);
// 2 edges/thread. All csr_src consumers read ushort (halved index bytes).
// ---------------------------------------------------------------------------

typedef __attribute__((ext_vector_type(8))) short bf16x8;
typedef __attribute__((ext_vector_type(4))) float f32x4;

__device__ __forceinline__ float wave_sum(float v) {
#pragma unroll
  for (int o = 32; o > 0; o >>= 1) v += __shfl_xor(v, o, 64);
  return v;
}

__device__ __forceinline__ int wave_sum_i(int v) {
#pragma unroll
  for (int o = 32; o > 0; o >>= 1) v += __shfl_xor(v, o, 64);
  return v;
}

__device__ __forceinline__ float elu_f(float v) {
  return v > 0.f ? v : __expf(v) - 1.0f;
}

__device__ __forceinline__ unsigned short f2bf(float x) {
  union { float f; unsigned u; } v;
  v.f = x;
  unsigned r = v.u + 0x7FFFu + ((v.u >> 16) & 1u);
  return (unsigned short)(r >> 16);
}

__device__ __forceinline__ float bf2f(unsigned short h) {
  union { unsigned u; float f; } v;
  v.u = ((unsigned)h) << 16;
  return v.f;
}

// packed 2xbf16 (lo=head0, hi=head1) -> (f0, f1)
__device__ __forceinline__ float2 unpk(unsigned v) {
  union { unsigned u; float f; } a, b;
  a.u = v << 16;
  b.u = v & 0xFFFF0000u;
  return make_float2(a.f, b.f);
}

// ---------------- CSR build ----------------
__global__ __launch_bounds__(256) void deg_kernel(const int* __restrict__ dst,
                                                  int* __restrict__ deg, int E) {
  int i = blockIdx.x * 256 + threadIdx.x;
  if (i < E) atomicAdd(&deg[dst[i]], 1);
}

// phase 1: per-1024-chunk sums
__global__ __launch_bounds__(256) void scan_partial(const int* __restrict__ deg,
                                                    int* __restrict__ psum, int n) {
  __shared__ int red[4];
  const int t = threadIdx.x;
  const int base = blockIdx.x * 1024;
  int s = 0;
#pragma unroll
  for (int j = 0; j < 4; ++j) {
    int idx = base + t + j * 256;
    s += (idx < n) ? deg[idx] : 0;
  }
  s = wave_sum_i(s);
  const int lane = t & 63, w = t >> 6;
  if (lane == 0) red[w] = s;
  __syncthreads();
  if (t == 0) psum[blockIdx.x] = red[0] + red[1] + red[2] + red[3];
}

// phase 2: exclusive scan of partials (single wave, carry loop)
__global__ __launch_bounds__(64) void scan_psum(int* __restrict__ psum, int PB) {
  const int lane = threadIdx.x;
  int carry = 0;
  for (int base = 0; base < PB; base += 64) {
    int v = (base + lane < PB) ? psum[base + lane] : 0;
    int inc = v;
#pragma unroll
    for (int o = 1; o < 64; o <<= 1) {
      int u = __shfl_up(inc, o, 64);
      if (lane >= o) inc += u;
    }
    if (base + lane < PB) psum[base + lane] = carry + inc - v;
    carry += __shfl(inc, 63, 64);
  }
}

// phase 3: per-chunk exclusive scan + block offset -> row_start
__global__ __launch_bounds__(256) void scan_final(const int* __restrict__ deg,
                                                  const int* __restrict__ psum,
                                                  int* __restrict__ row_start,
                                                  int n, int E) {
  __shared__ int woff[4];
  const int t = threadIdx.x;
  const int lane = t & 63, w = t >> 6;
  const int base = blockIdx.x * 1024 + t * 4;
  int d0 = (base + 0 < n) ? deg[base + 0] : 0;
  int d1 = (base + 1 < n) ? deg[base + 1] : 0;
  int d2 = (base + 2 < n) ? deg[base + 2] : 0;
  int d3 = (base + 3 < n) ? deg[base + 3] : 0;
  int l0 = d0, l1 = l0 + d1, l2 = l1 + d2, l3 = l2 + d3;
  int inc = l3;
#pragma unroll
  for (int o = 1; o < 64; o <<= 1) {
    int u = __shfl_up(inc, o, 64);
    if (lane >= o) inc += u;
  }
  int texc = inc - l3;  // exclusive within wave
  if (lane == 63) woff[w] = inc;
  __syncthreads();
  int wo = 0;
  if (w == 0 && lane < 4) {
    int s = woff[lane];
    int p = s;
#pragma unroll
    for (int o = 1; o < 4; o <<= 1) {
      int u = __shfl_up(p, o, 64);
      if (lane >= o) p += u;
    }
    woff[lane] = p - s;  // exclusive wave offsets
  }
  __syncthreads();
  wo = woff[w];
  const int boff = psum[blockIdx.x] + wo + texc;
  if (base + 0 < n) row_start[base + 0] = boff;
  if (base + 1 < n) row_start[base + 1] = boff + l0;
  if (base + 2 < n) row_start[base + 2] = boff + l1;
  if (base + 3 < n) row_start[base + 3] = boff + l2;
  if (blockIdx.x == 0 && t == 0) row_start[n] = E;
}

// cursor pre-filled with row_start; atomicAdd -> absolute slot; plain ushort
// store (src ids fit 16 bits since N < 65536).
__global__ __launch_bounds__(256) void scatter_kernel(const int* __restrict__ src,
                                                      const int* __restrict__ dst,
                                                      int* __restrict__ cursor,
                                                      unsigned short* __restrict__ csr_src,
                                                      int E) {
  int i = blockIdx.x * 512 + threadIdx.x;
  int i2 = i + 256;
  int d0 = (i < E) ? dst[i] : 0;
  int d1 = (i2 < E) ? dst[i2] : 0;
  int s0 = (i < E) ? src[i] : 0;
  int s1 = (i2 < E) ? src[i2] : 0;
  int p0 = 0, p1 = 0;
  if (i < E) p0 = atomicAdd(&cursor[d0], 1);
  if (i2 < E) p1 = atomicAdd(&cursor[d1], 1);
  if (i < E) csr_src[p0] = (unsigned short)s0;
  if (i2 < E) csr_src[p1] = (unsigned short)s1;
}

// ---------------- fp32 -> bf16 hi/lo split (x input) ----------------
__global__ __launch_bounds__(256) void split_x(const float* __restrict__ x,
                                               unsigned short* __restrict__ xh,
                                               unsigned short* __restrict__ xl, int n4) {
  int i = blockIdx.x * 256 + threadIdx.x;
  int stride = gridDim.x * 256;
  for (; i < n4; i += stride) {
    float4 v = ((const float4*)x)[i];
    ushort4 h, l;
    h.x = f2bf(v.x); l.x = f2bf(v.x - bf2f(h.x));
    h.y = f2bf(v.y); l.y = f2bf(v.y - bf2f(h.y));
    h.z = f2bf(v.z); l.z = f2bf(v.z - bf2f(h.z));
    h.w = f2bf(v.w); l.w = f2bf(v.w - bf2f(h.w));
    ((ushort4*)xh)[i] = h;
    ((ushort4*)xl)[i] = l;
  }
}

// ---------------- weight prep: W[K][N] f32 -> W^T hi/lo [Npad][K] bf16 ------
__global__ __launch_bounds__(256) void prep_w(const float* __restrict__ W, int N, int K,
                                              int Npad, unsigned short* __restrict__ th,
                                              unsigned short* __restrict__ tl) {
  int i = blockIdx.x * 256 + threadIdx.x;
  if (i >= Npad * K) return;
  int n = i / K, k = i - n * K;
  float v = (n < N) ? W[(size_t)k * N + n] : 0.f;
  unsigned short h = f2bf(v);
  th[i] = h;
  tl[i] = f2bf(v - bf2f(h));
}

// ---------------- MFMA GEMM: C = A @ B, split-bf16, LDS-staged B ----------
// A as hi/lo bf16 [M][K]; B^T as hi/lo bf16 [Npad][K]; Npad = NT*16.
// Block = 4 waves = 128 rows; wave = 32 rows (2 fragments) x NT*16 cols.
// omode: 0 = f32 std (ldc floats); 1 = packed-bf16 head-interleave, uint
// stride ldu = ldc>>1; 2 = bf16 std (ldc ushorts).
template <int K, int NT>
__global__ __launch_bounds__(256) void gemm_mfma(
    const unsigned short* __restrict__ Ah, const unsigned short* __restrict__ Al,
    const unsigned short* __restrict__ BTh0, const unsigned short* __restrict__ BTl0,
    const unsigned short* __restrict__ BTh1, const unsigned short* __restrict__ BTl1,
    void* __restrict__ C0, void* __restrict__ C1,
    int ldc, int M, int Ncols, int omode0, int omode1) {
  constexpr int K2 = K * 2;    // bytes per B^T row
  constexpr int NKT = K / 32;  // k-tiles
  __shared__ unsigned short Bs[2][2][NT * 512];  // [buf][hi/lo][nt*512 + kg*128 + lrow*8]

  const unsigned short* BTh = blockIdx.y ? BTh1 : BTh0;
  const unsigned short* BTl = blockIdx.y ? BTl1 : BTl0;
  void* Cv = blockIdx.y ? C1 : C0;
  const int omode = blockIdx.y ? omode1 : omode0;

  const int wid = threadIdx.x >> 6;
  const int lane = threadIdx.x & 63;
  const int lrow = lane & 15;
  const int kg = lane >> 4;
  const int row0 = blockIdx.x * 128 + wid * 32;
  const int ra = min(row0 + lrow, M - 1);
  const int rb = min(row0 + 16 + lrow, M - 1);
  const size_t aoffA = (size_t)ra * K + kg * 8;
  const size_t aoffB = (size_t)rb * K + kg * 8;

  auto stage = [&](int buf, int kt) {
    for (int j = wid; j < 2 * NT; j += 4) {
      const int h = (j >= NT) ? 1 : 0;
      const int nt = h ? j - NT : j;
      const unsigned short* src = h ? BTl : BTh;
      const char* g = (const char*)src + (size_t)(nt * 16 + lrow) * K2 + kt * 64 + kg * 16;
      unsigned short* l = &Bs[buf][h][nt * 512];
      __builtin_amdgcn_global_load_lds(
          (const __attribute__((address_space(1))) unsigned*)g,
          (__attribute__((address_space(3))) unsigned*)l, 16, 0, 0);
    }
  };

  f32x4 accA[NT] = {};
  f32x4 accB[NT] = {};

  stage(0, 0);
  bf16x8 cahA = *(const bf16x8*)(Ah + aoffA);
  bf16x8 calA = *(const bf16x8*)(Al + aoffA);
  bf16x8 cahB = *(const bf16x8*)(Ah + aoffB);
  bf16x8 calB = *(const bf16x8*)(Al + aoffB);

  for (int kt = 0; kt < NKT; ++kt) {
    __syncthreads();  // buf[kt&1] staged
    if (kt + 1 < NKT) stage((kt + 1) & 1, kt + 1);
    const int kn = (kt + 1 < NKT) ? (kt + 1) * 32 : kt * 32;
    bf16x8 nahA = *(const bf16x8*)(Ah + aoffA + kn);
    bf16x8 nalA = *(const bf16x8*)(Al + aoffA + kn);
    bf16x8 nahB = *(const bf16x8*)(Ah + aoffB + kn);
    bf16x8 nalB = *(const bf16x8*)(Al + aoffB + kn);
    const int buf = kt & 1;
#pragma unroll
    for (int nt = 0; nt < NT; ++nt) {
      bf16x8 bh = ((const bf16x8*)&Bs[buf][0][nt * 512])[lane];
      bf16x8 bl = ((const bf16x8*)&Bs[buf][1][nt * 512])[lane];
      accA[nt] = __builtin_amdgcn_mfma_f32_16x16x32_bf16(cahA, bh, accA[nt], 0, 0, 0);
      accA[nt] = __builtin_amdgcn_mfma_f32_16x16x32_bf16(cahA, bl, accA[nt], 0, 0, 0);
      accA[nt] = __builtin_amdgcn_mfma_f32_16x16x32_bf16(calA, bh, accA[nt], 0, 0, 0);
      accB[nt] = __builtin_amdgcn_mfma_f32_16x16x32_bf16(cahB, bh, accB[nt], 0, 0, 0);
      accB[nt] = __builtin_amdgcn_mfma_f32_16x16x32_bf16(cahB, bl, accB[nt], 0, 0, 0);
      accB[nt] = __builtin_amdgcn_mfma_f32_16x16x32_bf16(calB, bh, accB[nt], 0, 0, 0);
    }
    cahA = nahA; calA = nalA; cahB = nahB; calB = nalB;
  }

  if (omode == 1) {
    // packed-bf16 head-interleave: uint stride = ldc/2
    unsigned* Cu = (unsigned*)Cv;
    const int ldu = ldc >> 1;
#pragma unroll
    for (int nt = 0; nt < NT / 2; ++nt) {
      int d = nt * 16 + lrow;
#pragma unroll
      for (int r = 0; r < 4; ++r) {
        int g0 = row0 + kg * 4 + r;
        if (g0 < M) {
          unsigned p = (unsigned)f2bf(accA[nt][r]) |
                       ((unsigned)f2bf(accA[nt + NT / 2][r]) << 16);
          Cu[(size_t)g0 * ldu + d] = p;
        }
        int g1 = row0 + 16 + kg * 4 + r;
        if (g1 < M) {
          unsigned p = (unsigned)f2bf(accB[nt][r]) |
                       ((unsigned)f2bf(accB[nt + NT / 2][r]) << 16);
          Cu[(size_t)g1 * ldu + d] = p;
        }
      }
    }
  } else if (omode == 2) {
    unsigned short* Cs = (unsigned short*)Cv;
#pragma unroll
    for (int nt = 0; nt < NT; ++nt) {
      int gc = nt * 16 + lrow;
      if (gc >= Ncols) continue;
#pragma unroll
      for (int r = 0; r < 4; ++r) {
        int g0 = row0 + kg * 4 + r;
        if (g0 < M) Cs[(size_t)g0 * ldc + gc] = f2bf(accA[nt][r]);
        int g1 = row0 + 16 + kg * 4 + r;
        if (g1 < M) Cs[(size_t)g1 * ldc + gc] = f2bf(accB[nt][r]);
      }
    }
  } else {
    float* C = (float*)Cv;
#pragma unroll
    for (int nt = 0; nt < NT; ++nt) {
      int gc = nt * 16 + lrow;
      if (gc >= Ncols) continue;
#pragma unroll
      for (int r = 0; r < 4; ++r) {
        int g0 = row0 + kg * 4 + r;
        if (g0 < M) C[(size_t)g0 * ldc + gc] = accA[nt][r];
        int g1 = row0 + 16 + kg * 4 + r;
        if (g1 < M) C[(size_t)g1 * ldc + gc] = accB[nt][r];
      }
    }
  }
}

// ---------------- SAGE aggregation (wave per node) -> h0 bf16 hi/lo --------
// yI: packed 2xbf16 per (node, d) uint. 8-wide unrolled gathers (MLP).
__global__ __launch_bounds__(256) void sage_agg(const float* __restrict__ z,
                                                const unsigned* __restrict__ yI,
                                                const int* __restrict__ row_start,
                                                const unsigned short* __restrict__ csr_src,
                                                const float* __restrict__ b,
                                                unsigned short* __restrict__ h0h,
                                                unsigned short* __restrict__ h0l, int N) {
  int wid = threadIdx.x >> 6;
  int lane = threadIdx.x & 63;
  int n = blockIdx.x * 4 + wid;
  if (n >= N) return;
  int s = row_start[n], e = row_start[n + 1];
  float a0 = 0.f, a1 = 0.f;
  int i = s;
  for (; i + 7 < e; i += 8) {
    unsigned v0 = yI[(size_t)csr_src[i] * 64 + lane];
    unsigned v1 = yI[(size_t)csr_src[i + 1] * 64 + lane];
    unsigned v2 = yI[(size_t)csr_src[i + 2] * 64 + lane];
    unsigned v3 = yI[(size_t)csr_src[i + 3] * 64 + lane];
    unsigned v4 = yI[(size_t)csr_src[i + 4] * 64 + lane];
    unsigned v5 = yI[(size_t)csr_src[i + 5] * 64 + lane];
    unsigned v6 = yI[(size_t)csr_src[i + 6] * 64 + lane];
    unsigned v7 = yI[(size_t)csr_src[i + 7] * 64 + lane];
    float2 f0 = unpk(v0), f1 = unpk(v1), f2 = unpk(v2), f3 = unpk(v3);
    float2 f4 = unpk(v4), f5 = unpk(v5), f6 = unpk(v6), f7 = unpk(v7);
    a0 += f0.x + f1.x + f2.x + f3.x + f4.x + f5.x + f6.x + f7.x;
    a1 += f0.y + f1.y + f2.y + f3.y + f4.y + f5.y + f6.y + f7.y;
  }
  for (; i < e; ++i) {
    float2 f = unpk(yI[(size_t)csr_src[i] * 64 + lane]);
    a0 += f.x;
    a1 += f.y;
  }
  float inv = 1.0f / fmaxf((float)(e - s), 1.0f);
  size_t base = (size_t)n * 128;
  float v0 = elu_f(z[base + lane] + a0 * inv + b[lane]);
  float v1 = elu_f(z[base + 64 + lane] + a1 * inv + b[64 + lane]);
  unsigned short hh0 = f2bf(v0), hh1 = f2bf(v1);
  h0h[base + lane] = hh0;
  h0l[base + lane] = f2bf(v0 - bf2f(hh0));
  h0h[base + 64 + lane] = hh1;
  h0l[base + 64 + lane] = f2bf(v1 - bf2f(hh1));
}

// ---------------- per-node attention logits (layer 1) ----------------------
__global__ __launch_bounds__(256) void elr1_kernel(const unsigned* __restrict__ featI,
                                                   const float* __restrict__ al,
                                                   const float* __restrict__ ar,
                                                   float2* __restrict__ el,
                                                   float2* __restrict__ er, int N) {
  int wid = threadIdx.x >> 6;
  int lane = threadIdx.x & 63;
  int n = blockIdx.x * 4 + wid;
  if (n >= N) return;
  float2 f = unpk(featI[(size_t)n * 64 + lane]);
  float e0 = wave_sum(f.x * al[lane]);
  float e1 = wave_sum(f.y * al[64 + lane]);
  float r0 = wave_sum(f.x * ar[lane]);
  float r1 = wave_sum(f.y * ar[64 + lane]);
  if (lane == 0) {
    el[n] = make_float2(e0, e1);
    er[n] = make_float2(r0, r1);
  }
}

// ---------------- attn1: thread per node, softmax weights ------------------
__global__ __launch_bounds__(256) void attn1_kernel(const float2* __restrict__ el,
                                                    const float2* __restrict__ er,
                                                    const int* __restrict__ row_start,
                                                    const unsigned short* __restrict__ csr_src,
                                                    float2* __restrict__ alpha,
                                                    float2* __restrict__ inv_s, int N) {
  int n = blockIdx.x * 256 + threadIdx.x;
  if (n >= N) return;
  int beg = row_start[n], end = row_start[n + 1];
  float2 r = er[n];
  float m0 = -INFINITY, m1 = -INFINITY;
  for (int i = beg; i < end; ++i) {
    float2 l = el[csr_src[i]];
    float e0 = l.x + r.x;
    e0 = e0 > 0.f ? e0 : 0.2f * e0;
    float e1 = l.y + r.y;
    e1 = e1 > 0.f ? e1 : 0.2f * e1;
    alpha[i] = make_float2(e0, e1);
    m0 = fmaxf(m0, e0);
    m1 = fmaxf(m1, e1);
  }
  float s0 = 0.f, s1 = 0.f;
  for (int i = beg; i < end; ++i) {
    float2 a = alpha[i];
    float p0 = __expf(a.x - m0);
    float p1 = __expf(a.y - m1);
    s0 += p0;
    s1 += p1;
    alpha[i] = make_float2(p0, p1);
  }
  inv_s[n] = make_float2(1.0f / fmaxf(s0, 1e-9f), 1.0f / fmaxf(s1, 1e-9f));
}

// ---------------- fused GAT layer 1 aggregation -> h1 bf16 hi/lo -----------
// 8-wide unrolled gathers (MLP).
__global__ __launch_bounds__(256) void gat1_agg(const unsigned* __restrict__ featI,
                                                const float2* __restrict__ alpha,
                                                const float2* __restrict__ inv_s,
                                                const int* __restrict__ row_start,
                                                const unsigned short* __restrict__ csr_src,
                                                const float* __restrict__ b,
                                                unsigned short* __restrict__ h1h,
                                                unsigned short* __restrict__ h1l, int N) {
  int wid = threadIdx.x >> 6;
  int lane = threadIdx.x & 63;
  int n = blockIdx.x * 4 + wid;
  if (n >= N) return;
  int beg = row_start[n], end = row_start[n + 1];
  float a0 = 0.f, a1 = 0.f;
  int i = beg;
  for (; i + 7 < end; i += 8) {
    unsigned v0 = featI[(size_t)csr_src[i] * 64 + lane];
    unsigned v1 = featI[(size_t)csr_src[i + 1] * 64 + lane];
    unsigned v2 = featI[(size_t)csr_src[i + 2] * 64 + lane];
    unsigned v3 = featI[(size_t)csr_src[i + 3] * 64 + lane];
    unsigned v4 = featI[(size_t)csr_src[i + 4] * 64 + lane];
    unsigned v5 = featI[(size_t)csr_src[i + 5] * 64 + lane];
    unsigned v6 = featI[(size_t)csr_src[i + 6] * 64 + lane];
    unsigned v7 = featI[(size_t)csr_src[i + 7] * 64 + lane];
    float2 p0 = alpha[i], p1 = alpha[i + 1], p2 = alpha[i + 2], p3 = alpha[i + 3];
    float2 p4 = alpha[i + 4], p5 = alpha[i + 5], p6 = alpha[i + 6], p7 = alpha[i + 7];
    float2 f0 = unpk(v0), f1 = unpk(v1), f2 = unpk(v2), f3 = unpk(v3);
    float2 f4 = unpk(v4), f5 = unpk(v5), f6 = unpk(v6), f7 = unpk(v7);
    a0 = fmaf(p0.x, f0.x, a0); a1 = fmaf(p0.y, f0.y, a1);
    a0 = fmaf(p1.x, f1.x, a0); a1 = fmaf(p1.y, f1.y, a1);
    a0 = fmaf(p2.x, f2.x, a0); a1 = fmaf(p2.y, f2.y, a1);
    a0 = fmaf(p3.x, f3.x, a0); a1 = fmaf(p3.y, f3.y, a1);
    a0 = fmaf(p4.x, f4.x, a0); a1 = fmaf(p4.y, f4.y, a1);
    a0 = fmaf(p5.x, f5.x, a0); a1 = fmaf(p5.y, f5.y, a1);
    a0 = fmaf(p6.x, f6.x, a0); a1 = fmaf(p6.y, f6.y, a1);
    a0 = fmaf(p7.x, f7.x, a0); a1 = fmaf(p7.y, f7.y, a1);
  }
  for (; i < end; ++i) {
    float2 p = alpha[i];
    float2 f = unpk(featI[(size_t)csr_src[i] * 64 + lane]);
    a0 = fmaf(p.x, f.x, a0);
    a1 = fmaf(p.y, f.y, a1);
  }
  float2 is = inv_s[n];
  float o0 = elu_f(a0 * is.x + b[lane]);
  float o1 = elu_f(a1 * is.y + b[64 + lane]);
  size_t base = (size_t)n * 128;
  unsigned short hh0 = f2bf(o0), hh1 = f2bf(o1);
  h1h[base + lane] = hh0;
  h1l[base + lane] = f2bf(o0 - bf2f(hh0));
  h1h[base + 64 + lane] = hh1;
  h1l[base + 64 + lane] = f2bf(o1 - bf2f(hh1));
}

// ---------------- per-node attention logits (layer 2) ----------------------
__global__ __launch_bounds__(256) void elr2_kernel(const unsigned short* __restrict__ feat,  // bf16 ld48
                                                   const float* __restrict__ al,
                                                   const float* __restrict__ ar,
                                                   float* __restrict__ el,
                                                   float* __restrict__ er, int N) {
  int wid = threadIdx.x >> 6;
  int lane = threadIdx.x & 63;
  int n = blockIdx.x * 4 + wid;
  if (n >= N) return;
  float f = 0.f, a = 0.f, r = 0.f;
  if (lane < 47) {
    f = bf2f(feat[(size_t)n * 48 + lane]);
    a = al[lane];
    r = ar[lane];
  }
  float e = wave_sum(f * a);
  float rr = wave_sum(f * r);
  if (lane == 0) {
    el[n] = e;
    er[n] = rr;
  }
}

// ---------------- attn2: thread per node ----------------------------------
__global__ __launch_bounds__(256) void attn2_kernel(const float* __restrict__ el,
                                                    const float* __restrict__ er,
                                                    const int* __restrict__ row_start,
                                                    const unsigned short* __restrict__ csr_src,
                                                    float* __restrict__ alpha,
                                                    float* __restrict__ inv_s, int N) {
  int n = blockIdx.x * 256 + threadIdx.x;
  if (n >= N) return;
  int beg = row_start[n], end = row_start[n + 1];
  float r = er[n];
  float m = -INFINITY;
  for (int i = beg; i < end; ++i) {
    float e = el[csr_src[i]] + r;
    e = e > 0.f ? e : 0.2f * e;
    alpha[i] = e;
    m = fmaxf(m, e);
  }
  float s = 0.f;
  for (int i = beg; i < end; ++i) {
    float p = __expf(alpha[i] - m);
    s += p;
    alpha[i] = p;
  }
  inv_s[n] = 1.0f / fmaxf(s, 1e-9f);
}

// ---------------- fused GAT layer 2 aggregation -> d_out ------------------
// 8-wide unrolled gathers (MLP).
__global__ __launch_bounds__(256) void gat2_agg(const unsigned short* __restrict__ feat,  // bf16 ld48
                                                const float* __restrict__ alpha,
                                                const float* __restrict__ inv_s,
                                                const int* __restrict__ row_start,
                                                const unsigned short* __restrict__ csr_src,
                                                const float* __restrict__ b,
                                                float* __restrict__ out, int N) {
  int wid = threadIdx.x >> 6;
  int lane = threadIdx.x & 63;
  int n = blockIdx.x * 4 + wid;
  if (n >= N) return;
  int beg = row_start[n], end = row_start[n + 1];
  int lidx = lane < 47 ? lane : 0;
  float acc = 0.f;
  int i = beg;
  for (; i + 7 < end; i += 8) {
    float g0 = bf2f(feat[(size_t)csr_src[i] * 48 + lidx]);
    float g1 = bf2f(feat[(size_t)csr_src[i + 1] * 48 + lidx]);
    float g2 = bf2f(feat[(size_t)csr_src[i + 2] * 48 + lidx]);
    float g3 = bf2f(feat[(size_t)csr_src[i + 3] * 48 + lidx]);
    float g4 = bf2f(feat[(size_t)csr_src[i + 4] * 48 + lidx]);
    float g5 = bf2f(feat[(size_t)csr_src[i + 5] * 48 + lidx]);
    float g6 = bf2f(feat[(size_t)csr_src[i + 6] * 48 + lidx]);
    float g7 = bf2f(feat[(size_t)csr_src[i + 7] * 48 + lidx]);
    float p0 = alpha[i], p1 = alpha[i + 1], p2 = alpha[i + 2], p3 = alpha[i + 3];
    float p4 = alpha[i + 4], p5 = alpha[i + 5], p6 = alpha[i + 6], p7 = alpha[i + 7];
    acc = fmaf(p0, g0, acc);
    acc = fmaf(p1, g1, acc);
    acc = fmaf(p2, g2, acc);
    acc = fmaf(p3, g3, acc);
    acc = fmaf(p4, g4, acc);
    acc = fmaf(p5, g5, acc);
    acc = fmaf(p6, g6, acc);
    acc = fmaf(p7, g7, acc);
  }
  for (; i < end; ++i) {
    acc = fmaf(alpha[i], bf2f(feat[(size_t)csr_src[i] * 48 + lidx]), acc);
  }
  if (lane < 47) {
    out[(size_t)n * 47 + lane] = acc * inv_s[n] + b[lane];
  }
}

// ---------------------------------------------------------------------------
extern "C" void kernel_launch(void* const* d_in, const int* in_sizes, int n_in,
                              void* d_out, int out_size, void* d_ws, size_t ws_size,
                              hipStream_t stream) {
  const float* x = (const float*)d_in[0];
  const int* src = (const int*)d_in[1];
  const int* dst = (const int*)d_in[2];
  const float* sage_w_self = (const float*)d_in[3];
  const float* sage_w_neigh = (const float*)d_in[4];
  const float* sage_b = (const float*)d_in[5];
  const float* gat1_w = (const float*)d_in[6];
  const float* gat1_al = (const float*)d_in[7];
  const float* gat1_ar = (const float*)d_in[8];
  const float* gat1_b = (const float*)d_in[9];
  const float* gat2_w = (const float*)d_in[10];
  const float* gat2_al = (const float*)d_in[11];
  const float* gat2_ar = (const float*)d_in[12];
  const float* gat2_b = (const float*)d_in[13];
  float* out = (float*)d_out;

  const int N = in_sizes[0] / 256;
  const int E = in_sizes[1];

  char* ws = (char*)d_ws;
  size_t off = 0;
  auto alloc = [&](size_t bytes) {
    size_t o = off;
    off += (bytes + 255) & ~(size_t)255;
    return o;
  };
  int* deg_i = (int*)(ws + alloc((size_t)N * 4));
  int* row_start = (int*)(ws + alloc((size_t)(N + 1) * 4));
  int* cursor = (int*)(ws + alloc((size_t)N * 4));
  unsigned short* csr_src = (unsigned short*)(ws + alloc((size_t)E * 2));
  int* psum = (int*)(ws + alloc(((size_t)N / 1024 + 2) * 4));
  float* bufA = (float*)(ws + alloc((size_t)N * 128 * 4));       // z; later alpha1/alpha2
  unsigned* bufG = (unsigned*)(ws + alloc((size_t)N * 64 * 4));  // yI -> feat1I -> feat2b
  unsigned short* bufX = (unsigned short*)(ws + alloc((size_t)N * 256 * 2 * 2));  // xh|xl
  unsigned short* wt_sh = (unsigned short*)(ws + alloc(128 * 256 * 2));
  unsigned short* wt_sl = (unsigned short*)(ws + alloc(128 * 256 * 2));
  unsigned short* wt_nh = (unsigned short*)(ws + alloc(128 * 256 * 2));
  unsigned short* wt_nl = (unsigned short*)(ws + alloc(128 * 256 * 2));
  unsigned short* wt_1h = (unsigned short*)(ws + alloc(128 * 128 * 2));
  unsigned short* wt_1l = (unsigned short*)(ws + alloc(128 * 128 * 2));
  unsigned short* wt_2h = (unsigned short*)(ws + alloc(48 * 128 * 2));
  unsigned short* wt_2l = (unsigned short*)(ws + alloc(48 * 128 * 2));
  float2* el1 = (float2*)(ws + alloc((size_t)N * 8));
  float2* er1 = (float2*)(ws + alloc((size_t)N * 8));
  float* el2 = (float*)(ws + alloc((size_t)N * 4));
  float* er2 = (float*)(ws + alloc((size_t)N * 4));
  float2* inv_s1 = (float2*)(ws + alloc((size_t)N * 8));
  float* inv_s2 = (float*)(ws + alloc((size_t)N * 4));
  (void)ws_size;
  (void)n_in;
  (void)out_size;

  // lifetimes:
  unsigned short* xh = (unsigned short*)bufX;       // dead after L0 gemm
  unsigned short* xl = bufX + (size_t)N * 256;      // dead after L0 gemm
  float* z = bufA;                                  // dead after sage_agg
  unsigned* yI = bufG;                              // dead after sage_agg
  unsigned short* h0h = bufX;                       // reuse xh region
  unsigned short* h0l = bufX + (size_t)N * 128;
  unsigned* feat1I = bufG;                          // reuse yI; dead after gat1_agg
  float2* alpha1 = (float2*)bufA;                   // reuse z; dead after gat1_agg
  unsigned short* h1h = bufX + (size_t)N * 256;     // reuse xl region
  unsigned short* h1l = bufX + (size_t)N * 256 + (size_t)N * 128;
  unsigned short* feat2b = (unsigned short*)bufG;   // reuse feat1I
  float* alpha2 = bufA;                             // reuse alpha1

  hipMemsetAsync(deg_i, 0, (size_t)N * 4, stream);

  const int eb = (E + 255) / 256;
  const int eb2 = (E + 511) / 512;
  const int nb4 = (N + 3) / 4;
  const int nb256 = (N + 255) / 256;
  const int gx = (N + 127) / 128;
  const int PB = (N + 1023) / 1024;

  split_x<<<2048, 256, 0, stream>>>(x, xh, xl, N * 64);
  prep_w<<<(128 * 256 + 255) / 256, 256, 0, stream>>>(sage_w_self, 128, 256, 128, wt_sh, wt_sl);
  prep_w<<<(128 * 256 + 255) / 256, 256, 0, stream>>>(sage_w_neigh, 128, 256, 128, wt_nh, wt_nl);
  prep_w<<<(128 * 128 + 255) / 256, 256, 0, stream>>>(gat1_w, 128, 128, 128, wt_1h, wt_1l);
  prep_w<<<(48 * 128 + 255) / 256, 256, 0, stream>>>(gat2_w, 47, 128, 48, wt_2h, wt_2l);

  deg_kernel<<<eb, 256, 0, stream>>>(dst, deg_i, E);
  scan_partial<<<PB, 256, 0, stream>>>(deg_i, psum, N);
  scan_psum<<<1, 64, 0, stream>>>(psum, PB);
  scan_final<<<PB, 256, 0, stream>>>(deg_i, psum, row_start, N, E);
  hipMemcpyAsync(cursor, row_start, (size_t)N * 4, hipMemcpyDeviceToDevice, stream);
  scatter_kernel<<<eb2, 256, 0, stream>>>(src, dst, cursor, csr_src, E);

  // layer 0: y=0 -> z = x@W_self (f32, ldc=128 floats),
  //          y=1 -> yI = x@W_neigh (packed bf16 ilv, ldu=64 uints)
  {
    dim3 grid(gx, 2);
    gemm_mfma<256, 8><<<grid, 256, 0, stream>>>(xh, xl, wt_sh, wt_sl, wt_nh, wt_nl,
                                                z, yI, 128, N, 128, 0, 1);
  }
  sage_agg<<<nb4, 256, 0, stream>>>(z, yI, row_start, csr_src, sage_b, h0h, h0l, N);

  // GAT layer 1: feat1I = h0 @ gat1_w (packed bf16 ilv, ldc=128 -> ldu=64 uints)
  {
    dim3 grid(gx, 1);
    gemm_mfma<128, 8><<<grid, 256, 0, stream>>>(h0h, h0l, wt_1h, wt_1l, wt_1h, wt_1l,
                                                feat1I, feat1I, 128, N, 128, 1, 1);
  }
  elr1_kernel<<<nb4, 256, 0, stream>>>(feat1I, gat1_al, gat1_ar, el1, er1, N);
  attn1_kernel<<<nb256, 256, 0, stream>>>(el1, er1, row_start, csr_src, alpha1, inv_s1, N);
  gat1_agg<<<nb4, 256, 0, stream>>>(feat1I, alpha1, inv_s1, row_start, csr_src, gat1_b,
                                    h1h, h1l, N);

  // GAT layer 2: feat2b = h1 @ gat2_w (bf16 std, ldc=48 ushorts)
  {
    dim3 grid(gx, 1);
    gemm_mfma<128, 3><<<grid, 256, 0, stream>>>(h1h, h1l, wt_2h, wt_2l, wt_2h, wt_2l,
                                                feat2b, feat2b, 48, N, 47, 2, 2);
  }
  elr2_kernel<<<nb4, 256, 0, stream>>>(feat2b, gat2_al, gat2_ar, el2, er2, N);
  attn2_kernel<<<nb256, 256, 0, stream>>>(el2, er2, row_start, csr_src, alpha2, inv_s2, N);
  gat2_agg<<<nb4, 256, 0, stream>>>(feat2b, alpha2, inv_s2, row_start, csr_src, gat2_b, out, N);
}

// Round 14
// 318.528 us; speedup vs baseline: 1.2533x; 1.1473x over previous
//
#include <hip/hip_runtime.h>

// ---------------------------------------------------------------------------
// GAT_4733053960619: SAGEConv(mean) -> ELU -> GAT(2 heads,64) -> ELU -> GAT(1,47)
// N=50000, E=800000, IN_FEATS=256. All fp32.
//
// R13 = R12 + softmax fused into agg kernels (attn1/attn2 deleted).
// Per node-wave, windowed (256-edge) wave-parallel online softmax:
// phase1 lane-per-edge logits -> wave max/sum -> (p0,p1,u) parked in
// wave-private LDS; phase2 uniform ds_read broadcast + 8-wide gather-fma.
// Removes alpha1/alpha2 round-trips (9.6MB W + 9.6MB R) + 2 dispatches.
// ---------------------------------------------------------------------------

typedef __attribute__((ext_vector_type(8))) short bf16x8;
typedef __attribute__((ext_vector_type(4))) float f32x4;

__device__ __forceinline__ float wave_sum(float v) {
#pragma unroll
  for (int o = 32; o > 0; o >>= 1) v += __shfl_xor(v, o, 64);
  return v;
}

__device__ __forceinline__ int wave_sum_i(int v) {
#pragma unroll
  for (int o = 32; o > 0; o >>= 1) v += __shfl_xor(v, o, 64);
  return v;
}

__device__ __forceinline__ float elu_f(float v) {
  return v > 0.f ? v : __expf(v) - 1.0f;
}

__device__ __forceinline__ unsigned short f2bf(float x) {
  union { float f; unsigned u; } v;
  v.f = x;
  unsigned r = v.u + 0x7FFFu + ((v.u >> 16) & 1u);
  return (unsigned short)(r >> 16);
}

__device__ __forceinline__ float bf2f(unsigned short h) {
  union { unsigned u; float f; } v;
  v.u = ((unsigned)h) << 16;
  return v.f;
}

// packed 2xbf16 (lo=head0, hi=head1) -> (f0, f1)
__device__ __forceinline__ float2 unpk(unsigned v) {
  union { unsigned u; float f; } a, b;
  a.u = v << 16;
  b.u = v & 0xFFFF0000u;
  return make_float2(a.f, b.f);
}

// ---------------- CSR build ----------------
__global__ __launch_bounds__(256) void deg_kernel(const int* __restrict__ dst,
                                                  int* __restrict__ deg, int E) {
  int i = blockIdx.x * 256 + threadIdx.x;
  if (i < E) atomicAdd(&deg[dst[i]], 1);
}

// phase 1: per-1024-chunk sums
__global__ __launch_bounds__(256) void scan_partial(const int* __restrict__ deg,
                                                    int* __restrict__ psum, int n) {
  __shared__ int red[4];
  const int t = threadIdx.x;
  const int base = blockIdx.x * 1024;
  int s = 0;
#pragma unroll
  for (int j = 0; j < 4; ++j) {
    int idx = base + t + j * 256;
    s += (idx < n) ? deg[idx] : 0;
  }
  s = wave_sum_i(s);
  const int lane = t & 63, w = t >> 6;
  if (lane == 0) red[w] = s;
  __syncthreads();
  if (t == 0) psum[blockIdx.x] = red[0] + red[1] + red[2] + red[3];
}

// phase 2: exclusive scan of partials (single wave, carry loop)
__global__ __launch_bounds__(64) void scan_psum(int* __restrict__ psum, int PB) {
  const int lane = threadIdx.x;
  int carry = 0;
  for (int base = 0; base < PB; base += 64) {
    int v = (base + lane < PB) ? psum[base + lane] : 0;
    int inc = v;
#pragma unroll
    for (int o = 1; o < 64; o <<= 1) {
      int u = __shfl_up(inc, o, 64);
      if (lane >= o) inc += u;
    }
    if (base + lane < PB) psum[base + lane] = carry + inc - v;
    carry += __shfl(inc, 63, 64);
  }
}

// phase 3: per-chunk exclusive scan + block offset -> row_start
__global__ __launch_bounds__(256) void scan_final(const int* __restrict__ deg,
                                                  const int* __restrict__ psum,
                                                  int* __restrict__ row_start,
                                                  int n, int E) {
  __shared__ int woff[4];
  const int t = threadIdx.x;
  const int lane = t & 63, w = t >> 6;
  const int base = blockIdx.x * 1024 + t * 4;
  int d0 = (base + 0 < n) ? deg[base + 0] : 0;
  int d1 = (base + 1 < n) ? deg[base + 1] : 0;
  int d2 = (base + 2 < n) ? deg[base + 2] : 0;
  int d3 = (base + 3 < n) ? deg[base + 3] : 0;
  int l0 = d0, l1 = l0 + d1, l2 = l1 + d2, l3 = l2 + d3;
  int inc = l3;
#pragma unroll
  for (int o = 1; o < 64; o <<= 1) {
    int u = __shfl_up(inc, o, 64);
    if (lane >= o) inc += u;
  }
  int texc = inc - l3;  // exclusive within wave
  if (lane == 63) woff[w] = inc;
  __syncthreads();
  int wo = 0;
  if (w == 0 && lane < 4) {
    int s = woff[lane];
    int p = s;
#pragma unroll
    for (int o = 1; o < 4; o <<= 1) {
      int u = __shfl_up(p, o, 64);
      if (lane >= o) p += u;
    }
    woff[lane] = p - s;  // exclusive wave offsets
  }
  __syncthreads();
  wo = woff[w];
  const int boff = psum[blockIdx.x] + wo + texc;
  if (base + 0 < n) row_start[base + 0] = boff;
  if (base + 1 < n) row_start[base + 1] = boff + l0;
  if (base + 2 < n) row_start[base + 2] = boff + l1;
  if (base + 3 < n) row_start[base + 3] = boff + l2;
  if (blockIdx.x == 0 && t == 0) row_start[n] = E;
}

// cursor pre-filled with row_start; atomicAdd -> absolute slot; plain ushort
// store (src ids fit 16 bits since N < 65536).
__global__ __launch_bounds__(256) void scatter_kernel(const int* __restrict__ src,
                                                      const int* __restrict__ dst,
                                                      int* __restrict__ cursor,
                                                      unsigned short* __restrict__ csr_src,
                                                      int E) {
  int i = blockIdx.x * 512 + threadIdx.x;
  int i2 = i + 256;
  int d0 = (i < E) ? dst[i] : 0;
  int d1 = (i2 < E) ? dst[i2] : 0;
  int s0 = (i < E) ? src[i] : 0;
  int s1 = (i2 < E) ? src[i2] : 0;
  int p0 = 0, p1 = 0;
  if (i < E) p0 = atomicAdd(&cursor[d0], 1);
  if (i2 < E) p1 = atomicAdd(&cursor[d1], 1);
  if (i < E) csr_src[p0] = (unsigned short)s0;
  if (i2 < E) csr_src[p1] = (unsigned short)s1;
}

// ---------------- fp32 -> bf16 hi/lo split (x input) ----------------
__global__ __launch_bounds__(256) void split_x(const float* __restrict__ x,
                                               unsigned short* __restrict__ xh,
                                               unsigned short* __restrict__ xl, int n4) {
  int i = blockIdx.x * 256 + threadIdx.x;
  int stride = gridDim.x * 256;
  for (; i < n4; i += stride) {
    float4 v = ((const float4*)x)[i];
    ushort4 h, l;
    h.x = f2bf(v.x); l.x = f2bf(v.x - bf2f(h.x));
    h.y = f2bf(v.y); l.y = f2bf(v.y - bf2f(h.y));
    h.z = f2bf(v.z); l.z = f2bf(v.z - bf2f(h.z));
    h.w = f2bf(v.w); l.w = f2bf(v.w - bf2f(h.w));
    ((ushort4*)xh)[i] = h;
    ((ushort4*)xl)[i] = l;
  }
}

// ---------------- weight prep: W[K][N] f32 -> W^T hi/lo [Npad][K] bf16 ------
__global__ __launch_bounds__(256) void prep_w(const float* __restrict__ W, int N, int K,
                                              int Npad, unsigned short* __restrict__ th,
                                              unsigned short* __restrict__ tl) {
  int i = blockIdx.x * 256 + threadIdx.x;
  if (i >= Npad * K) return;
  int n = i / K, k = i - n * K;
  float v = (n < N) ? W[(size_t)k * N + n] : 0.f;
  unsigned short h = f2bf(v);
  th[i] = h;
  tl[i] = f2bf(v - bf2f(h));
}

// ---------------- MFMA GEMM: C = A @ B, split-bf16, LDS-staged B ----------
// A as hi/lo bf16 [M][K]; B^T as hi/lo bf16 [Npad][K]; Npad = NT*16.
// Block = 4 waves = 128 rows; wave = 32 rows (2 fragments) x NT*16 cols.
// omode: 0 = f32 std (ldc floats); 1 = packed-bf16 head-interleave, uint
// stride ldu = ldc>>1; 2 = bf16 std (ldc ushorts).
template <int K, int NT>
__global__ __launch_bounds__(256) void gemm_mfma(
    const unsigned short* __restrict__ Ah, const unsigned short* __restrict__ Al,
    const unsigned short* __restrict__ BTh0, const unsigned short* __restrict__ BTl0,
    const unsigned short* __restrict__ BTh1, const unsigned short* __restrict__ BTl1,
    void* __restrict__ C0, void* __restrict__ C1,
    int ldc, int M, int Ncols, int omode0, int omode1) {
  constexpr int K2 = K * 2;    // bytes per B^T row
  constexpr int NKT = K / 32;  // k-tiles
  __shared__ unsigned short Bs[2][2][NT * 512];  // [buf][hi/lo][nt*512 + kg*128 + lrow*8]

  const unsigned short* BTh = blockIdx.y ? BTh1 : BTh0;
  const unsigned short* BTl = blockIdx.y ? BTl1 : BTl0;
  void* Cv = blockIdx.y ? C1 : C0;
  const int omode = blockIdx.y ? omode1 : omode0;

  const int wid = threadIdx.x >> 6;
  const int lane = threadIdx.x & 63;
  const int lrow = lane & 15;
  const int kg = lane >> 4;
  const int row0 = blockIdx.x * 128 + wid * 32;
  const int ra = min(row0 + lrow, M - 1);
  const int rb = min(row0 + 16 + lrow, M - 1);
  const size_t aoffA = (size_t)ra * K + kg * 8;
  const size_t aoffB = (size_t)rb * K + kg * 8;

  auto stage = [&](int buf, int kt) {
    for (int j = wid; j < 2 * NT; j += 4) {
      const int h = (j >= NT) ? 1 : 0;
      const int nt = h ? j - NT : j;
      const unsigned short* src = h ? BTl : BTh;
      const char* g = (const char*)src + (size_t)(nt * 16 + lrow) * K2 + kt * 64 + kg * 16;
      unsigned short* l = &Bs[buf][h][nt * 512];
      __builtin_amdgcn_global_load_lds(
          (const __attribute__((address_space(1))) unsigned*)g,
          (__attribute__((address_space(3))) unsigned*)l, 16, 0, 0);
    }
  };

  f32x4 accA[NT] = {};
  f32x4 accB[NT] = {};

  stage(0, 0);
  bf16x8 cahA = *(const bf16x8*)(Ah + aoffA);
  bf16x8 calA = *(const bf16x8*)(Al + aoffA);
  bf16x8 cahB = *(const bf16x8*)(Ah + aoffB);
  bf16x8 calB = *(const bf16x8*)(Al + aoffB);

  for (int kt = 0; kt < NKT; ++kt) {
    __syncthreads();  // buf[kt&1] staged
    if (kt + 1 < NKT) stage((kt + 1) & 1, kt + 1);
    const int kn = (kt + 1 < NKT) ? (kt + 1) * 32 : kt * 32;
    bf16x8 nahA = *(const bf16x8*)(Ah + aoffA + kn);
    bf16x8 nalA = *(const bf16x8*)(Al + aoffA + kn);
    bf16x8 nahB = *(const bf16x8*)(Ah + aoffB + kn);
    bf16x8 nalB = *(const bf16x8*)(Al + aoffB + kn);
    const int buf = kt & 1;
#pragma unroll
    for (int nt = 0; nt < NT; ++nt) {
      bf16x8 bh = ((const bf16x8*)&Bs[buf][0][nt * 512])[lane];
      bf16x8 bl = ((const bf16x8*)&Bs[buf][1][nt * 512])[lane];
      accA[nt] = __builtin_amdgcn_mfma_f32_16x16x32_bf16(cahA, bh, accA[nt], 0, 0, 0);
      accA[nt] = __builtin_amdgcn_mfma_f32_16x16x32_bf16(cahA, bl, accA[nt], 0, 0, 0);
      accA[nt] = __builtin_amdgcn_mfma_f32_16x16x32_bf16(calA, bh, accA[nt], 0, 0, 0);
      accB[nt] = __builtin_amdgcn_mfma_f32_16x16x32_bf16(cahB, bh, accB[nt], 0, 0, 0);
      accB[nt] = __builtin_amdgcn_mfma_f32_16x16x32_bf16(cahB, bl, accB[nt], 0, 0, 0);
      accB[nt] = __builtin_amdgcn_mfma_f32_16x16x32_bf16(calB, bh, accB[nt], 0, 0, 0);
    }
    cahA = nahA; calA = nalA; cahB = nahB; calB = nalB;
  }

  if (omode == 1) {
    // packed-bf16 head-interleave: uint stride = ldc/2
    unsigned* Cu = (unsigned*)Cv;
    const int ldu = ldc >> 1;
#pragma unroll
    for (int nt = 0; nt < NT / 2; ++nt) {
      int d = nt * 16 + lrow;
#pragma unroll
      for (int r = 0; r < 4; ++r) {
        int g0 = row0 + kg * 4 + r;
        if (g0 < M) {
          unsigned p = (unsigned)f2bf(accA[nt][r]) |
                       ((unsigned)f2bf(accA[nt + NT / 2][r]) << 16);
          Cu[(size_t)g0 * ldu + d] = p;
        }
        int g1 = row0 + 16 + kg * 4 + r;
        if (g1 < M) {
          unsigned p = (unsigned)f2bf(accB[nt][r]) |
                       ((unsigned)f2bf(accB[nt + NT / 2][r]) << 16);
          Cu[(size_t)g1 * ldu + d] = p;
        }
      }
    }
  } else if (omode == 2) {
    unsigned short* Cs = (unsigned short*)Cv;
#pragma unroll
    for (int nt = 0; nt < NT; ++nt) {
      int gc = nt * 16 + lrow;
      if (gc >= Ncols) continue;
#pragma unroll
      for (int r = 0; r < 4; ++r) {
        int g0 = row0 + kg * 4 + r;
        if (g0 < M) Cs[(size_t)g0 * ldc + gc] = f2bf(accA[nt][r]);
        int g1 = row0 + 16 + kg * 4 + r;
        if (g1 < M) Cs[(size_t)g1 * ldc + gc] = f2bf(accB[nt][r]);
      }
    }
  } else {
    float* C = (float*)Cv;
#pragma unroll
    for (int nt = 0; nt < NT; ++nt) {
      int gc = nt * 16 + lrow;
      if (gc >= Ncols) continue;
#pragma unroll
      for (int r = 0; r < 4; ++r) {
        int g0 = row0 + kg * 4 + r;
        if (g0 < M) C[(size_t)g0 * ldc + gc] = accA[nt][r];
        int g1 = row0 + 16 + kg * 4 + r;
        if (g1 < M) C[(size_t)g1 * ldc + gc] = accB[nt][r];
      }
    }
  }
}

// ---------------- SAGE aggregation (wave per node) -> h0 bf16 hi/lo --------
// yI: packed 2xbf16 per (node, d) uint. 8-wide unrolled gathers (MLP).
__global__ __launch_bounds__(256) void sage_agg(const float* __restrict__ z,
                                                const unsigned* __restrict__ yI,
                                                const int* __restrict__ row_start,
                                                const unsigned short* __restrict__ csr_src,
                                                const float* __restrict__ b,
                                                unsigned short* __restrict__ h0h,
                                                unsigned short* __restrict__ h0l, int N) {
  int wid = threadIdx.x >> 6;
  int lane = threadIdx.x & 63;
  int n = blockIdx.x * 4 + wid;
  if (n >= N) return;
  int s = row_start[n], e = row_start[n + 1];
  float a0 = 0.f, a1 = 0.f;
  int i = s;
  for (; i + 7 < e; i += 8) {
    unsigned v0 = yI[(size_t)csr_src[i] * 64 + lane];
    unsigned v1 = yI[(size_t)csr_src[i + 1] * 64 + lane];
    unsigned v2 = yI[(size_t)csr_src[i + 2] * 64 + lane];
    unsigned v3 = yI[(size_t)csr_src[i + 3] * 64 + lane];
    unsigned v4 = yI[(size_t)csr_src[i + 4] * 64 + lane];
    unsigned v5 = yI[(size_t)csr_src[i + 5] * 64 + lane];
    unsigned v6 = yI[(size_t)csr_src[i + 6] * 64 + lane];
    unsigned v7 = yI[(size_t)csr_src[i + 7] * 64 + lane];
    float2 f0 = unpk(v0), f1 = unpk(v1), f2 = unpk(v2), f3 = unpk(v3);
    float2 f4 = unpk(v4), f5 = unpk(v5), f6 = unpk(v6), f7 = unpk(v7);
    a0 += f0.x + f1.x + f2.x + f3.x + f4.x + f5.x + f6.x + f7.x;
    a1 += f0.y + f1.y + f2.y + f3.y + f4.y + f5.y + f6.y + f7.y;
  }
  for (; i < e; ++i) {
    float2 f = unpk(yI[(size_t)csr_src[i] * 64 + lane]);
    a0 += f.x;
    a1 += f.y;
  }
  float inv = 1.0f / fmaxf((float)(e - s), 1.0f);
  size_t base = (size_t)n * 128;
  float v0 = elu_f(z[base + lane] + a0 * inv + b[lane]);
  float v1 = elu_f(z[base + 64 + lane] + a1 * inv + b[64 + lane]);
  unsigned short hh0 = f2bf(v0), hh1 = f2bf(v1);
  h0h[base + lane] = hh0;
  h0l[base + lane] = f2bf(v0 - bf2f(hh0));
  h0h[base + 64 + lane] = hh1;
  h0l[base + 64 + lane] = f2bf(v1 - bf2f(hh1));
}

// ---------------- per-node attention logits (layer 1) ----------------------
__global__ __launch_bounds__(256) void elr1_kernel(const unsigned* __restrict__ featI,
                                                   const float* __restrict__ al,
                                                   const float* __restrict__ ar,
                                                   float2* __restrict__ el,
                                                   float2* __restrict__ er, int N) {
  int wid = threadIdx.x >> 6;
  int lane = threadIdx.x & 63;
  int n = blockIdx.x * 4 + wid;
  if (n >= N) return;
  float2 f = unpk(featI[(size_t)n * 64 + lane]);
  float e0 = wave_sum(f.x * al[lane]);
  float e1 = wave_sum(f.y * al[64 + lane]);
  float r0 = wave_sum(f.x * ar[lane]);
  float r1 = wave_sum(f.y * ar[64 + lane]);
  if (lane == 0) {
    el[n] = make_float2(e0, e1);
    er[n] = make_float2(r0, r1);
  }
}

// ---------------- fused GAT layer 1: softmax + aggregation (wave/node) -----
// Windowed (256-edge) wave-parallel online softmax; (p0,p1,u) parked in
// wave-private LDS; phase2 uniform ds_read broadcast + 8-wide gather-fma.
__global__ __launch_bounds__(256) void gat1_agg(const unsigned* __restrict__ featI,
                                                const float2* __restrict__ el,
                                                const float2* __restrict__ er,
                                                const int* __restrict__ row_start,
                                                const unsigned short* __restrict__ csr_src,
                                                const float* __restrict__ b,
                                                unsigned short* __restrict__ h1h,
                                                unsigned short* __restrict__ h1l, int N) {
  __shared__ float4 pbuf[4][256];
  int wid = threadIdx.x >> 6;
  int lane = threadIdx.x & 63;
  int n = blockIdx.x * 4 + wid;
  if (n >= N) return;
  int beg = row_start[n], end = row_start[n + 1];
  float2 ern = er[n];
  float m0 = -INFINITY, m1 = -INFINITY;
  float s0 = 0.f, s1 = 0.f, a0 = 0.f, a1 = 0.f;
  for (int w = beg; w < end; w += 256) {
    int nv = min(end - w, 256);
    float e0c[4], e1c[4];
    unsigned uc[4];
    float wm0 = -INFINITY, wm1 = -INFINITY;
#pragma unroll
    for (int c = 0; c < 4; ++c) {
      int i = w + c * 64 + lane;
      bool v = (i < w + nv);
      unsigned u = v ? (unsigned)csr_src[i] : 0u;
      float2 l = el[u];
      float e0 = l.x + ern.x;
      e0 = e0 > 0.f ? e0 : 0.2f * e0;
      float e1 = l.y + ern.y;
      e1 = e1 > 0.f ? e1 : 0.2f * e1;
      if (!v) {
        e0 = -INFINITY;
        e1 = -INFINITY;
      }
      uc[c] = u;
      e0c[c] = e0;
      e1c[c] = e1;
      wm0 = fmaxf(wm0, e0);
      wm1 = fmaxf(wm1, e1);
    }
#pragma unroll
    for (int o = 32; o > 0; o >>= 1) {
      wm0 = fmaxf(wm0, __shfl_xor(wm0, o, 64));
      wm1 = fmaxf(wm1, __shfl_xor(wm1, o, 64));
    }
    float nm0 = fmaxf(m0, wm0), nm1 = fmaxf(m1, wm1);
    float sc0 = __expf(m0 - nm0);  // first window: exp(-inf)=0, a/s were 0
    float sc1 = __expf(m1 - nm1);
    float ls0 = 0.f, ls1 = 0.f;
#pragma unroll
    for (int c = 0; c < 4; ++c) {
      float p0 = __expf(e0c[c] - nm0);  // invalid: exp(-inf)=0
      float p1 = __expf(e1c[c] - nm1);
      ls0 += p0;
      ls1 += p1;
      pbuf[wid][c * 64 + lane] = make_float4(p0, p1, __uint_as_float(uc[c]), 0.f);
    }
    ls0 = wave_sum(ls0);
    ls1 = wave_sum(ls1);
    s0 = s0 * sc0 + ls0;
    s1 = s1 * sc1 + ls1;
    a0 *= sc0;
    a1 *= sc1;
    m0 = nm0;
    m1 = nm1;
    // phase 2: 8-wide gather-fma; entries >= nv have p=0 (harmless u=0 gather)
    for (int j = 0; j < nv; j += 8) {
      float4 q0 = pbuf[wid][j + 0];
      float4 q1 = pbuf[wid][j + 1];
      float4 q2 = pbuf[wid][j + 2];
      float4 q3 = pbuf[wid][j + 3];
      float4 q4 = pbuf[wid][j + 4];
      float4 q5 = pbuf[wid][j + 5];
      float4 q6 = pbuf[wid][j + 6];
      float4 q7 = pbuf[wid][j + 7];
      unsigned x0 = featI[(size_t)__float_as_uint(q0.z) * 64 + lane];
      unsigned x1 = featI[(size_t)__float_as_uint(q1.z) * 64 + lane];
      unsigned x2 = featI[(size_t)__float_as_uint(q2.z) * 64 + lane];
      unsigned x3 = featI[(size_t)__float_as_uint(q3.z) * 64 + lane];
      unsigned x4 = featI[(size_t)__float_as_uint(q4.z) * 64 + lane];
      unsigned x5 = featI[(size_t)__float_as_uint(q5.z) * 64 + lane];
      unsigned x6 = featI[(size_t)__float_as_uint(q6.z) * 64 + lane];
      unsigned x7 = featI[(size_t)__float_as_uint(q7.z) * 64 + lane];
      float2 f0 = unpk(x0), f1 = unpk(x1), f2 = unpk(x2), f3 = unpk(x3);
      float2 f4 = unpk(x4), f5 = unpk(x5), f6 = unpk(x6), f7 = unpk(x7);
      a0 = fmaf(q0.x, f0.x, a0); a1 = fmaf(q0.y, f0.y, a1);
      a0 = fmaf(q1.x, f1.x, a0); a1 = fmaf(q1.y, f1.y, a1);
      a0 = fmaf(q2.x, f2.x, a0); a1 = fmaf(q2.y, f2.y, a1);
      a0 = fmaf(q3.x, f3.x, a0); a1 = fmaf(q3.y, f3.y, a1);
      a0 = fmaf(q4.x, f4.x, a0); a1 = fmaf(q4.y, f4.y, a1);
      a0 = fmaf(q5.x, f5.x, a0); a1 = fmaf(q5.y, f5.y, a1);
      a0 = fmaf(q6.x, f6.x, a0); a1 = fmaf(q6.y, f6.y, a1);
      a0 = fmaf(q7.x, f7.x, a0); a1 = fmaf(q7.y, f7.y, a1);
    }
  }
  float inv0 = 1.0f / fmaxf(s0, 1e-9f);
  float inv1 = 1.0f / fmaxf(s1, 1e-9f);
  float o0 = elu_f(a0 * inv0 + b[lane]);
  float o1 = elu_f(a1 * inv1 + b[64 + lane]);
  size_t base = (size_t)n * 128;
  unsigned short hh0 = f2bf(o0), hh1 = f2bf(o1);
  h1h[base + lane] = hh0;
  h1l[base + lane] = f2bf(o0 - bf2f(hh0));
  h1h[base + 64 + lane] = hh1;
  h1l[base + 64 + lane] = f2bf(o1 - bf2f(hh1));
}

// ---------------- per-node attention logits (layer 2) ----------------------
__global__ __launch_bounds__(256) void elr2_kernel(const unsigned short* __restrict__ feat,  // bf16 ld48
                                                   const float* __restrict__ al,
                                                   const float* __restrict__ ar,
                                                   float* __restrict__ el,
                                                   float* __restrict__ er, int N) {
  int wid = threadIdx.x >> 6;
  int lane = threadIdx.x & 63;
  int n = blockIdx.x * 4 + wid;
  if (n >= N) return;
  float f = 0.f, a = 0.f, r = 0.f;
  if (lane < 47) {
    f = bf2f(feat[(size_t)n * 48 + lane]);
    a = al[lane];
    r = ar[lane];
  }
  float e = wave_sum(f * a);
  float rr = wave_sum(f * r);
  if (lane == 0) {
    el[n] = e;
    er[n] = rr;
  }
}

// ---------------- fused GAT layer 2: softmax + aggregation -> d_out --------
__global__ __launch_bounds__(256) void gat2_agg(const unsigned short* __restrict__ feat,  // bf16 ld48
                                                const float* __restrict__ el,
                                                const float* __restrict__ er,
                                                const int* __restrict__ row_start,
                                                const unsigned short* __restrict__ csr_src,
                                                const float* __restrict__ b,
                                                float* __restrict__ out, int N) {
  __shared__ float2 pbuf[4][256];
  int wid = threadIdx.x >> 6;
  int lane = threadIdx.x & 63;
  int n = blockIdx.x * 4 + wid;
  if (n >= N) return;
  int beg = row_start[n], end = row_start[n + 1];
  float ern = er[n];
  int lidx = lane < 47 ? lane : 0;
  float m = -INFINITY, s = 0.f, acc = 0.f;
  for (int w = beg; w < end; w += 256) {
    int nv = min(end - w, 256);
    float ec[4];
    unsigned uc[4];
    float wm = -INFINITY;
#pragma unroll
    for (int c = 0; c < 4; ++c) {
      int i = w + c * 64 + lane;
      bool v = (i < w + nv);
      unsigned u = v ? (unsigned)csr_src[i] : 0u;
      float e = el[u] + ern;
      e = e > 0.f ? e : 0.2f * e;
      if (!v) e = -INFINITY;
      uc[c] = u;
      ec[c] = e;
      wm = fmaxf(wm, e);
    }
#pragma unroll
    for (int o = 32; o > 0; o >>= 1) wm = fmaxf(wm, __shfl_xor(wm, o, 64));
    float nm = fmaxf(m, wm);
    float sc = __expf(m - nm);
    float ls = 0.f;
#pragma unroll
    for (int c = 0; c < 4; ++c) {
      float p = __expf(ec[c] - nm);
      ls += p;
      pbuf[wid][c * 64 + lane] = make_float2(p, __uint_as_float(uc[c]));
    }
    ls = wave_sum(ls);
    s = s * sc + ls;
    acc *= sc;
    m = nm;
    for (int j = 0; j < nv; j += 8) {
      float2 q0 = pbuf[wid][j + 0];
      float2 q1 = pbuf[wid][j + 1];
      float2 q2 = pbuf[wid][j + 2];
      float2 q3 = pbuf[wid][j + 3];
      float2 q4 = pbuf[wid][j + 4];
      float2 q5 = pbuf[wid][j + 5];
      float2 q6 = pbuf[wid][j + 6];
      float2 q7 = pbuf[wid][j + 7];
      float g0 = bf2f(feat[(size_t)__float_as_uint(q0.y) * 48 + lidx]);
      float g1 = bf2f(feat[(size_t)__float_as_uint(q1.y) * 48 + lidx]);
      float g2 = bf2f(feat[(size_t)__float_as_uint(q2.y) * 48 + lidx]);
      float g3 = bf2f(feat[(size_t)__float_as_uint(q3.y) * 48 + lidx]);
      float g4 = bf2f(feat[(size_t)__float_as_uint(q4.y) * 48 + lidx]);
      float g5 = bf2f(feat[(size_t)__float_as_uint(q5.y) * 48 + lidx]);
      float g6 = bf2f(feat[(size_t)__float_as_uint(q6.y) * 48 + lidx]);
      float g7 = bf2f(feat[(size_t)__float_as_uint(q7.y) * 48 + lidx]);
      acc = fmaf(q0.x, g0, acc);
      acc = fmaf(q1.x, g1, acc);
      acc = fmaf(q2.x, g2, acc);
      acc = fmaf(q3.x, g3, acc);
      acc = fmaf(q4.x, g4, acc);
      acc = fmaf(q5.x, g5, acc);
      acc = fmaf(q6.x, g6, acc);
      acc = fmaf(q7.x, g7, acc);
    }
  }
  if (lane < 47) {
    out[(size_t)n * 47 + lane] = acc / fmaxf(s, 1e-9f) + b[lane];
  }
}

// ---------------------------------------------------------------------------
extern "C" void kernel_launch(void* const* d_in, const int* in_sizes, int n_in,
                              void* d_out, int out_size, void* d_ws, size_t ws_size,
                              hipStream_t stream) {
  const float* x = (const float*)d_in[0];
  const int* src = (const int*)d_in[1];
  const int* dst = (const int*)d_in[2];
  const float* sage_w_self = (const float*)d_in[3];
  const float* sage_w_neigh = (const float*)d_in[4];
  const float* sage_b = (const float*)d_in[5];
  const float* gat1_w = (const float*)d_in[6];
  const float* gat1_al = (const float*)d_in[7];
  const float* gat1_ar = (const float*)d_in[8];
  const float* gat1_b = (const float*)d_in[9];
  const float* gat2_w = (const float*)d_in[10];
  const float* gat2_al = (const float*)d_in[11];
  const float* gat2_ar = (const float*)d_in[12];
  const float* gat2_b = (const float*)d_in[13];
  float* out = (float*)d_out;

  const int N = in_sizes[0] / 256;
  const int E = in_sizes[1];

  char* ws = (char*)d_ws;
  size_t off = 0;
  auto alloc = [&](size_t bytes) {
    size_t o = off;
    off += (bytes + 255) & ~(size_t)255;
    return o;
  };
  int* deg_i = (int*)(ws + alloc((size_t)N * 4));
  int* row_start = (int*)(ws + alloc((size_t)(N + 1) * 4));
  int* cursor = (int*)(ws + alloc((size_t)N * 4));
  unsigned short* csr_src = (unsigned short*)(ws + alloc((size_t)E * 2));
  int* psum = (int*)(ws + alloc(((size_t)N / 1024 + 2) * 4));
  float* bufA = (float*)(ws + alloc((size_t)N * 128 * 4));       // z
  unsigned* bufG = (unsigned*)(ws + alloc((size_t)N * 64 * 4));  // yI -> feat1I -> feat2b
  unsigned short* bufX = (unsigned short*)(ws + alloc((size_t)N * 256 * 2 * 2));  // xh|xl
  unsigned short* wt_sh = (unsigned short*)(ws + alloc(128 * 256 * 2));
  unsigned short* wt_sl = (unsigned short*)(ws + alloc(128 * 256 * 2));
  unsigned short* wt_nh = (unsigned short*)(ws + alloc(128 * 256 * 2));
  unsigned short* wt_nl = (unsigned short*)(ws + alloc(128 * 256 * 2));
  unsigned short* wt_1h = (unsigned short*)(ws + alloc(128 * 128 * 2));
  unsigned short* wt_1l = (unsigned short*)(ws + alloc(128 * 128 * 2));
  unsigned short* wt_2h = (unsigned short*)(ws + alloc(48 * 128 * 2));
  unsigned short* wt_2l = (unsigned short*)(ws + alloc(48 * 128 * 2));
  float2* el1 = (float2*)(ws + alloc((size_t)N * 8));
  float2* er1 = (float2*)(ws + alloc((size_t)N * 8));
  float* el2 = (float*)(ws + alloc((size_t)N * 4));
  float* er2 = (float*)(ws + alloc((size_t)N * 4));
  (void)ws_size;
  (void)n_in;
  (void)out_size;

  // lifetimes:
  unsigned short* xh = (unsigned short*)bufX;       // dead after L0 gemm
  unsigned short* xl = bufX + (size_t)N * 256;      // dead after L0 gemm
  float* z = bufA;                                  // dead after sage_agg
  unsigned* yI = bufG;                              // dead after sage_agg
  unsigned short* h0h = bufX;                       // reuse xh region
  unsigned short* h0l = bufX + (size_t)N * 128;
  unsigned* feat1I = bufG;                          // reuse yI; dead after gat1_agg
  unsigned short* h1h = bufX + (size_t)N * 256;     // reuse xl region
  unsigned short* h1l = bufX + (size_t)N * 256 + (size_t)N * 128;
  unsigned short* feat2b = (unsigned short*)bufG;   // reuse feat1I

  hipMemsetAsync(deg_i, 0, (size_t)N * 4, stream);

  const int eb = (E + 255) / 256;
  const int eb2 = (E + 511) / 512;
  const int nb4 = (N + 3) / 4;
  const int gx = (N + 127) / 128;
  const int PB = (N + 1023) / 1024;

  split_x<<<2048, 256, 0, stream>>>(x, xh, xl, N * 64);
  prep_w<<<(128 * 256 + 255) / 256, 256, 0, stream>>>(sage_w_self, 128, 256, 128, wt_sh, wt_sl);
  prep_w<<<(128 * 256 + 255) / 256, 256, 0, stream>>>(sage_w_neigh, 128, 256, 128, wt_nh, wt_nl);
  prep_w<<<(128 * 128 + 255) / 256, 256, 0, stream>>>(gat1_w, 128, 128, 128, wt_1h, wt_1l);
  prep_w<<<(48 * 128 + 255) / 256, 256, 0, stream>>>(gat2_w, 47, 128, 48, wt_2h, wt_2l);

  deg_kernel<<<eb, 256, 0, stream>>>(dst, deg_i, E);
  scan_partial<<<PB, 256, 0, stream>>>(deg_i, psum, N);
  scan_psum<<<1, 64, 0, stream>>>(psum, PB);
  scan_final<<<PB, 256, 0, stream>>>(deg_i, psum, row_start, N, E);
  hipMemcpyAsync(cursor, row_start, (size_t)N * 4, hipMemcpyDeviceToDevice, stream);
  scatter_kernel<<<eb2, 256, 0, stream>>>(src, dst, cursor, csr_src, E);

  // layer 0: y=0 -> z = x@W_self (f32, ldc=128 floats),
  //          y=1 -> yI = x@W_neigh (packed bf16 ilv, ldu=64 uints)
  {
    dim3 grid(gx, 2);
    gemm_mfma<256, 8><<<grid, 256, 0, stream>>>(xh, xl, wt_sh, wt_sl, wt_nh, wt_nl,
                                                z, yI, 128, N, 128, 0, 1);
  }
  sage_agg<<<nb4, 256, 0, stream>>>(z, yI, row_start, csr_src, sage_b, h0h, h0l, N);

  // GAT layer 1: feat1I = h0 @ gat1_w (packed bf16 ilv, ldc=128 -> ldu=64 uints)
  {
    dim3 grid(gx, 1);
    gemm_mfma<128, 8><<<grid, 256, 0, stream>>>(h0h, h0l, wt_1h, wt_1l, wt_1h, wt_1l,
                                                feat1I, feat1I, 128, N, 128, 1, 1);
  }
  elr1_kernel<<<nb4, 256, 0, stream>>>(feat1I, gat1_al, gat1_ar, el1, er1, N);
  gat1_agg<<<nb4, 256, 0, stream>>>(feat1I, el1, er1, row_start, csr_src, gat1_b,
                                    h1h, h1l, N);

  // GAT layer 2: feat2b = h1 @ gat2_w (bf16 std, ldc=48 ushorts)
  {
    dim3 grid(gx, 1);
    gemm_mfma<128, 3><<<grid, 256, 0, stream>>>(h1h, h1l, wt_2h, wt_2l, wt_2h, wt_2l,
                                                feat2b, feat2b, 48, N, 47, 2, 2);
  }
  elr2_kernel<<<nb4, 256, 0, stream>>>(feat2b, gat2_al, gat2_ar, el2, er2, N);
  gat2_agg<<<nb4, 256, 0, stream>>>(feat2b, el2, er2, row_start, csr_src, gat2_b, out, N);
}

// Round 15
// 317.429 us; speedup vs baseline: 1.2576x; 1.0035x over previous
//
#include <hip/hip_runtime.h>

// ---------------------------------------------------------------------------
// GAT_4733053960619: SAGEConv(mean) -> ELU -> GAT(2 heads,64) -> ELU -> GAT(1,47)
// N=50000, E=800000, IN_FEATS=256. All fp32.
//
// R14 = R13 + chunk-skip in the fused agg kernels: phase-1 softmax chunks
// run only when c*64 < nv (R13 burned 256 slots/window of exp/LDS work for
// mean-degree-16 nodes -> VALUBusy 60%). Slots in executed chunks beyond nv
// carry p=0; skipped chunks are provably never read by phase 2.
// ---------------------------------------------------------------------------

typedef __attribute__((ext_vector_type(8))) short bf16x8;
typedef __attribute__((ext_vector_type(4))) float f32x4;

__device__ __forceinline__ float wave_sum(float v) {
#pragma unroll
  for (int o = 32; o > 0; o >>= 1) v += __shfl_xor(v, o, 64);
  return v;
}

__device__ __forceinline__ int wave_sum_i(int v) {
#pragma unroll
  for (int o = 32; o > 0; o >>= 1) v += __shfl_xor(v, o, 64);
  return v;
}

__device__ __forceinline__ float elu_f(float v) {
  return v > 0.f ? v : __expf(v) - 1.0f;
}

__device__ __forceinline__ unsigned short f2bf(float x) {
  union { float f; unsigned u; } v;
  v.f = x;
  unsigned r = v.u + 0x7FFFu + ((v.u >> 16) & 1u);
  return (unsigned short)(r >> 16);
}

__device__ __forceinline__ float bf2f(unsigned short h) {
  union { unsigned u; float f; } v;
  v.u = ((unsigned)h) << 16;
  return v.f;
}

// packed 2xbf16 (lo=head0, hi=head1) -> (f0, f1)
__device__ __forceinline__ float2 unpk(unsigned v) {
  union { unsigned u; float f; } a, b;
  a.u = v << 16;
  b.u = v & 0xFFFF0000u;
  return make_float2(a.f, b.f);
}

// ---------------- CSR build ----------------
__global__ __launch_bounds__(256) void deg_kernel(const int* __restrict__ dst,
                                                  int* __restrict__ deg, int E) {
  int i = blockIdx.x * 256 + threadIdx.x;
  if (i < E) atomicAdd(&deg[dst[i]], 1);
}

// phase 1: per-1024-chunk sums
__global__ __launch_bounds__(256) void scan_partial(const int* __restrict__ deg,
                                                    int* __restrict__ psum, int n) {
  __shared__ int red[4];
  const int t = threadIdx.x;
  const int base = blockIdx.x * 1024;
  int s = 0;
#pragma unroll
  for (int j = 0; j < 4; ++j) {
    int idx = base + t + j * 256;
    s += (idx < n) ? deg[idx] : 0;
  }
  s = wave_sum_i(s);
  const int lane = t & 63, w = t >> 6;
  if (lane == 0) red[w] = s;
  __syncthreads();
  if (t == 0) psum[blockIdx.x] = red[0] + red[1] + red[2] + red[3];
}

// phase 2: exclusive scan of partials (single wave, carry loop)
__global__ __launch_bounds__(64) void scan_psum(int* __restrict__ psum, int PB) {
  const int lane = threadIdx.x;
  int carry = 0;
  for (int base = 0; base < PB; base += 64) {
    int v = (base + lane < PB) ? psum[base + lane] : 0;
    int inc = v;
#pragma unroll
    for (int o = 1; o < 64; o <<= 1) {
      int u = __shfl_up(inc, o, 64);
      if (lane >= o) inc += u;
    }
    if (base + lane < PB) psum[base + lane] = carry + inc - v;
    carry += __shfl(inc, 63, 64);
  }
}

// phase 3: per-chunk exclusive scan + block offset -> row_start
__global__ __launch_bounds__(256) void scan_final(const int* __restrict__ deg,
                                                  const int* __restrict__ psum,
                                                  int* __restrict__ row_start,
                                                  int n, int E) {
  __shared__ int woff[4];
  const int t = threadIdx.x;
  const int lane = t & 63, w = t >> 6;
  const int base = blockIdx.x * 1024 + t * 4;
  int d0 = (base + 0 < n) ? deg[base + 0] : 0;
  int d1 = (base + 1 < n) ? deg[base + 1] : 0;
  int d2 = (base + 2 < n) ? deg[base + 2] : 0;
  int d3 = (base + 3 < n) ? deg[base + 3] : 0;
  int l0 = d0, l1 = l0 + d1, l2 = l1 + d2, l3 = l2 + d3;
  int inc = l3;
#pragma unroll
  for (int o = 1; o < 64; o <<= 1) {
    int u = __shfl_up(inc, o, 64);
    if (lane >= o) inc += u;
  }
  int texc = inc - l3;  // exclusive within wave
  if (lane == 63) woff[w] = inc;
  __syncthreads();
  int wo = 0;
  if (w == 0 && lane < 4) {
    int s = woff[lane];
    int p = s;
#pragma unroll
    for (int o = 1; o < 4; o <<= 1) {
      int u = __shfl_up(p, o, 64);
      if (lane >= o) p += u;
    }
    woff[lane] = p - s;  // exclusive wave offsets
  }
  __syncthreads();
  wo = woff[w];
  const int boff = psum[blockIdx.x] + wo + texc;
  if (base + 0 < n) row_start[base + 0] = boff;
  if (base + 1 < n) row_start[base + 1] = boff + l0;
  if (base + 2 < n) row_start[base + 2] = boff + l1;
  if (base + 3 < n) row_start[base + 3] = boff + l2;
  if (blockIdx.x == 0 && t == 0) row_start[n] = E;
}

// cursor pre-filled with row_start; atomicAdd -> absolute slot; plain ushort
// store (src ids fit 16 bits since N < 65536).
__global__ __launch_bounds__(256) void scatter_kernel(const int* __restrict__ src,
                                                      const int* __restrict__ dst,
                                                      int* __restrict__ cursor,
                                                      unsigned short* __restrict__ csr_src,
                                                      int E) {
  int i = blockIdx.x * 512 + threadIdx.x;
  int i2 = i + 256;
  int d0 = (i < E) ? dst[i] : 0;
  int d1 = (i2 < E) ? dst[i2] : 0;
  int s0 = (i < E) ? src[i] : 0;
  int s1 = (i2 < E) ? src[i2] : 0;
  int p0 = 0, p1 = 0;
  if (i < E) p0 = atomicAdd(&cursor[d0], 1);
  if (i2 < E) p1 = atomicAdd(&cursor[d1], 1);
  if (i < E) csr_src[p0] = (unsigned short)s0;
  if (i2 < E) csr_src[p1] = (unsigned short)s1;
}

// ---------------- fp32 -> bf16 hi/lo split (x input) ----------------
__global__ __launch_bounds__(256) void split_x(const float* __restrict__ x,
                                               unsigned short* __restrict__ xh,
                                               unsigned short* __restrict__ xl, int n4) {
  int i = blockIdx.x * 256 + threadIdx.x;
  int stride = gridDim.x * 256;
  for (; i < n4; i += stride) {
    float4 v = ((const float4*)x)[i];
    ushort4 h, l;
    h.x = f2bf(v.x); l.x = f2bf(v.x - bf2f(h.x));
    h.y = f2bf(v.y); l.y = f2bf(v.y - bf2f(h.y));
    h.z = f2bf(v.z); l.z = f2bf(v.z - bf2f(h.z));
    h.w = f2bf(v.w); l.w = f2bf(v.w - bf2f(h.w));
    ((ushort4*)xh)[i] = h;
    ((ushort4*)xl)[i] = l;
  }
}

// ---------------- weight prep: W[K][N] f32 -> W^T hi/lo [Npad][K] bf16 ------
__global__ __launch_bounds__(256) void prep_w(const float* __restrict__ W, int N, int K,
                                              int Npad, unsigned short* __restrict__ th,
                                              unsigned short* __restrict__ tl) {
  int i = blockIdx.x * 256 + threadIdx.x;
  if (i >= Npad * K) return;
  int n = i / K, k = i - n * K;
  float v = (n < N) ? W[(size_t)k * N + n] : 0.f;
  unsigned short h = f2bf(v);
  th[i] = h;
  tl[i] = f2bf(v - bf2f(h));
}

// ---------------- MFMA GEMM: C = A @ B, split-bf16, LDS-staged B ----------
// A as hi/lo bf16 [M][K]; B^T as hi/lo bf16 [Npad][K]; Npad = NT*16.
// Block = 4 waves = 128 rows; wave = 32 rows (2 fragments) x NT*16 cols.
// omode: 0 = f32 std (ldc floats); 1 = packed-bf16 head-interleave, uint
// stride ldu = ldc>>1; 2 = bf16 std (ldc ushorts).
template <int K, int NT>
__global__ __launch_bounds__(256) void gemm_mfma(
    const unsigned short* __restrict__ Ah, const unsigned short* __restrict__ Al,
    const unsigned short* __restrict__ BTh0, const unsigned short* __restrict__ BTl0,
    const unsigned short* __restrict__ BTh1, const unsigned short* __restrict__ BTl1,
    void* __restrict__ C0, void* __restrict__ C1,
    int ldc, int M, int Ncols, int omode0, int omode1) {
  constexpr int K2 = K * 2;    // bytes per B^T row
  constexpr int NKT = K / 32;  // k-tiles
  __shared__ unsigned short Bs[2][2][NT * 512];  // [buf][hi/lo][nt*512 + kg*128 + lrow*8]

  const unsigned short* BTh = blockIdx.y ? BTh1 : BTh0;
  const unsigned short* BTl = blockIdx.y ? BTl1 : BTl0;
  void* Cv = blockIdx.y ? C1 : C0;
  const int omode = blockIdx.y ? omode1 : omode0;

  const int wid = threadIdx.x >> 6;
  const int lane = threadIdx.x & 63;
  const int lrow = lane & 15;
  const int kg = lane >> 4;
  const int row0 = blockIdx.x * 128 + wid * 32;
  const int ra = min(row0 + lrow, M - 1);
  const int rb = min(row0 + 16 + lrow, M - 1);
  const size_t aoffA = (size_t)ra * K + kg * 8;
  const size_t aoffB = (size_t)rb * K + kg * 8;

  auto stage = [&](int buf, int kt) {
    for (int j = wid; j < 2 * NT; j += 4) {
      const int h = (j >= NT) ? 1 : 0;
      const int nt = h ? j - NT : j;
      const unsigned short* src = h ? BTl : BTh;
      const char* g = (const char*)src + (size_t)(nt * 16 + lrow) * K2 + kt * 64 + kg * 16;
      unsigned short* l = &Bs[buf][h][nt * 512];
      __builtin_amdgcn_global_load_lds(
          (const __attribute__((address_space(1))) unsigned*)g,
          (__attribute__((address_space(3))) unsigned*)l, 16, 0, 0);
    }
  };

  f32x4 accA[NT] = {};
  f32x4 accB[NT] = {};

  stage(0, 0);
  bf16x8 cahA = *(const bf16x8*)(Ah + aoffA);
  bf16x8 calA = *(const bf16x8*)(Al + aoffA);
  bf16x8 cahB = *(const bf16x8*)(Ah + aoffB);
  bf16x8 calB = *(const bf16x8*)(Al + aoffB);

  for (int kt = 0; kt < NKT; ++kt) {
    __syncthreads();  // buf[kt&1] staged
    if (kt + 1 < NKT) stage((kt + 1) & 1, kt + 1);
    const int kn = (kt + 1 < NKT) ? (kt + 1) * 32 : kt * 32;
    bf16x8 nahA = *(const bf16x8*)(Ah + aoffA + kn);
    bf16x8 nalA = *(const bf16x8*)(Al + aoffA + kn);
    bf16x8 nahB = *(const bf16x8*)(Ah + aoffB + kn);
    bf16x8 nalB = *(const bf16x8*)(Al + aoffB + kn);
    const int buf = kt & 1;
#pragma unroll
    for (int nt = 0; nt < NT; ++nt) {
      bf16x8 bh = ((const bf16x8*)&Bs[buf][0][nt * 512])[lane];
      bf16x8 bl = ((const bf16x8*)&Bs[buf][1][nt * 512])[lane];
      accA[nt] = __builtin_amdgcn_mfma_f32_16x16x32_bf16(cahA, bh, accA[nt], 0, 0, 0);
      accA[nt] = __builtin_amdgcn_mfma_f32_16x16x32_bf16(cahA, bl, accA[nt], 0, 0, 0);
      accA[nt] = __builtin_amdgcn_mfma_f32_16x16x32_bf16(calA, bh, accA[nt], 0, 0, 0);
      accB[nt] = __builtin_amdgcn_mfma_f32_16x16x32_bf16(cahB, bh, accB[nt], 0, 0, 0);
      accB[nt] = __builtin_amdgcn_mfma_f32_16x16x32_bf16(cahB, bl, accB[nt], 0, 0, 0);
      accB[nt] = __builtin_amdgcn_mfma_f32_16x16x32_bf16(calB, bh, accB[nt], 0, 0, 0);
    }
    cahA = nahA; calA = nalA; cahB = nahB; calB = nalB;
  }

  if (omode == 1) {
    // packed-bf16 head-interleave: uint stride = ldc/2
    unsigned* Cu = (unsigned*)Cv;
    const int ldu = ldc >> 1;
#pragma unroll
    for (int nt = 0; nt < NT / 2; ++nt) {
      int d = nt * 16 + lrow;
#pragma unroll
      for (int r = 0; r < 4; ++r) {
        int g0 = row0 + kg * 4 + r;
        if (g0 < M) {
          unsigned p = (unsigned)f2bf(accA[nt][r]) |
                       ((unsigned)f2bf(accA[nt + NT / 2][r]) << 16);
          Cu[(size_t)g0 * ldu + d] = p;
        }
        int g1 = row0 + 16 + kg * 4 + r;
        if (g1 < M) {
          unsigned p = (unsigned)f2bf(accB[nt][r]) |
                       ((unsigned)f2bf(accB[nt + NT / 2][r]) << 16);
          Cu[(size_t)g1 * ldu + d] = p;
        }
      }
    }
  } else if (omode == 2) {
    unsigned short* Cs = (unsigned short*)Cv;
#pragma unroll
    for (int nt = 0; nt < NT; ++nt) {
      int gc = nt * 16 + lrow;
      if (gc >= Ncols) continue;
#pragma unroll
      for (int r = 0; r < 4; ++r) {
        int g0 = row0 + kg * 4 + r;
        if (g0 < M) Cs[(size_t)g0 * ldc + gc] = f2bf(accA[nt][r]);
        int g1 = row0 + 16 + kg * 4 + r;
        if (g1 < M) Cs[(size_t)g1 * ldc + gc] = f2bf(accB[nt][r]);
      }
    }
  } else {
    float* C = (float*)Cv;
#pragma unroll
    for (int nt = 0; nt < NT; ++nt) {
      int gc = nt * 16 + lrow;
      if (gc >= Ncols) continue;
#pragma unroll
      for (int r = 0; r < 4; ++r) {
        int g0 = row0 + kg * 4 + r;
        if (g0 < M) C[(size_t)g0 * ldc + gc] = accA[nt][r];
        int g1 = row0 + 16 + kg * 4 + r;
        if (g1 < M) C[(size_t)g1 * ldc + gc] = accB[nt][r];
      }
    }
  }
}

// ---------------- SAGE aggregation (wave per node) -> h0 bf16 hi/lo --------
// yI: packed 2xbf16 per (node, d) uint. 8-wide unrolled gathers (MLP).
__global__ __launch_bounds__(256) void sage_agg(const float* __restrict__ z,
                                                const unsigned* __restrict__ yI,
                                                const int* __restrict__ row_start,
                                                const unsigned short* __restrict__ csr_src,
                                                const float* __restrict__ b,
                                                unsigned short* __restrict__ h0h,
                                                unsigned short* __restrict__ h0l, int N) {
  int wid = threadIdx.x >> 6;
  int lane = threadIdx.x & 63;
  int n = blockIdx.x * 4 + wid;
  if (n >= N) return;
  int s = row_start[n], e = row_start[n + 1];
  float a0 = 0.f, a1 = 0.f;
  int i = s;
  for (; i + 7 < e; i += 8) {
    unsigned v0 = yI[(size_t)csr_src[i] * 64 + lane];
    unsigned v1 = yI[(size_t)csr_src[i + 1] * 64 + lane];
    unsigned v2 = yI[(size_t)csr_src[i + 2] * 64 + lane];
    unsigned v3 = yI[(size_t)csr_src[i + 3] * 64 + lane];
    unsigned v4 = yI[(size_t)csr_src[i + 4] * 64 + lane];
    unsigned v5 = yI[(size_t)csr_src[i + 5] * 64 + lane];
    unsigned v6 = yI[(size_t)csr_src[i + 6] * 64 + lane];
    unsigned v7 = yI[(size_t)csr_src[i + 7] * 64 + lane];
    float2 f0 = unpk(v0), f1 = unpk(v1), f2 = unpk(v2), f3 = unpk(v3);
    float2 f4 = unpk(v4), f5 = unpk(v5), f6 = unpk(v6), f7 = unpk(v7);
    a0 += f0.x + f1.x + f2.x + f3.x + f4.x + f5.x + f6.x + f7.x;
    a1 += f0.y + f1.y + f2.y + f3.y + f4.y + f5.y + f6.y + f7.y;
  }
  for (; i < e; ++i) {
    float2 f = unpk(yI[(size_t)csr_src[i] * 64 + lane]);
    a0 += f.x;
    a1 += f.y;
  }
  float inv = 1.0f / fmaxf((float)(e - s), 1.0f);
  size_t base = (size_t)n * 128;
  float v0 = elu_f(z[base + lane] + a0 * inv + b[lane]);
  float v1 = elu_f(z[base + 64 + lane] + a1 * inv + b[64 + lane]);
  unsigned short hh0 = f2bf(v0), hh1 = f2bf(v1);
  h0h[base + lane] = hh0;
  h0l[base + lane] = f2bf(v0 - bf2f(hh0));
  h0h[base + 64 + lane] = hh1;
  h0l[base + 64 + lane] = f2bf(v1 - bf2f(hh1));
}

// ---------------- per-node attention logits (layer 1) ----------------------
__global__ __launch_bounds__(256) void elr1_kernel(const unsigned* __restrict__ featI,
                                                   const float* __restrict__ al,
                                                   const float* __restrict__ ar,
                                                   float2* __restrict__ el,
                                                   float2* __restrict__ er, int N) {
  int wid = threadIdx.x >> 6;
  int lane = threadIdx.x & 63;
  int n = blockIdx.x * 4 + wid;
  if (n >= N) return;
  float2 f = unpk(featI[(size_t)n * 64 + lane]);
  float e0 = wave_sum(f.x * al[lane]);
  float e1 = wave_sum(f.y * al[64 + lane]);
  float r0 = wave_sum(f.x * ar[lane]);
  float r1 = wave_sum(f.y * ar[64 + lane]);
  if (lane == 0) {
    el[n] = make_float2(e0, e1);
    er[n] = make_float2(r0, r1);
  }
}

// ---------------- fused GAT layer 1: softmax + aggregation (wave/node) -----
// Windowed (256-edge) wave-parallel online softmax with CHUNK SKIP:
// only chunks with c*64 < nv execute. (p0,p1,u) parked in wave-private LDS;
// phase2 uniform ds_read broadcast + 8-wide gather-fma.
__global__ __launch_bounds__(256) void gat1_agg(const unsigned* __restrict__ featI,
                                                const float2* __restrict__ el,
                                                const float2* __restrict__ er,
                                                const int* __restrict__ row_start,
                                                const unsigned short* __restrict__ csr_src,
                                                const float* __restrict__ b,
                                                unsigned short* __restrict__ h1h,
                                                unsigned short* __restrict__ h1l, int N) {
  __shared__ float4 pbuf[4][256];
  int wid = threadIdx.x >> 6;
  int lane = threadIdx.x & 63;
  int n = blockIdx.x * 4 + wid;
  if (n >= N) return;
  int beg = row_start[n], end = row_start[n + 1];
  float2 ern = er[n];
  float m0 = -INFINITY, m1 = -INFINITY;
  float s0 = 0.f, s1 = 0.f, a0 = 0.f, a1 = 0.f;
  for (int w = beg; w < end; w += 256) {
    int nv = min(end - w, 256);
    float e0c[4], e1c[4];
    unsigned uc[4];
    float wm0 = -INFINITY, wm1 = -INFINITY;
#pragma unroll
    for (int c = 0; c < 4; ++c) {
      if (c * 64 < nv) {
        int i = w + c * 64 + lane;
        bool v = (c * 64 + lane < nv);
        unsigned u = v ? (unsigned)csr_src[i] : 0u;
        float2 l = el[u];
        float e0 = l.x + ern.x;
        e0 = e0 > 0.f ? e0 : 0.2f * e0;
        float e1 = l.y + ern.y;
        e1 = e1 > 0.f ? e1 : 0.2f * e1;
        if (!v) {
          e0 = -INFINITY;
          e1 = -INFINITY;
        }
        uc[c] = u;
        e0c[c] = e0;
        e1c[c] = e1;
        wm0 = fmaxf(wm0, e0);
        wm1 = fmaxf(wm1, e1);
      }
    }
#pragma unroll
    for (int o = 32; o > 0; o >>= 1) {
      wm0 = fmaxf(wm0, __shfl_xor(wm0, o, 64));
      wm1 = fmaxf(wm1, __shfl_xor(wm1, o, 64));
    }
    float nm0 = fmaxf(m0, wm0), nm1 = fmaxf(m1, wm1);
    float sc0 = __expf(m0 - nm0);  // first window: exp(-inf)=0, a/s were 0
    float sc1 = __expf(m1 - nm1);
    float ls0 = 0.f, ls1 = 0.f;
#pragma unroll
    for (int c = 0; c < 4; ++c) {
      if (c * 64 < nv) {
        float p0 = __expf(e0c[c] - nm0);  // invalid: exp(-inf)=0
        float p1 = __expf(e1c[c] - nm1);
        ls0 += p0;
        ls1 += p1;
        pbuf[wid][c * 64 + lane] = make_float4(p0, p1, __uint_as_float(uc[c]), 0.f);
      }
    }
    ls0 = wave_sum(ls0);
    ls1 = wave_sum(ls1);
    s0 = s0 * sc0 + ls0;
    s1 = s1 * sc1 + ls1;
    a0 *= sc0;
    a1 *= sc1;
    m0 = nm0;
    m1 = nm1;
    // phase 2: 8-wide gather-fma; entries >= nv in executed chunks have p=0
    for (int j = 0; j < nv; j += 8) {
      float4 q0 = pbuf[wid][j + 0];
      float4 q1 = pbuf[wid][j + 1];
      float4 q2 = pbuf[wid][j + 2];
      float4 q3 = pbuf[wid][j + 3];
      float4 q4 = pbuf[wid][j + 4];
      float4 q5 = pbuf[wid][j + 5];
      float4 q6 = pbuf[wid][j + 6];
      float4 q7 = pbuf[wid][j + 7];
      unsigned x0 = featI[(size_t)__float_as_uint(q0.z) * 64 + lane];
      unsigned x1 = featI[(size_t)__float_as_uint(q1.z) * 64 + lane];
      unsigned x2 = featI[(size_t)__float_as_uint(q2.z) * 64 + lane];
      unsigned x3 = featI[(size_t)__float_as_uint(q3.z) * 64 + lane];
      unsigned x4 = featI[(size_t)__float_as_uint(q4.z) * 64 + lane];
      unsigned x5 = featI[(size_t)__float_as_uint(q5.z) * 64 + lane];
      unsigned x6 = featI[(size_t)__float_as_uint(q6.z) * 64 + lane];
      unsigned x7 = featI[(size_t)__float_as_uint(q7.z) * 64 + lane];
      float2 f0 = unpk(x0), f1 = unpk(x1), f2 = unpk(x2), f3 = unpk(x3);
      float2 f4 = unpk(x4), f5 = unpk(x5), f6 = unpk(x6), f7 = unpk(x7);
      a0 = fmaf(q0.x, f0.x, a0); a1 = fmaf(q0.y, f0.y, a1);
      a0 = fmaf(q1.x, f1.x, a0); a1 = fmaf(q1.y, f1.y, a1);
      a0 = fmaf(q2.x, f2.x, a0); a1 = fmaf(q2.y, f2.y, a1);
      a0 = fmaf(q3.x, f3.x, a0); a1 = fmaf(q3.y, f3.y, a1);
      a0 = fmaf(q4.x, f4.x, a0); a1 = fmaf(q4.y, f4.y, a1);
      a0 = fmaf(q5.x, f5.x, a0); a1 = fmaf(q5.y, f5.y, a1);
      a0 = fmaf(q6.x, f6.x, a0); a1 = fmaf(q6.y, f6.y, a1);
      a0 = fmaf(q7.x, f7.x, a0); a1 = fmaf(q7.y, f7.y, a1);
    }
  }
  float inv0 = 1.0f / fmaxf(s0, 1e-9f);
  float inv1 = 1.0f / fmaxf(s1, 1e-9f);
  float o0 = elu_f(a0 * inv0 + b[lane]);
  float o1 = elu_f(a1 * inv1 + b[64 + lane]);
  size_t base = (size_t)n * 128;
  unsigned short hh0 = f2bf(o0), hh1 = f2bf(o1);
  h1h[base + lane] = hh0;
  h1l[base + lane] = f2bf(o0 - bf2f(hh0));
  h1h[base + 64 + lane] = hh1;
  h1l[base + 64 + lane] = f2bf(o1 - bf2f(hh1));
}

// ---------------- per-node attention logits (layer 2) ----------------------
__global__ __launch_bounds__(256) void elr2_kernel(const unsigned short* __restrict__ feat,  // bf16 ld48
                                                   const float* __restrict__ al,
                                                   const float* __restrict__ ar,
                                                   float* __restrict__ el,
                                                   float* __restrict__ er, int N) {
  int wid = threadIdx.x >> 6;
  int lane = threadIdx.x & 63;
  int n = blockIdx.x * 4 + wid;
  if (n >= N) return;
  float f = 0.f, a = 0.f, r = 0.f;
  if (lane < 47) {
    f = bf2f(feat[(size_t)n * 48 + lane]);
    a = al[lane];
    r = ar[lane];
  }
  float e = wave_sum(f * a);
  float rr = wave_sum(f * r);
  if (lane == 0) {
    el[n] = e;
    er[n] = rr;
  }
}

// ---------------- fused GAT layer 2: softmax + aggregation -> d_out --------
__global__ __launch_bounds__(256) void gat2_agg(const unsigned short* __restrict__ feat,  // bf16 ld48
                                                const float* __restrict__ el,
                                                const float* __restrict__ er,
                                                const int* __restrict__ row_start,
                                                const unsigned short* __restrict__ csr_src,
                                                const float* __restrict__ b,
                                                float* __restrict__ out, int N) {
  __shared__ float2 pbuf[4][256];
  int wid = threadIdx.x >> 6;
  int lane = threadIdx.x & 63;
  int n = blockIdx.x * 4 + wid;
  if (n >= N) return;
  int beg = row_start[n], end = row_start[n + 1];
  float ern = er[n];
  int lidx = lane < 47 ? lane : 0;
  float m = -INFINITY, s = 0.f, acc = 0.f;
  for (int w = beg; w < end; w += 256) {
    int nv = min(end - w, 256);
    float ec[4];
    unsigned uc[4];
    float wm = -INFINITY;
#pragma unroll
    for (int c = 0; c < 4; ++c) {
      if (c * 64 < nv) {
        int i = w + c * 64 + lane;
        bool v = (c * 64 + lane < nv);
        unsigned u = v ? (unsigned)csr_src[i] : 0u;
        float e = el[u] + ern;
        e = e > 0.f ? e : 0.2f * e;
        if (!v) e = -INFINITY;
        uc[c] = u;
        ec[c] = e;
        wm = fmaxf(wm, e);
      }
    }
#pragma unroll
    for (int o = 32; o > 0; o >>= 1) wm = fmaxf(wm, __shfl_xor(wm, o, 64));
    float nm = fmaxf(m, wm);
    float sc = __expf(m - nm);
    float ls = 0.f;
#pragma unroll
    for (int c = 0; c < 4; ++c) {
      if (c * 64 < nv) {
        float p = __expf(ec[c] - nm);
        ls += p;
        pbuf[wid][c * 64 + lane] = make_float2(p, __uint_as_float(uc[c]));
      }
    }
    ls = wave_sum(ls);
    s = s * sc + ls;
    acc *= sc;
    m = nm;
    for (int j = 0; j < nv; j += 8) {
      float2 q0 = pbuf[wid][j + 0];
      float2 q1 = pbuf[wid][j + 1];
      float2 q2 = pbuf[wid][j + 2];
      float2 q3 = pbuf[wid][j + 3];
      float2 q4 = pbuf[wid][j + 4];
      float2 q5 = pbuf[wid][j + 5];
      float2 q6 = pbuf[wid][j + 6];
      float2 q7 = pbuf[wid][j + 7];
      float g0 = bf2f(feat[(size_t)__float_as_uint(q0.y) * 48 + lidx]);
      float g1 = bf2f(feat[(size_t)__float_as_uint(q1.y) * 48 + lidx]);
      float g2 = bf2f(feat[(size_t)__float_as_uint(q2.y) * 48 + lidx]);
      float g3 = bf2f(feat[(size_t)__float_as_uint(q3.y) * 48 + lidx]);
      float g4 = bf2f(feat[(size_t)__float_as_uint(q4.y) * 48 + lidx]);
      float g5 = bf2f(feat[(size_t)__float_as_uint(q5.y) * 48 + lidx]);
      float g6 = bf2f(feat[(size_t)__float_as_uint(q6.y) * 48 + lidx]);
      float g7 = bf2f(feat[(size_t)__float_as_uint(q7.y) * 48 + lidx]);
      acc = fmaf(q0.x, g0, acc);
      acc = fmaf(q1.x, g1, acc);
      acc = fmaf(q2.x, g2, acc);
      acc = fmaf(q3.x, g3, acc);
      acc = fmaf(q4.x, g4, acc);
      acc = fmaf(q5.x, g5, acc);
      acc = fmaf(q6.x, g6, acc);
      acc = fmaf(q7.x, g7, acc);
    }
  }
  if (lane < 47) {
    out[(size_t)n * 47 + lane] = acc / fmaxf(s, 1e-9f) + b[lane];
  }
}

// ---------------------------------------------------------------------------
extern "C" void kernel_launch(void* const* d_in, const int* in_sizes, int n_in,
                              void* d_out, int out_size, void* d_ws, size_t ws_size,
                              hipStream_t stream) {
  const float* x = (const float*)d_in[0];
  const int* src = (const int*)d_in[1];
  const int* dst = (const int*)d_in[2];
  const float* sage_w_self = (const float*)d_in[3];
  const float* sage_w_neigh = (const float*)d_in[4];
  const float* sage_b = (const float*)d_in[5];
  const float* gat1_w = (const float*)d_in[6];
  const float* gat1_al = (const float*)d_in[7];
  const float* gat1_ar = (const float*)d_in[8];
  const float* gat1_b = (const float*)d_in[9];
  const float* gat2_w = (const float*)d_in[10];
  const float* gat2_al = (const float*)d_in[11];
  const float* gat2_ar = (const float*)d_in[12];
  const float* gat2_b = (const float*)d_in[13];
  float* out = (float*)d_out;

  const int N = in_sizes[0] / 256;
  const int E = in_sizes[1];

  char* ws = (char*)d_ws;
  size_t off = 0;
  auto alloc = [&](size_t bytes) {
    size_t o = off;
    off += (bytes + 255) & ~(size_t)255;
    return o;
  };
  int* deg_i = (int*)(ws + alloc((size_t)N * 4));
  int* row_start = (int*)(ws + alloc((size_t)(N + 1) * 4));
  int* cursor = (int*)(ws + alloc((size_t)N * 4));
  unsigned short* csr_src = (unsigned short*)(ws + alloc((size_t)E * 2));
  int* psum = (int*)(ws + alloc(((size_t)N / 1024 + 2) * 4));
  float* bufA = (float*)(ws + alloc((size_t)N * 128 * 4));       // z
  unsigned* bufG = (unsigned*)(ws + alloc((size_t)N * 64 * 4));  // yI -> feat1I -> feat2b
  unsigned short* bufX = (unsigned short*)(ws + alloc((size_t)N * 256 * 2 * 2));  // xh|xl
  unsigned short* wt_sh = (unsigned short*)(ws + alloc(128 * 256 * 2));
  unsigned short* wt_sl = (unsigned short*)(ws + alloc(128 * 256 * 2));
  unsigned short* wt_nh = (unsigned short*)(ws + alloc(128 * 256 * 2));
  unsigned short* wt_nl = (unsigned short*)(ws + alloc(128 * 256 * 2));
  unsigned short* wt_1h = (unsigned short*)(ws + alloc(128 * 128 * 2));
  unsigned short* wt_1l = (unsigned short*)(ws + alloc(128 * 128 * 2));
  unsigned short* wt_2h = (unsigned short*)(ws + alloc(48 * 128 * 2));
  unsigned short* wt_2l = (unsigned short*)(ws + alloc(48 * 128 * 2));
  float2* el1 = (float2*)(ws + alloc((size_t)N * 8));
  float2* er1 = (float2*)(ws + alloc((size_t)N * 8));
  float* el2 = (float*)(ws + alloc((size_t)N * 4));
  float* er2 = (float*)(ws + alloc((size_t)N * 4));
  (void)ws_size;
  (void)n_in;
  (void)out_size;

  // lifetimes:
  unsigned short* xh = (unsigned short*)bufX;       // dead after L0 gemm
  unsigned short* xl = bufX + (size_t)N * 256;      // dead after L0 gemm
  float* z = bufA;                                  // dead after sage_agg
  unsigned* yI = bufG;                              // dead after sage_agg
  unsigned short* h0h = bufX;                       // reuse xh region
  unsigned short* h0l = bufX + (size_t)N * 128;
  unsigned* feat1I = bufG;                          // reuse yI; dead after gat1_agg
  unsigned short* h1h = bufX + (size_t)N * 256;     // reuse xl region
  unsigned short* h1l = bufX + (size_t)N * 256 + (size_t)N * 128;
  unsigned short* feat2b = (unsigned short*)bufG;   // reuse feat1I

  hipMemsetAsync(deg_i, 0, (size_t)N * 4, stream);

  const int eb = (E + 255) / 256;
  const int eb2 = (E + 511) / 512;
  const int nb4 = (N + 3) / 4;
  const int gx = (N + 127) / 128;
  const int PB = (N + 1023) / 1024;

  split_x<<<2048, 256, 0, stream>>>(x, xh, xl, N * 64);
  prep_w<<<(128 * 256 + 255) / 256, 256, 0, stream>>>(sage_w_self, 128, 256, 128, wt_sh, wt_sl);
  prep_w<<<(128 * 256 + 255) / 256, 256, 0, stream>>>(sage_w_neigh, 128, 256, 128, wt_nh, wt_nl);
  prep_w<<<(128 * 128 + 255) / 256, 256, 0, stream>>>(gat1_w, 128, 128, 128, wt_1h, wt_1l);
  prep_w<<<(48 * 128 + 255) / 256, 256, 0, stream>>>(gat2_w, 47, 128, 48, wt_2h, wt_2l);

  deg_kernel<<<eb, 256, 0, stream>>>(dst, deg_i, E);
  scan_partial<<<PB, 256, 0, stream>>>(deg_i, psum, N);
  scan_psum<<<1, 64, 0, stream>>>(psum, PB);
  scan_final<<<PB, 256, 0, stream>>>(deg_i, psum, row_start, N, E);
  hipMemcpyAsync(cursor, row_start, (size_t)N * 4, hipMemcpyDeviceToDevice, stream);
  scatter_kernel<<<eb2, 256, 0, stream>>>(src, dst, cursor, csr_src, E);

  // layer 0: y=0 -> z = x@W_self (f32, ldc=128 floats),
  //          y=1 -> yI = x@W_neigh (packed bf16 ilv, ldu=64 uints)
  {
    dim3 grid(gx, 2);
    gemm_mfma<256, 8><<<grid, 256, 0, stream>>>(xh, xl, wt_sh, wt_sl, wt_nh, wt_nl,
                                                z, yI, 128, N, 128, 0, 1);
  }
  sage_agg<<<nb4, 256, 0, stream>>>(z, yI, row_start, csr_src, sage_b, h0h, h0l, N);

  // GAT layer 1: feat1I = h0 @ gat1_w (packed bf16 ilv, ldc=128 -> ldu=64 uints)
  {
    dim3 grid(gx, 1);
    gemm_mfma<128, 8><<<grid, 256, 0, stream>>>(h0h, h0l, wt_1h, wt_1l, wt_1h, wt_1l,
                                                feat1I, feat1I, 128, N, 128, 1, 1);
  }
  elr1_kernel<<<nb4, 256, 0, stream>>>(feat1I, gat1_al, gat1_ar, el1, er1, N);
  gat1_agg<<<nb4, 256, 0, stream>>>(feat1I, el1, er1, row_start, csr_src, gat1_b,
                                    h1h, h1l, N);

  // GAT layer 2: feat2b = h1 @ gat2_w (bf16 std, ldc=48 ushorts)
  {
    dim3 grid(gx, 1);
    gemm_mfma<128, 3><<<grid, 256, 0, stream>>>(h1h, h1l, wt_2h, wt_2l, wt_2h, wt_2l,
                                                feat2b, feat2b, 48, N, 47, 2, 2);
  }
  elr2_kernel<<<nb4, 256, 0, stream>>>(feat2b, gat2_al, gat2_ar, el2, er2, N);
  gat2_agg<<<nb4, 256, 0, stream>>>(feat2b, el2, er2, row_start, csr_src, gat2_b, out, N);
}

// Round 16
// 301.075 us; speedup vs baseline: 1.3260x; 1.0543x over previous
//
#include <hip/hip_runtime.h>

// ---------------------------------------------------------------------------
// GAT_4733053960619: SAGEConv(mean) -> ELU -> GAT(2 heads,64) -> ELU -> GAT(1,47)
// N=50000, E=800000, IN_FEATS=256. All fp32.
//
// R15 = R14 with split_x DELETED: the L0 GEMM reads x (f32) directly and does
// the bf16 hi/lo split in-register (AF32 template path; same bytes/lane as
// the pre-split load, ~96 extra VALU ops/kt hidden under MFMA). Removes a
// 102 MB HBM round-trip + one dispatch. Bit-identical math.
// ---------------------------------------------------------------------------

typedef __attribute__((ext_vector_type(8))) short bf16x8;
typedef __attribute__((ext_vector_type(4))) float f32x4;

__device__ __forceinline__ float wave_sum(float v) {
#pragma unroll
  for (int o = 32; o > 0; o >>= 1) v += __shfl_xor(v, o, 64);
  return v;
}

__device__ __forceinline__ int wave_sum_i(int v) {
#pragma unroll
  for (int o = 32; o > 0; o >>= 1) v += __shfl_xor(v, o, 64);
  return v;
}

__device__ __forceinline__ float elu_f(float v) {
  return v > 0.f ? v : __expf(v) - 1.0f;
}

__device__ __forceinline__ unsigned short f2bf(float x) {
  union { float f; unsigned u; } v;
  v.f = x;
  unsigned r = v.u + 0x7FFFu + ((v.u >> 16) & 1u);
  return (unsigned short)(r >> 16);
}

__device__ __forceinline__ float bf2f(unsigned short h) {
  union { unsigned u; float f; } v;
  v.u = ((unsigned)h) << 16;
  return v.f;
}

// packed 2xbf16 (lo=head0, hi=head1) -> (f0, f1)
__device__ __forceinline__ float2 unpk(unsigned v) {
  union { unsigned u; float f; } a, b;
  a.u = v << 16;
  b.u = v & 0xFFFF0000u;
  return make_float2(a.f, b.f);
}

struct bfpair {
  bf16x8 h, l;
};

// load 8 consecutive f32 and split to bf16 hi/lo in-register
__device__ __forceinline__ bfpair cvt8(const float* __restrict__ p) {
  float4 a = *(const float4*)p;
  float4 b = *(const float4*)(p + 4);
  float v[8] = {a.x, a.y, a.z, a.w, b.x, b.y, b.z, b.w};
  bfpair r;
#pragma unroll
  for (int j = 0; j < 8; ++j) {
    unsigned short hh = f2bf(v[j]);
    r.h[j] = (short)hh;
    r.l[j] = (short)f2bf(v[j] - bf2f(hh));
  }
  return r;
}

// ---------------- CSR build ----------------
__global__ __launch_bounds__(256) void deg_kernel(const int* __restrict__ dst,
                                                  int* __restrict__ deg, int E) {
  int i = blockIdx.x * 256 + threadIdx.x;
  if (i < E) atomicAdd(&deg[dst[i]], 1);
}

// phase 1: per-1024-chunk sums
__global__ __launch_bounds__(256) void scan_partial(const int* __restrict__ deg,
                                                    int* __restrict__ psum, int n) {
  __shared__ int red[4];
  const int t = threadIdx.x;
  const int base = blockIdx.x * 1024;
  int s = 0;
#pragma unroll
  for (int j = 0; j < 4; ++j) {
    int idx = base + t + j * 256;
    s += (idx < n) ? deg[idx] : 0;
  }
  s = wave_sum_i(s);
  const int lane = t & 63, w = t >> 6;
  if (lane == 0) red[w] = s;
  __syncthreads();
  if (t == 0) psum[blockIdx.x] = red[0] + red[1] + red[2] + red[3];
}

// phase 2: exclusive scan of partials (single wave, carry loop)
__global__ __launch_bounds__(64) void scan_psum(int* __restrict__ psum, int PB) {
  const int lane = threadIdx.x;
  int carry = 0;
  for (int base = 0; base < PB; base += 64) {
    int v = (base + lane < PB) ? psum[base + lane] : 0;
    int inc = v;
#pragma unroll
    for (int o = 1; o < 64; o <<= 1) {
      int u = __shfl_up(inc, o, 64);
      if (lane >= o) inc += u;
    }
    if (base + lane < PB) psum[base + lane] = carry + inc - v;
    carry += __shfl(inc, 63, 64);
  }
}

// phase 3: per-chunk exclusive scan + block offset -> row_start
__global__ __launch_bounds__(256) void scan_final(const int* __restrict__ deg,
                                                  const int* __restrict__ psum,
                                                  int* __restrict__ row_start,
                                                  int n, int E) {
  __shared__ int woff[4];
  const int t = threadIdx.x;
  const int lane = t & 63, w = t >> 6;
  const int base = blockIdx.x * 1024 + t * 4;
  int d0 = (base + 0 < n) ? deg[base + 0] : 0;
  int d1 = (base + 1 < n) ? deg[base + 1] : 0;
  int d2 = (base + 2 < n) ? deg[base + 2] : 0;
  int d3 = (base + 3 < n) ? deg[base + 3] : 0;
  int l0 = d0, l1 = l0 + d1, l2 = l1 + d2, l3 = l2 + d3;
  int inc = l3;
#pragma unroll
  for (int o = 1; o < 64; o <<= 1) {
    int u = __shfl_up(inc, o, 64);
    if (lane >= o) inc += u;
  }
  int texc = inc - l3;  // exclusive within wave
  if (lane == 63) woff[w] = inc;
  __syncthreads();
  int wo = 0;
  if (w == 0 && lane < 4) {
    int s = woff[lane];
    int p = s;
#pragma unroll
    for (int o = 1; o < 4; o <<= 1) {
      int u = __shfl_up(p, o, 64);
      if (lane >= o) p += u;
    }
    woff[lane] = p - s;  // exclusive wave offsets
  }
  __syncthreads();
  wo = woff[w];
  const int boff = psum[blockIdx.x] + wo + texc;
  if (base + 0 < n) row_start[base + 0] = boff;
  if (base + 1 < n) row_start[base + 1] = boff + l0;
  if (base + 2 < n) row_start[base + 2] = boff + l1;
  if (base + 3 < n) row_start[base + 3] = boff + l2;
  if (blockIdx.x == 0 && t == 0) row_start[n] = E;
}

// cursor pre-filled with row_start; atomicAdd -> absolute slot; plain ushort
// store (src ids fit 16 bits since N < 65536).
__global__ __launch_bounds__(256) void scatter_kernel(const int* __restrict__ src,
                                                      const int* __restrict__ dst,
                                                      int* __restrict__ cursor,
                                                      unsigned short* __restrict__ csr_src,
                                                      int E) {
  int i = blockIdx.x * 512 + threadIdx.x;
  int i2 = i + 256;
  int d0 = (i < E) ? dst[i] : 0;
  int d1 = (i2 < E) ? dst[i2] : 0;
  int s0 = (i < E) ? src[i] : 0;
  int s1 = (i2 < E) ? src[i2] : 0;
  int p0 = 0, p1 = 0;
  if (i < E) p0 = atomicAdd(&cursor[d0], 1);
  if (i2 < E) p1 = atomicAdd(&cursor[d1], 1);
  if (i < E) csr_src[p0] = (unsigned short)s0;
  if (i2 < E) csr_src[p1] = (unsigned short)s1;
}

// ---------------- weight prep: W[K][N] f32 -> W^T hi/lo [Npad][K] bf16 ------
__global__ __launch_bounds__(256) void prep_w(const float* __restrict__ W, int N, int K,
                                              int Npad, unsigned short* __restrict__ th,
                                              unsigned short* __restrict__ tl) {
  int i = blockIdx.x * 256 + threadIdx.x;
  if (i >= Npad * K) return;
  int n = i / K, k = i - n * K;
  float v = (n < N) ? W[(size_t)k * N + n] : 0.f;
  unsigned short h = f2bf(v);
  th[i] = h;
  tl[i] = f2bf(v - bf2f(h));
}

// ---------------- MFMA GEMM: C = A @ B, split-bf16, LDS-staged B ----------
// A: if AF32, raw f32 [M][K] split to hi/lo in-register; else pre-split
// hi/lo bf16 (Av=hi, Al=lo). B^T as hi/lo bf16 [Npad][K]; Npad = NT*16.
// Block = 4 waves = 128 rows; wave = 32 rows (2 fragments) x NT*16 cols.
// omode: 0 = f32 std (ldc floats); 1 = packed-bf16 head-interleave, uint
// stride ldu = ldc>>1; 2 = bf16 std (ldc ushorts).
template <int K, int NT, int AF32>
__global__ __launch_bounds__(256) void gemm_mfma(
    const void* __restrict__ Av, const unsigned short* __restrict__ Al,
    const unsigned short* __restrict__ BTh0, const unsigned short* __restrict__ BTl0,
    const unsigned short* __restrict__ BTh1, const unsigned short* __restrict__ BTl1,
    void* __restrict__ C0, void* __restrict__ C1,
    int ldc, int M, int Ncols, int omode0, int omode1) {
  constexpr int K2 = K * 2;    // bytes per B^T row
  constexpr int NKT = K / 32;  // k-tiles
  __shared__ unsigned short Bs[2][2][NT * 512];  // [buf][hi/lo][nt*512 + kg*128 + lrow*8]

  const unsigned short* BTh = blockIdx.y ? BTh1 : BTh0;
  const unsigned short* BTl = blockIdx.y ? BTl1 : BTl0;
  void* Cv = blockIdx.y ? C1 : C0;
  const int omode = blockIdx.y ? omode1 : omode0;

  const int wid = threadIdx.x >> 6;
  const int lane = threadIdx.x & 63;
  const int lrow = lane & 15;
  const int kg = lane >> 4;
  const int row0 = blockIdx.x * 128 + wid * 32;
  const int ra = min(row0 + lrow, M - 1);
  const int rb = min(row0 + 16 + lrow, M - 1);
  const size_t aoffA = (size_t)ra * K + kg * 8;
  const size_t aoffB = (size_t)rb * K + kg * 8;

  const float* Af = (const float*)Av;
  const unsigned short* Ah = (const unsigned short*)Av;

  auto loadA = [&](size_t off) -> bfpair {
    if constexpr (AF32) {
      return cvt8(Af + off);
    } else {
      bfpair r;
      r.h = *(const bf16x8*)(Ah + off);
      r.l = *(const bf16x8*)(Al + off);
      return r;
    }
  };

  auto stage = [&](int buf, int kt) {
    for (int j = wid; j < 2 * NT; j += 4) {
      const int h = (j >= NT) ? 1 : 0;
      const int nt = h ? j - NT : j;
      const unsigned short* src = h ? BTl : BTh;
      const char* g = (const char*)src + (size_t)(nt * 16 + lrow) * K2 + kt * 64 + kg * 16;
      unsigned short* l = &Bs[buf][h][nt * 512];
      __builtin_amdgcn_global_load_lds(
          (const __attribute__((address_space(1))) unsigned*)g,
          (__attribute__((address_space(3))) unsigned*)l, 16, 0, 0);
    }
  };

  f32x4 accA[NT] = {};
  f32x4 accB[NT] = {};

  stage(0, 0);
  bfpair cA = loadA(aoffA);
  bfpair cB = loadA(aoffB);

  for (int kt = 0; kt < NKT; ++kt) {
    __syncthreads();  // buf[kt&1] staged
    if (kt + 1 < NKT) stage((kt + 1) & 1, kt + 1);
    const int kn = (kt + 1 < NKT) ? (kt + 1) * 32 : kt * 32;
    bfpair nA = loadA(aoffA + kn);
    bfpair nB = loadA(aoffB + kn);
    const int buf = kt & 1;
#pragma unroll
    for (int nt = 0; nt < NT; ++nt) {
      bf16x8 bh = ((const bf16x8*)&Bs[buf][0][nt * 512])[lane];
      bf16x8 bl = ((const bf16x8*)&Bs[buf][1][nt * 512])[lane];
      accA[nt] = __builtin_amdgcn_mfma_f32_16x16x32_bf16(cA.h, bh, accA[nt], 0, 0, 0);
      accA[nt] = __builtin_amdgcn_mfma_f32_16x16x32_bf16(cA.h, bl, accA[nt], 0, 0, 0);
      accA[nt] = __builtin_amdgcn_mfma_f32_16x16x32_bf16(cA.l, bh, accA[nt], 0, 0, 0);
      accB[nt] = __builtin_amdgcn_mfma_f32_16x16x32_bf16(cB.h, bh, accB[nt], 0, 0, 0);
      accB[nt] = __builtin_amdgcn_mfma_f32_16x16x32_bf16(cB.h, bl, accB[nt], 0, 0, 0);
      accB[nt] = __builtin_amdgcn_mfma_f32_16x16x32_bf16(cB.l, bh, accB[nt], 0, 0, 0);
    }
    cA = nA;
    cB = nB;
  }

  if (omode == 1) {
    // packed-bf16 head-interleave: uint stride = ldc/2
    unsigned* Cu = (unsigned*)Cv;
    const int ldu = ldc >> 1;
#pragma unroll
    for (int nt = 0; nt < NT / 2; ++nt) {
      int d = nt * 16 + lrow;
#pragma unroll
      for (int r = 0; r < 4; ++r) {
        int g0 = row0 + kg * 4 + r;
        if (g0 < M) {
          unsigned p = (unsigned)f2bf(accA[nt][r]) |
                       ((unsigned)f2bf(accA[nt + NT / 2][r]) << 16);
          Cu[(size_t)g0 * ldu + d] = p;
        }
        int g1 = row0 + 16 + kg * 4 + r;
        if (g1 < M) {
          unsigned p = (unsigned)f2bf(accB[nt][r]) |
                       ((unsigned)f2bf(accB[nt + NT / 2][r]) << 16);
          Cu[(size_t)g1 * ldu + d] = p;
        }
      }
    }
  } else if (omode == 2) {
    unsigned short* Cs = (unsigned short*)Cv;
#pragma unroll
    for (int nt = 0; nt < NT; ++nt) {
      int gc = nt * 16 + lrow;
      if (gc >= Ncols) continue;
#pragma unroll
      for (int r = 0; r < 4; ++r) {
        int g0 = row0 + kg * 4 + r;
        if (g0 < M) Cs[(size_t)g0 * ldc + gc] = f2bf(accA[nt][r]);
        int g1 = row0 + 16 + kg * 4 + r;
        if (g1 < M) Cs[(size_t)g1 * ldc + gc] = f2bf(accB[nt][r]);
      }
    }
  } else {
    float* C = (float*)Cv;
#pragma unroll
    for (int nt = 0; nt < NT; ++nt) {
      int gc = nt * 16 + lrow;
      if (gc >= Ncols) continue;
#pragma unroll
      for (int r = 0; r < 4; ++r) {
        int g0 = row0 + kg * 4 + r;
        if (g0 < M) C[(size_t)g0 * ldc + gc] = accA[nt][r];
        int g1 = row0 + 16 + kg * 4 + r;
        if (g1 < M) C[(size_t)g1 * ldc + gc] = accB[nt][r];
      }
    }
  }
}

// ---------------- SAGE aggregation (wave per node) -> h0 bf16 hi/lo --------
// yI: packed 2xbf16 per (node, d) uint. 8-wide unrolled gathers (MLP).
__global__ __launch_bounds__(256) void sage_agg(const float* __restrict__ z,
                                                const unsigned* __restrict__ yI,
                                                const int* __restrict__ row_start,
                                                const unsigned short* __restrict__ csr_src,
                                                const float* __restrict__ b,
                                                unsigned short* __restrict__ h0h,
                                                unsigned short* __restrict__ h0l, int N) {
  int wid = threadIdx.x >> 6;
  int lane = threadIdx.x & 63;
  int n = blockIdx.x * 4 + wid;
  if (n >= N) return;
  int s = row_start[n], e = row_start[n + 1];
  float a0 = 0.f, a1 = 0.f;
  int i = s;
  for (; i + 7 < e; i += 8) {
    unsigned v0 = yI[(size_t)csr_src[i] * 64 + lane];
    unsigned v1 = yI[(size_t)csr_src[i + 1] * 64 + lane];
    unsigned v2 = yI[(size_t)csr_src[i + 2] * 64 + lane];
    unsigned v3 = yI[(size_t)csr_src[i + 3] * 64 + lane];
    unsigned v4 = yI[(size_t)csr_src[i + 4] * 64 + lane];
    unsigned v5 = yI[(size_t)csr_src[i + 5] * 64 + lane];
    unsigned v6 = yI[(size_t)csr_src[i + 6] * 64 + lane];
    unsigned v7 = yI[(size_t)csr_src[i + 7] * 64 + lane];
    float2 f0 = unpk(v0), f1 = unpk(v1), f2 = unpk(v2), f3 = unpk(v3);
    float2 f4 = unpk(v4), f5 = unpk(v5), f6 = unpk(v6), f7 = unpk(v7);
    a0 += f0.x + f1.x + f2.x + f3.x + f4.x + f5.x + f6.x + f7.x;
    a1 += f0.y + f1.y + f2.y + f3.y + f4.y + f5.y + f6.y + f7.y;
  }
  for (; i < e; ++i) {
    float2 f = unpk(yI[(size_t)csr_src[i] * 64 + lane]);
    a0 += f.x;
    a1 += f.y;
  }
  float inv = 1.0f / fmaxf((float)(e - s), 1.0f);
  size_t base = (size_t)n * 128;
  float v0 = elu_f(z[base + lane] + a0 * inv + b[lane]);
  float v1 = elu_f(z[base + 64 + lane] + a1 * inv + b[64 + lane]);
  unsigned short hh0 = f2bf(v0), hh1 = f2bf(v1);
  h0h[base + lane] = hh0;
  h0l[base + lane] = f2bf(v0 - bf2f(hh0));
  h0h[base + 64 + lane] = hh1;
  h0l[base + 64 + lane] = f2bf(v1 - bf2f(hh1));
}

// ---------------- per-node attention logits (layer 1) ----------------------
__global__ __launch_bounds__(256) void elr1_kernel(const unsigned* __restrict__ featI,
                                                   const float* __restrict__ al,
                                                   const float* __restrict__ ar,
                                                   float2* __restrict__ el,
                                                   float2* __restrict__ er, int N) {
  int wid = threadIdx.x >> 6;
  int lane = threadIdx.x & 63;
  int n = blockIdx.x * 4 + wid;
  if (n >= N) return;
  float2 f = unpk(featI[(size_t)n * 64 + lane]);
  float e0 = wave_sum(f.x * al[lane]);
  float e1 = wave_sum(f.y * al[64 + lane]);
  float r0 = wave_sum(f.x * ar[lane]);
  float r1 = wave_sum(f.y * ar[64 + lane]);
  if (lane == 0) {
    el[n] = make_float2(e0, e1);
    er[n] = make_float2(r0, r1);
  }
}

// ---------------- fused GAT layer 1: softmax + aggregation (wave/node) -----
// Windowed (256-edge) wave-parallel online softmax with chunk skip.
__global__ __launch_bounds__(256) void gat1_agg(const unsigned* __restrict__ featI,
                                                const float2* __restrict__ el,
                                                const float2* __restrict__ er,
                                                const int* __restrict__ row_start,
                                                const unsigned short* __restrict__ csr_src,
                                                const float* __restrict__ b,
                                                unsigned short* __restrict__ h1h,
                                                unsigned short* __restrict__ h1l, int N) {
  __shared__ float4 pbuf[4][256];
  int wid = threadIdx.x >> 6;
  int lane = threadIdx.x & 63;
  int n = blockIdx.x * 4 + wid;
  if (n >= N) return;
  int beg = row_start[n], end = row_start[n + 1];
  float2 ern = er[n];
  float m0 = -INFINITY, m1 = -INFINITY;
  float s0 = 0.f, s1 = 0.f, a0 = 0.f, a1 = 0.f;
  for (int w = beg; w < end; w += 256) {
    int nv = min(end - w, 256);
    float e0c[4], e1c[4];
    unsigned uc[4];
    float wm0 = -INFINITY, wm1 = -INFINITY;
#pragma unroll
    for (int c = 0; c < 4; ++c) {
      if (c * 64 < nv) {
        int i = w + c * 64 + lane;
        bool v = (c * 64 + lane < nv);
        unsigned u = v ? (unsigned)csr_src[i] : 0u;
        float2 l = el[u];
        float e0 = l.x + ern.x;
        e0 = e0 > 0.f ? e0 : 0.2f * e0;
        float e1 = l.y + ern.y;
        e1 = e1 > 0.f ? e1 : 0.2f * e1;
        if (!v) {
          e0 = -INFINITY;
          e1 = -INFINITY;
        }
        uc[c] = u;
        e0c[c] = e0;
        e1c[c] = e1;
        wm0 = fmaxf(wm0, e0);
        wm1 = fmaxf(wm1, e1);
      }
    }
#pragma unroll
    for (int o = 32; o > 0; o >>= 1) {
      wm0 = fmaxf(wm0, __shfl_xor(wm0, o, 64));
      wm1 = fmaxf(wm1, __shfl_xor(wm1, o, 64));
    }
    float nm0 = fmaxf(m0, wm0), nm1 = fmaxf(m1, wm1);
    float sc0 = __expf(m0 - nm0);  // first window: exp(-inf)=0, a/s were 0
    float sc1 = __expf(m1 - nm1);
    float ls0 = 0.f, ls1 = 0.f;
#pragma unroll
    for (int c = 0; c < 4; ++c) {
      if (c * 64 < nv) {
        float p0 = __expf(e0c[c] - nm0);  // invalid: exp(-inf)=0
        float p1 = __expf(e1c[c] - nm1);
        ls0 += p0;
        ls1 += p1;
        pbuf[wid][c * 64 + lane] = make_float4(p0, p1, __uint_as_float(uc[c]), 0.f);
      }
    }
    ls0 = wave_sum(ls0);
    ls1 = wave_sum(ls1);
    s0 = s0 * sc0 + ls0;
    s1 = s1 * sc1 + ls1;
    a0 *= sc0;
    a1 *= sc1;
    m0 = nm0;
    m1 = nm1;
    // phase 2: 8-wide gather-fma; entries >= nv in executed chunks have p=0
    for (int j = 0; j < nv; j += 8) {
      float4 q0 = pbuf[wid][j + 0];
      float4 q1 = pbuf[wid][j + 1];
      float4 q2 = pbuf[wid][j + 2];
      float4 q3 = pbuf[wid][j + 3];
      float4 q4 = pbuf[wid][j + 4];
      float4 q5 = pbuf[wid][j + 5];
      float4 q6 = pbuf[wid][j + 6];
      float4 q7 = pbuf[wid][j + 7];
      unsigned x0 = featI[(size_t)__float_as_uint(q0.z) * 64 + lane];
      unsigned x1 = featI[(size_t)__float_as_uint(q1.z) * 64 + lane];
      unsigned x2 = featI[(size_t)__float_as_uint(q2.z) * 64 + lane];
      unsigned x3 = featI[(size_t)__float_as_uint(q3.z) * 64 + lane];
      unsigned x4 = featI[(size_t)__float_as_uint(q4.z) * 64 + lane];
      unsigned x5 = featI[(size_t)__float_as_uint(q5.z) * 64 + lane];
      unsigned x6 = featI[(size_t)__float_as_uint(q6.z) * 64 + lane];
      unsigned x7 = featI[(size_t)__float_as_uint(q7.z) * 64 + lane];
      float2 f0 = unpk(x0), f1 = unpk(x1), f2 = unpk(x2), f3 = unpk(x3);
      float2 f4 = unpk(x4), f5 = unpk(x5), f6 = unpk(x6), f7 = unpk(x7);
      a0 = fmaf(q0.x, f0.x, a0); a1 = fmaf(q0.y, f0.y, a1);
      a0 = fmaf(q1.x, f1.x, a0); a1 = fmaf(q1.y, f1.y, a1);
      a0 = fmaf(q2.x, f2.x, a0); a1 = fmaf(q2.y, f2.y, a1);
      a0 = fmaf(q3.x, f3.x, a0); a1 = fmaf(q3.y, f3.y, a1);
      a0 = fmaf(q4.x, f4.x, a0); a1 = fmaf(q4.y, f4.y, a1);
      a0 = fmaf(q5.x, f5.x, a0); a1 = fmaf(q5.y, f5.y, a1);
      a0 = fmaf(q6.x, f6.x, a0); a1 = fmaf(q6.y, f6.y, a1);
      a0 = fmaf(q7.x, f7.x, a0); a1 = fmaf(q7.y, f7.y, a1);
    }
  }
  float inv0 = 1.0f / fmaxf(s0, 1e-9f);
  float inv1 = 1.0f / fmaxf(s1, 1e-9f);
  float o0 = elu_f(a0 * inv0 + b[lane]);
  float o1 = elu_f(a1 * inv1 + b[64 + lane]);
  size_t base = (size_t)n * 128;
  unsigned short hh0 = f2bf(o0), hh1 = f2bf(o1);
  h1h[base + lane] = hh0;
  h1l[base + lane] = f2bf(o0 - bf2f(hh0));
  h1h[base + 64 + lane] = hh1;
  h1l[base + 64 + lane] = f2bf(o1 - bf2f(hh1));
}

// ---------------- per-node attention logits (layer 2) ----------------------
__global__ __launch_bounds__(256) void elr2_kernel(const unsigned short* __restrict__ feat,  // bf16 ld48
                                                   const float* __restrict__ al,
                                                   const float* __restrict__ ar,
                                                   float* __restrict__ el,
                                                   float* __restrict__ er, int N) {
  int wid = threadIdx.x >> 6;
  int lane = threadIdx.x & 63;
  int n = blockIdx.x * 4 + wid;
  if (n >= N) return;
  float f = 0.f, a = 0.f, r = 0.f;
  if (lane < 47) {
    f = bf2f(feat[(size_t)n * 48 + lane]);
    a = al[lane];
    r = ar[lane];
  }
  float e = wave_sum(f * a);
  float rr = wave_sum(f * r);
  if (lane == 0) {
    el[n] = e;
    er[n] = rr;
  }
}

// ---------------- fused GAT layer 2: softmax + aggregation -> d_out --------
__global__ __launch_bounds__(256) void gat2_agg(const unsigned short* __restrict__ feat,  // bf16 ld48
                                                const float* __restrict__ el,
                                                const float* __restrict__ er,
                                                const int* __restrict__ row_start,
                                                const unsigned short* __restrict__ csr_src,
                                                const float* __restrict__ b,
                                                float* __restrict__ out, int N) {
  __shared__ float2 pbuf[4][256];
  int wid = threadIdx.x >> 6;
  int lane = threadIdx.x & 63;
  int n = blockIdx.x * 4 + wid;
  if (n >= N) return;
  int beg = row_start[n], end = row_start[n + 1];
  float ern = er[n];
  int lidx = lane < 47 ? lane : 0;
  float m = -INFINITY, s = 0.f, acc = 0.f;
  for (int w = beg; w < end; w += 256) {
    int nv = min(end - w, 256);
    float ec[4];
    unsigned uc[4];
    float wm = -INFINITY;
#pragma unroll
    for (int c = 0; c < 4; ++c) {
      if (c * 64 < nv) {
        int i = w + c * 64 + lane;
        bool v = (c * 64 + lane < nv);
        unsigned u = v ? (unsigned)csr_src[i] : 0u;
        float e = el[u] + ern;
        e = e > 0.f ? e : 0.2f * e;
        if (!v) e = -INFINITY;
        uc[c] = u;
        ec[c] = e;
        wm = fmaxf(wm, e);
      }
    }
#pragma unroll
    for (int o = 32; o > 0; o >>= 1) wm = fmaxf(wm, __shfl_xor(wm, o, 64));
    float nm = fmaxf(m, wm);
    float sc = __expf(m - nm);
    float ls = 0.f;
#pragma unroll
    for (int c = 0; c < 4; ++c) {
      if (c * 64 < nv) {
        float p = __expf(ec[c] - nm);
        ls += p;
        pbuf[wid][c * 64 + lane] = make_float2(p, __uint_as_float(uc[c]));
      }
    }
    ls = wave_sum(ls);
    s = s * sc + ls;
    acc *= sc;
    m = nm;
    for (int j = 0; j < nv; j += 8) {
      float2 q0 = pbuf[wid][j + 0];
      float2 q1 = pbuf[wid][j + 1];
      float2 q2 = pbuf[wid][j + 2];
      float2 q3 = pbuf[wid][j + 3];
      float2 q4 = pbuf[wid][j + 4];
      float2 q5 = pbuf[wid][j + 5];
      float2 q6 = pbuf[wid][j + 6];
      float2 q7 = pbuf[wid][j + 7];
      float g0 = bf2f(feat[(size_t)__float_as_uint(q0.y) * 48 + lidx]);
      float g1 = bf2f(feat[(size_t)__float_as_uint(q1.y) * 48 + lidx]);
      float g2 = bf2f(feat[(size_t)__float_as_uint(q2.y) * 48 + lidx]);
      float g3 = bf2f(feat[(size_t)__float_as_uint(q3.y) * 48 + lidx]);
      float g4 = bf2f(feat[(size_t)__float_as_uint(q4.y) * 48 + lidx]);
      float g5 = bf2f(feat[(size_t)__float_as_uint(q5.y) * 48 + lidx]);
      float g6 = bf2f(feat[(size_t)__float_as_uint(q6.y) * 48 + lidx]);
      float g7 = bf2f(feat[(size_t)__float_as_uint(q7.y) * 48 + lidx]);
      acc = fmaf(q0.x, g0, acc);
      acc = fmaf(q1.x, g1, acc);
      acc = fmaf(q2.x, g2, acc);
      acc = fmaf(q3.x, g3, acc);
      acc = fmaf(q4.x, g4, acc);
      acc = fmaf(q5.x, g5, acc);
      acc = fmaf(q6.x, g6, acc);
      acc = fmaf(q7.x, g7, acc);
    }
  }
  if (lane < 47) {
    out[(size_t)n * 47 + lane] = acc / fmaxf(s, 1e-9f) + b[lane];
  }
}

// ---------------------------------------------------------------------------
extern "C" void kernel_launch(void* const* d_in, const int* in_sizes, int n_in,
                              void* d_out, int out_size, void* d_ws, size_t ws_size,
                              hipStream_t stream) {
  const float* x = (const float*)d_in[0];
  const int* src = (const int*)d_in[1];
  const int* dst = (const int*)d_in[2];
  const float* sage_w_self = (const float*)d_in[3];
  const float* sage_w_neigh = (const float*)d_in[4];
  const float* sage_b = (const float*)d_in[5];
  const float* gat1_w = (const float*)d_in[6];
  const float* gat1_al = (const float*)d_in[7];
  const float* gat1_ar = (const float*)d_in[8];
  const float* gat1_b = (const float*)d_in[9];
  const float* gat2_w = (const float*)d_in[10];
  const float* gat2_al = (const float*)d_in[11];
  const float* gat2_ar = (const float*)d_in[12];
  const float* gat2_b = (const float*)d_in[13];
  float* out = (float*)d_out;

  const int N = in_sizes[0] / 256;
  const int E = in_sizes[1];

  char* ws = (char*)d_ws;
  size_t off = 0;
  auto alloc = [&](size_t bytes) {
    size_t o = off;
    off += (bytes + 255) & ~(size_t)255;
    return o;
  };
  int* deg_i = (int*)(ws + alloc((size_t)N * 4));
  int* row_start = (int*)(ws + alloc((size_t)(N + 1) * 4));
  int* cursor = (int*)(ws + alloc((size_t)N * 4));
  unsigned short* csr_src = (unsigned short*)(ws + alloc((size_t)E * 2));
  int* psum = (int*)(ws + alloc(((size_t)N / 1024 + 2) * 4));
  float* bufA = (float*)(ws + alloc((size_t)N * 128 * 4));       // z
  unsigned* bufG = (unsigned*)(ws + alloc((size_t)N * 64 * 4));  // yI -> feat1I -> feat2b
  unsigned short* bufX = (unsigned short*)(ws + alloc((size_t)N * 256 * 2));  // h0 | h1
  unsigned short* wt_sh = (unsigned short*)(ws + alloc(128 * 256 * 2));
  unsigned short* wt_sl = (unsigned short*)(ws + alloc(128 * 256 * 2));
  unsigned short* wt_nh = (unsigned short*)(ws + alloc(128 * 256 * 2));
  unsigned short* wt_nl = (unsigned short*)(ws + alloc(128 * 256 * 2));
  unsigned short* wt_1h = (unsigned short*)(ws + alloc(128 * 128 * 2));
  unsigned short* wt_1l = (unsigned short*)(ws + alloc(128 * 128 * 2));
  unsigned short* wt_2h = (unsigned short*)(ws + alloc(48 * 128 * 2));
  unsigned short* wt_2l = (unsigned short*)(ws + alloc(48 * 128 * 2));
  float2* el1 = (float2*)(ws + alloc((size_t)N * 8));
  float2* er1 = (float2*)(ws + alloc((size_t)N * 8));
  float* el2 = (float*)(ws + alloc((size_t)N * 4));
  float* er2 = (float*)(ws + alloc((size_t)N * 4));
  (void)ws_size;
  (void)n_in;
  (void)out_size;

  // lifetimes:
  float* z = bufA;                                  // dead after sage_agg
  unsigned* yI = bufG;                              // dead after sage_agg
  unsigned short* h0h = bufX;                       // dead after L1 gemm
  unsigned short* h0l = bufX + (size_t)N * 128;
  unsigned* feat1I = bufG;                          // reuse yI; dead after gat1_agg
  unsigned short* h1h = bufX;                       // reuse h0 region (dead)
  unsigned short* h1l = bufX + (size_t)N * 128;
  unsigned short* feat2b = (unsigned short*)bufG;   // reuse feat1I

  hipMemsetAsync(deg_i, 0, (size_t)N * 4, stream);

  const int eb = (E + 255) / 256;
  const int eb2 = (E + 511) / 512;
  const int nb4 = (N + 3) / 4;
  const int gx = (N + 127) / 128;
  const int PB = (N + 1023) / 1024;

  prep_w<<<(128 * 256 + 255) / 256, 256, 0, stream>>>(sage_w_self, 128, 256, 128, wt_sh, wt_sl);
  prep_w<<<(128 * 256 + 255) / 256, 256, 0, stream>>>(sage_w_neigh, 128, 256, 128, wt_nh, wt_nl);
  prep_w<<<(128 * 128 + 255) / 256, 256, 0, stream>>>(gat1_w, 128, 128, 128, wt_1h, wt_1l);
  prep_w<<<(48 * 128 + 255) / 256, 256, 0, stream>>>(gat2_w, 47, 128, 48, wt_2h, wt_2l);

  deg_kernel<<<eb, 256, 0, stream>>>(dst, deg_i, E);
  scan_partial<<<PB, 256, 0, stream>>>(deg_i, psum, N);
  scan_psum<<<1, 64, 0, stream>>>(psum, PB);
  scan_final<<<PB, 256, 0, stream>>>(deg_i, psum, row_start, N, E);
  hipMemcpyAsync(cursor, row_start, (size_t)N * 4, hipMemcpyDeviceToDevice, stream);
  scatter_kernel<<<eb2, 256, 0, stream>>>(src, dst, cursor, csr_src, E);

  // layer 0 (AF32: reads x f32 directly, in-register hi/lo split):
  //   y=0 -> z = x@W_self (f32, ldc=128 floats)
  //   y=1 -> yI = x@W_neigh (packed bf16 ilv, ldu=64 uints)
  {
    dim3 grid(gx, 2);
    gemm_mfma<256, 8, 1><<<grid, 256, 0, stream>>>(x, nullptr, wt_sh, wt_sl, wt_nh, wt_nl,
                                                   z, yI, 128, N, 128, 0, 1);
  }
  sage_agg<<<nb4, 256, 0, stream>>>(z, yI, row_start, csr_src, sage_b, h0h, h0l, N);

  // GAT layer 1: feat1I = h0 @ gat1_w (packed bf16 ilv, ldc=128 -> ldu=64 uints)
  {
    dim3 grid(gx, 1);
    gemm_mfma<128, 8, 0><<<grid, 256, 0, stream>>>(h0h, h0l, wt_1h, wt_1l, wt_1h, wt_1l,
                                                   feat1I, feat1I, 128, N, 128, 1, 1);
  }
  elr1_kernel<<<nb4, 256, 0, stream>>>(feat1I, gat1_al, gat1_ar, el1, er1, N);
  gat1_agg<<<nb4, 256, 0, stream>>>(feat1I, el1, er1, row_start, csr_src, gat1_b,
                                    h1h, h1l, N);

  // GAT layer 2: feat2b = h1 @ gat2_w (bf16 std, ldc=48 ushorts)
  {
    dim3 grid(gx, 1);
    gemm_mfma<128, 3, 0><<<grid, 256, 0, stream>>>(h1h, h1l, wt_2h, wt_2l, wt_2h, wt_2l,
                                                   feat2b, feat2b, 48, N, 47, 2, 2);
  }
  elr2_kernel<<<nb4, 256, 0, stream>>>(feat2b, gat2_al, gat2_ar, el2, er2, N);
  gat2_agg<<<nb4, 256, 0, stream>>>(feat2b, el2, er2, row_start, csr_src, gat2_b, out, N);
}

// Round 17
// 283.313 us; speedup vs baseline: 1.4091x; 1.0627x over previous
//
#include <hip/hip_runtime.h>

// ---------------------------------------------------------------------------
// GAT_4733053960619: SAGEConv(mean) -> ELU -> GAT(2 heads,64) -> ELU -> GAT(1,47)
// N=50000, E=800000, IN_FEATS=256. All fp32.
//
// R16 = R15 + (a) elr1/elr2 fused into GEMM epilogues (emode: per-row attn
// dots from the already-register-resident, bf16-rounded outputs + 16-lane
// shuffle tree; deletes 2 dispatches + 17.6MB of re-reads), (b) cursor init
// folded into scan_final (deletes the D2D memcpy dispatch).
// ---------------------------------------------------------------------------

typedef __attribute__((ext_vector_type(8))) short bf16x8;
typedef __attribute__((ext_vector_type(4))) float f32x4;

__device__ __forceinline__ float wave_sum(float v) {
#pragma unroll
  for (int o = 32; o > 0; o >>= 1) v += __shfl_xor(v, o, 64);
  return v;
}

__device__ __forceinline__ int wave_sum_i(int v) {
#pragma unroll
  for (int o = 32; o > 0; o >>= 1) v += __shfl_xor(v, o, 64);
  return v;
}

__device__ __forceinline__ float elu_f(float v) {
  return v > 0.f ? v : __expf(v) - 1.0f;
}

__device__ __forceinline__ unsigned short f2bf(float x) {
  union { float f; unsigned u; } v;
  v.f = x;
  unsigned r = v.u + 0x7FFFu + ((v.u >> 16) & 1u);
  return (unsigned short)(r >> 16);
}

__device__ __forceinline__ float bf2f(unsigned short h) {
  union { unsigned u; float f; } v;
  v.u = ((unsigned)h) << 16;
  return v.f;
}

// packed 2xbf16 (lo=head0, hi=head1) -> (f0, f1)
__device__ __forceinline__ float2 unpk(unsigned v) {
  union { unsigned u; float f; } a, b;
  a.u = v << 16;
  b.u = v & 0xFFFF0000u;
  return make_float2(a.f, b.f);
}

struct bfpair {
  bf16x8 h, l;
};

// load 8 consecutive f32 and split to bf16 hi/lo in-register
__device__ __forceinline__ bfpair cvt8(const float* __restrict__ p) {
  float4 a = *(const float4*)p;
  float4 b = *(const float4*)(p + 4);
  float v[8] = {a.x, a.y, a.z, a.w, b.x, b.y, b.z, b.w};
  bfpair r;
#pragma unroll
  for (int j = 0; j < 8; ++j) {
    unsigned short hh = f2bf(v[j]);
    r.h[j] = (short)hh;
    r.l[j] = (short)f2bf(v[j] - bf2f(hh));
  }
  return r;
}

// ---------------- CSR build ----------------
__global__ __launch_bounds__(256) void deg_kernel(const int* __restrict__ dst,
                                                  int* __restrict__ deg, int E) {
  int i = blockIdx.x * 256 + threadIdx.x;
  if (i < E) atomicAdd(&deg[dst[i]], 1);
}

// phase 1: per-1024-chunk sums
__global__ __launch_bounds__(256) void scan_partial(const int* __restrict__ deg,
                                                    int* __restrict__ psum, int n) {
  __shared__ int red[4];
  const int t = threadIdx.x;
  const int base = blockIdx.x * 1024;
  int s = 0;
#pragma unroll
  for (int j = 0; j < 4; ++j) {
    int idx = base + t + j * 256;
    s += (idx < n) ? deg[idx] : 0;
  }
  s = wave_sum_i(s);
  const int lane = t & 63, w = t >> 6;
  if (lane == 0) red[w] = s;
  __syncthreads();
  if (t == 0) psum[blockIdx.x] = red[0] + red[1] + red[2] + red[3];
}

// phase 2: exclusive scan of partials (single wave, carry loop)
__global__ __launch_bounds__(64) void scan_psum(int* __restrict__ psum, int PB) {
  const int lane = threadIdx.x;
  int carry = 0;
  for (int base = 0; base < PB; base += 64) {
    int v = (base + lane < PB) ? psum[base + lane] : 0;
    int inc = v;
#pragma unroll
    for (int o = 1; o < 64; o <<= 1) {
      int u = __shfl_up(inc, o, 64);
      if (lane >= o) inc += u;
    }
    if (base + lane < PB) psum[base + lane] = carry + inc - v;
    carry += __shfl(inc, 63, 64);
  }
}

// phase 3: per-chunk exclusive scan + block offset -> row_start AND cursor
__global__ __launch_bounds__(256) void scan_final(const int* __restrict__ deg,
                                                  const int* __restrict__ psum,
                                                  int* __restrict__ row_start,
                                                  int* __restrict__ cursor,
                                                  int n, int E) {
  __shared__ int woff[4];
  const int t = threadIdx.x;
  const int lane = t & 63, w = t >> 6;
  const int base = blockIdx.x * 1024 + t * 4;
  int d0 = (base + 0 < n) ? deg[base + 0] : 0;
  int d1 = (base + 1 < n) ? deg[base + 1] : 0;
  int d2 = (base + 2 < n) ? deg[base + 2] : 0;
  int d3 = (base + 3 < n) ? deg[base + 3] : 0;
  int l0 = d0, l1 = l0 + d1, l2 = l1 + d2, l3 = l2 + d3;
  int inc = l3;
#pragma unroll
  for (int o = 1; o < 64; o <<= 1) {
    int u = __shfl_up(inc, o, 64);
    if (lane >= o) inc += u;
  }
  int texc = inc - l3;  // exclusive within wave
  if (lane == 63) woff[w] = inc;
  __syncthreads();
  int wo = 0;
  if (w == 0 && lane < 4) {
    int s = woff[lane];
    int p = s;
#pragma unroll
    for (int o = 1; o < 4; o <<= 1) {
      int u = __shfl_up(p, o, 64);
      if (lane >= o) p += u;
    }
    woff[lane] = p - s;  // exclusive wave offsets
  }
  __syncthreads();
  wo = woff[w];
  const int boff = psum[blockIdx.x] + wo + texc;
  if (base + 0 < n) { row_start[base + 0] = boff;      cursor[base + 0] = boff; }
  if (base + 1 < n) { row_start[base + 1] = boff + l0; cursor[base + 1] = boff + l0; }
  if (base + 2 < n) { row_start[base + 2] = boff + l1; cursor[base + 2] = boff + l1; }
  if (base + 3 < n) { row_start[base + 3] = boff + l2; cursor[base + 3] = boff + l2; }
  if (blockIdx.x == 0 && t == 0) row_start[n] = E;
}

// cursor pre-filled with row_start; atomicAdd -> absolute slot; plain ushort
// store (src ids fit 16 bits since N < 65536).
__global__ __launch_bounds__(256) void scatter_kernel(const int* __restrict__ src,
                                                      const int* __restrict__ dst,
                                                      int* __restrict__ cursor,
                                                      unsigned short* __restrict__ csr_src,
                                                      int E) {
  int i = blockIdx.x * 512 + threadIdx.x;
  int i2 = i + 256;
  int d0 = (i < E) ? dst[i] : 0;
  int d1 = (i2 < E) ? dst[i2] : 0;
  int s0 = (i < E) ? src[i] : 0;
  int s1 = (i2 < E) ? src[i2] : 0;
  int p0 = 0, p1 = 0;
  if (i < E) p0 = atomicAdd(&cursor[d0], 1);
  if (i2 < E) p1 = atomicAdd(&cursor[d1], 1);
  if (i < E) csr_src[p0] = (unsigned short)s0;
  if (i2 < E) csr_src[p1] = (unsigned short)s1;
}

// ---------------- weight prep: W[K][N] f32 -> W^T hi/lo [Npad][K] bf16 ------
__global__ __launch_bounds__(256) void prep_w(const float* __restrict__ W, int N, int K,
                                              int Npad, unsigned short* __restrict__ th,
                                              unsigned short* __restrict__ tl) {
  int i = blockIdx.x * 256 + threadIdx.x;
  if (i >= Npad * K) return;
  int n = i / K, k = i - n * K;
  float v = (n < N) ? W[(size_t)k * N + n] : 0.f;
  unsigned short h = f2bf(v);
  th[i] = h;
  tl[i] = f2bf(v - bf2f(h));
}

// ---------------- MFMA GEMM: C = A @ B, split-bf16, LDS-staged B ----------
// A: if AF32, raw f32 [M][K] split to hi/lo in-register; else pre-split
// hi/lo bf16 (Av=hi, Al=lo). B^T as hi/lo bf16 [Npad][K]; Npad = NT*16.
// Block = 4 waves = 128 rows; wave = 32 rows (2 fragments) x NT*16 cols.
// omode: 0 = f32 std (ldc floats); 1 = packed-bf16 head-interleave, uint
// stride ldu = ldc>>1; 2 = bf16 std (ldc ushorts).
// emode: 0 = none; 1 = fused 2-head elr (with omode1, NT==8): el/er float2
// per row from bf16-rounded outputs; 2 = fused 1-head elr (with omode2).
template <int K, int NT, int AF32>
__global__ __launch_bounds__(256) void gemm_mfma(
    const void* __restrict__ Av, const unsigned short* __restrict__ Al,
    const unsigned short* __restrict__ BTh0, const unsigned short* __restrict__ BTl0,
    const unsigned short* __restrict__ BTh1, const unsigned short* __restrict__ BTl1,
    void* __restrict__ C0, void* __restrict__ C1,
    int ldc, int M, int Ncols, int omode0, int omode1,
    const float* __restrict__ atl, const float* __restrict__ atr,
    void* __restrict__ elp, void* __restrict__ erp, int emode) {
  constexpr int K2 = K * 2;    // bytes per B^T row
  constexpr int NKT = K / 32;  // k-tiles
  __shared__ unsigned short Bs[2][2][NT * 512];  // [buf][hi/lo][nt*512 + kg*128 + lrow*8]

  const unsigned short* BTh = blockIdx.y ? BTh1 : BTh0;
  const unsigned short* BTl = blockIdx.y ? BTl1 : BTl0;
  void* Cv = blockIdx.y ? C1 : C0;
  const int omode = blockIdx.y ? omode1 : omode0;

  const int wid = threadIdx.x >> 6;
  const int lane = threadIdx.x & 63;
  const int lrow = lane & 15;
  const int kg = lane >> 4;
  const int row0 = blockIdx.x * 128 + wid * 32;
  const int ra = min(row0 + lrow, M - 1);
  const int rb = min(row0 + 16 + lrow, M - 1);
  const size_t aoffA = (size_t)ra * K + kg * 8;
  const size_t aoffB = (size_t)rb * K + kg * 8;

  const float* Af = (const float*)Av;
  const unsigned short* Ah = (const unsigned short*)Av;

  auto loadA = [&](size_t off) -> bfpair {
    if constexpr (AF32) {
      return cvt8(Af + off);
    } else {
      bfpair r;
      r.h = *(const bf16x8*)(Ah + off);
      r.l = *(const bf16x8*)(Al + off);
      return r;
    }
  };

  auto stage = [&](int buf, int kt) {
    for (int j = wid; j < 2 * NT; j += 4) {
      const int h = (j >= NT) ? 1 : 0;
      const int nt = h ? j - NT : j;
      const unsigned short* src = h ? BTl : BTh;
      const char* g = (const char*)src + (size_t)(nt * 16 + lrow) * K2 + kt * 64 + kg * 16;
      unsigned short* l = &Bs[buf][h][nt * 512];
      __builtin_amdgcn_global_load_lds(
          (const __attribute__((address_space(1))) unsigned*)g,
          (__attribute__((address_space(3))) unsigned*)l, 16, 0, 0);
    }
  };

  f32x4 accA[NT] = {};
  f32x4 accB[NT] = {};

  stage(0, 0);
  bfpair cA = loadA(aoffA);
  bfpair cB = loadA(aoffB);

  for (int kt = 0; kt < NKT; ++kt) {
    __syncthreads();  // buf[kt&1] staged
    if (kt + 1 < NKT) stage((kt + 1) & 1, kt + 1);
    const int kn = (kt + 1 < NKT) ? (kt + 1) * 32 : kt * 32;
    bfpair nA = loadA(aoffA + kn);
    bfpair nB = loadA(aoffB + kn);
    const int buf = kt & 1;
#pragma unroll
    for (int nt = 0; nt < NT; ++nt) {
      bf16x8 bh = ((const bf16x8*)&Bs[buf][0][nt * 512])[lane];
      bf16x8 bl = ((const bf16x8*)&Bs[buf][1][nt * 512])[lane];
      accA[nt] = __builtin_amdgcn_mfma_f32_16x16x32_bf16(cA.h, bh, accA[nt], 0, 0, 0);
      accA[nt] = __builtin_amdgcn_mfma_f32_16x16x32_bf16(cA.h, bl, accA[nt], 0, 0, 0);
      accA[nt] = __builtin_amdgcn_mfma_f32_16x16x32_bf16(cA.l, bh, accA[nt], 0, 0, 0);
      accB[nt] = __builtin_amdgcn_mfma_f32_16x16x32_bf16(cB.h, bh, accB[nt], 0, 0, 0);
      accB[nt] = __builtin_amdgcn_mfma_f32_16x16x32_bf16(cB.h, bl, accB[nt], 0, 0, 0);
      accB[nt] = __builtin_amdgcn_mfma_f32_16x16x32_bf16(cB.l, bh, accB[nt], 0, 0, 0);
    }
    cA = nA;
    cB = nB;
  }

  if (omode == 1) {
    // packed-bf16 head-interleave: uint stride = ldc/2; optional fused elr
    unsigned* Cu = (unsigned*)Cv;
    const int ldu = ldc >> 1;
    float2* elo = (float2*)elp;
    float2* ero = (float2*)erp;
    float a0v[4], a1v[4], r0v[4], r1v[4];
    if (emode == 1) {
#pragma unroll
      for (int nt = 0; nt < NT / 2 && nt < 4; ++nt) {
        int d = nt * 16 + lrow;
        a0v[nt] = atl[d];
        a1v[nt] = atl[64 + d];
        r0v[nt] = atr[d];
        r1v[nt] = atr[64 + d];
      }
    }
#pragma unroll
    for (int r = 0; r < 4; ++r) {
      int g0 = row0 + kg * 4 + r;
      int g1 = row0 + 16 + kg * 4 + r;
      float eA0 = 0, eA1 = 0, rA0 = 0, rA1 = 0;
      float eB0 = 0, eB1 = 0, rB0 = 0, rB1 = 0;
#pragma unroll
      for (int nt = 0; nt < NT / 2; ++nt) {
        int d = nt * 16 + lrow;
        unsigned pA = (unsigned)f2bf(accA[nt][r]) |
                      ((unsigned)f2bf(accA[nt + NT / 2][r]) << 16);
        unsigned pB = (unsigned)f2bf(accB[nt][r]) |
                      ((unsigned)f2bf(accB[nt + NT / 2][r]) << 16);
        if (g0 < M) Cu[(size_t)g0 * ldu + d] = pA;
        if (g1 < M) Cu[(size_t)g1 * ldu + d] = pB;
        if (emode == 1 && nt < 4) {
          float2 fA = unpk(pA), fB = unpk(pB);
          eA0 = fmaf(fA.x, a0v[nt], eA0);
          eA1 = fmaf(fA.y, a1v[nt], eA1);
          rA0 = fmaf(fA.x, r0v[nt], rA0);
          rA1 = fmaf(fA.y, r1v[nt], rA1);
          eB0 = fmaf(fB.x, a0v[nt], eB0);
          eB1 = fmaf(fB.y, a1v[nt], eB1);
          rB0 = fmaf(fB.x, r0v[nt], rB0);
          rB1 = fmaf(fB.y, r1v[nt], rB1);
        }
      }
      if (emode == 1) {
#pragma unroll
        for (int o = 1; o < 16; o <<= 1) {
          eA0 += __shfl_xor(eA0, o, 64);
          eA1 += __shfl_xor(eA1, o, 64);
          rA0 += __shfl_xor(rA0, o, 64);
          rA1 += __shfl_xor(rA1, o, 64);
          eB0 += __shfl_xor(eB0, o, 64);
          eB1 += __shfl_xor(eB1, o, 64);
          rB0 += __shfl_xor(rB0, o, 64);
          rB1 += __shfl_xor(rB1, o, 64);
        }
        if (lrow == 0) {
          if (g0 < M) {
            elo[g0] = make_float2(eA0, eA1);
            ero[g0] = make_float2(rA0, rA1);
          }
          if (g1 < M) {
            elo[g1] = make_float2(eB0, eB1);
            ero[g1] = make_float2(rB0, rB1);
          }
        }
      }
    }
  } else if (omode == 2) {
    unsigned short* Cs = (unsigned short*)Cv;
    float* elo = (float*)elp;
    float* ero = (float*)erp;
    float av[NT], rv[NT];
    if (emode == 2) {
#pragma unroll
      for (int nt = 0; nt < NT; ++nt) {
        int gc = nt * 16 + lrow;
        av[nt] = (gc < Ncols) ? atl[gc] : 0.f;
        rv[nt] = (gc < Ncols) ? atr[gc] : 0.f;
      }
    }
#pragma unroll
    for (int r = 0; r < 4; ++r) {
      int g0 = row0 + kg * 4 + r;
      int g1 = row0 + 16 + kg * 4 + r;
      float eA = 0, rA = 0, eB = 0, rB = 0;
#pragma unroll
      for (int nt = 0; nt < NT; ++nt) {
        int gc = nt * 16 + lrow;
        if (gc >= Ncols) continue;
        unsigned short hA = f2bf(accA[nt][r]);
        unsigned short hB = f2bf(accB[nt][r]);
        if (g0 < M) Cs[(size_t)g0 * ldc + gc] = hA;
        if (g1 < M) Cs[(size_t)g1 * ldc + gc] = hB;
        if (emode == 2) {
          float fA = bf2f(hA), fB = bf2f(hB);
          eA = fmaf(fA, av[nt], eA);
          rA = fmaf(fA, rv[nt], rA);
          eB = fmaf(fB, av[nt], eB);
          rB = fmaf(fB, rv[nt], rB);
        }
      }
      if (emode == 2) {
#pragma unroll
        for (int o = 1; o < 16; o <<= 1) {
          eA += __shfl_xor(eA, o, 64);
          rA += __shfl_xor(rA, o, 64);
          eB += __shfl_xor(eB, o, 64);
          rB += __shfl_xor(rB, o, 64);
        }
        if (lrow == 0) {
          if (g0 < M) {
            elo[g0] = eA;
            ero[g0] = rA;
          }
          if (g1 < M) {
            elo[g1] = eB;
            ero[g1] = rB;
          }
        }
      }
    }
  } else {
    float* C = (float*)Cv;
#pragma unroll
    for (int nt = 0; nt < NT; ++nt) {
      int gc = nt * 16 + lrow;
      if (gc >= Ncols) continue;
#pragma unroll
      for (int r = 0; r < 4; ++r) {
        int g0 = row0 + kg * 4 + r;
        if (g0 < M) C[(size_t)g0 * ldc + gc] = accA[nt][r];
        int g1 = row0 + 16 + kg * 4 + r;
        if (g1 < M) C[(size_t)g1 * ldc + gc] = accB[nt][r];
      }
    }
  }
}

// ---------------- SAGE aggregation (wave per node) -> h0 bf16 hi/lo --------
// yI: packed 2xbf16 per (node, d) uint. 8-wide unrolled gathers (MLP).
__global__ __launch_bounds__(256) void sage_agg(const float* __restrict__ z,
                                                const unsigned* __restrict__ yI,
                                                const int* __restrict__ row_start,
                                                const unsigned short* __restrict__ csr_src,
                                                const float* __restrict__ b,
                                                unsigned short* __restrict__ h0h,
                                                unsigned short* __restrict__ h0l, int N) {
  int wid = threadIdx.x >> 6;
  int lane = threadIdx.x & 63;
  int n = blockIdx.x * 4 + wid;
  if (n >= N) return;
  int s = row_start[n], e = row_start[n + 1];
  float a0 = 0.f, a1 = 0.f;
  int i = s;
  for (; i + 7 < e; i += 8) {
    unsigned v0 = yI[(size_t)csr_src[i] * 64 + lane];
    unsigned v1 = yI[(size_t)csr_src[i + 1] * 64 + lane];
    unsigned v2 = yI[(size_t)csr_src[i + 2] * 64 + lane];
    unsigned v3 = yI[(size_t)csr_src[i + 3] * 64 + lane];
    unsigned v4 = yI[(size_t)csr_src[i + 4] * 64 + lane];
    unsigned v5 = yI[(size_t)csr_src[i + 5] * 64 + lane];
    unsigned v6 = yI[(size_t)csr_src[i + 6] * 64 + lane];
    unsigned v7 = yI[(size_t)csr_src[i + 7] * 64 + lane];
    float2 f0 = unpk(v0), f1 = unpk(v1), f2 = unpk(v2), f3 = unpk(v3);
    float2 f4 = unpk(v4), f5 = unpk(v5), f6 = unpk(v6), f7 = unpk(v7);
    a0 += f0.x + f1.x + f2.x + f3.x + f4.x + f5.x + f6.x + f7.x;
    a1 += f0.y + f1.y + f2.y + f3.y + f4.y + f5.y + f6.y + f7.y;
  }
  for (; i < e; ++i) {
    float2 f = unpk(yI[(size_t)csr_src[i] * 64 + lane]);
    a0 += f.x;
    a1 += f.y;
  }
  float inv = 1.0f / fmaxf((float)(e - s), 1.0f);
  size_t base = (size_t)n * 128;
  float v0 = elu_f(z[base + lane] + a0 * inv + b[lane]);
  float v1 = elu_f(z[base + 64 + lane] + a1 * inv + b[64 + lane]);
  unsigned short hh0 = f2bf(v0), hh1 = f2bf(v1);
  h0h[base + lane] = hh0;
  h0l[base + lane] = f2bf(v0 - bf2f(hh0));
  h0h[base + 64 + lane] = hh1;
  h0l[base + 64 + lane] = f2bf(v1 - bf2f(hh1));
}

// ---------------- fused GAT layer 1: softmax + aggregation (wave/node) -----
// Windowed (256-edge) wave-parallel online softmax with chunk skip.
__global__ __launch_bounds__(256) void gat1_agg(const unsigned* __restrict__ featI,
                                                const float2* __restrict__ el,
                                                const float2* __restrict__ er,
                                                const int* __restrict__ row_start,
                                                const unsigned short* __restrict__ csr_src,
                                                const float* __restrict__ b,
                                                unsigned short* __restrict__ h1h,
                                                unsigned short* __restrict__ h1l, int N) {
  __shared__ float4 pbuf[4][256];
  int wid = threadIdx.x >> 6;
  int lane = threadIdx.x & 63;
  int n = blockIdx.x * 4 + wid;
  if (n >= N) return;
  int beg = row_start[n], end = row_start[n + 1];
  float2 ern = er[n];
  float m0 = -INFINITY, m1 = -INFINITY;
  float s0 = 0.f, s1 = 0.f, a0 = 0.f, a1 = 0.f;
  for (int w = beg; w < end; w += 256) {
    int nv = min(end - w, 256);
    float e0c[4], e1c[4];
    unsigned uc[4];
    float wm0 = -INFINITY, wm1 = -INFINITY;
#pragma unroll
    for (int c = 0; c < 4; ++c) {
      if (c * 64 < nv) {
        int i = w + c * 64 + lane;
        bool v = (c * 64 + lane < nv);
        unsigned u = v ? (unsigned)csr_src[i] : 0u;
        float2 l = el[u];
        float e0 = l.x + ern.x;
        e0 = e0 > 0.f ? e0 : 0.2f * e0;
        float e1 = l.y + ern.y;
        e1 = e1 > 0.f ? e1 : 0.2f * e1;
        if (!v) {
          e0 = -INFINITY;
          e1 = -INFINITY;
        }
        uc[c] = u;
        e0c[c] = e0;
        e1c[c] = e1;
        wm0 = fmaxf(wm0, e0);
        wm1 = fmaxf(wm1, e1);
      }
    }
#pragma unroll
    for (int o = 32; o > 0; o >>= 1) {
      wm0 = fmaxf(wm0, __shfl_xor(wm0, o, 64));
      wm1 = fmaxf(wm1, __shfl_xor(wm1, o, 64));
    }
    float nm0 = fmaxf(m0, wm0), nm1 = fmaxf(m1, wm1);
    float sc0 = __expf(m0 - nm0);  // first window: exp(-inf)=0, a/s were 0
    float sc1 = __expf(m1 - nm1);
    float ls0 = 0.f, ls1 = 0.f;
#pragma unroll
    for (int c = 0; c < 4; ++c) {
      if (c * 64 < nv) {
        float p0 = __expf(e0c[c] - nm0);  // invalid: exp(-inf)=0
        float p1 = __expf(e1c[c] - nm1);
        ls0 += p0;
        ls1 += p1;
        pbuf[wid][c * 64 + lane] = make_float4(p0, p1, __uint_as_float(uc[c]), 0.f);
      }
    }
    ls0 = wave_sum(ls0);
    ls1 = wave_sum(ls1);
    s0 = s0 * sc0 + ls0;
    s1 = s1 * sc1 + ls1;
    a0 *= sc0;
    a1 *= sc1;
    m0 = nm0;
    m1 = nm1;
    // phase 2: 8-wide gather-fma; entries >= nv in executed chunks have p=0
    for (int j = 0; j < nv; j += 8) {
      float4 q0 = pbuf[wid][j + 0];
      float4 q1 = pbuf[wid][j + 1];
      float4 q2 = pbuf[wid][j + 2];
      float4 q3 = pbuf[wid][j + 3];
      float4 q4 = pbuf[wid][j + 4];
      float4 q5 = pbuf[wid][j + 5];
      float4 q6 = pbuf[wid][j + 6];
      float4 q7 = pbuf[wid][j + 7];
      unsigned x0 = featI[(size_t)__float_as_uint(q0.z) * 64 + lane];
      unsigned x1 = featI[(size_t)__float_as_uint(q1.z) * 64 + lane];
      unsigned x2 = featI[(size_t)__float_as_uint(q2.z) * 64 + lane];
      unsigned x3 = featI[(size_t)__float_as_uint(q3.z) * 64 + lane];
      unsigned x4 = featI[(size_t)__float_as_uint(q4.z) * 64 + lane];
      unsigned x5 = featI[(size_t)__float_as_uint(q5.z) * 64 + lane];
      unsigned x6 = featI[(size_t)__float_as_uint(q6.z) * 64 + lane];
      unsigned x7 = featI[(size_t)__float_as_uint(q7.z) * 64 + lane];
      float2 f0 = unpk(x0), f1 = unpk(x1), f2 = unpk(x2), f3 = unpk(x3);
      float2 f4 = unpk(x4), f5 = unpk(x5), f6 = unpk(x6), f7 = unpk(x7);
      a0 = fmaf(q0.x, f0.x, a0); a1 = fmaf(q0.y, f0.y, a1);
      a0 = fmaf(q1.x, f1.x, a0); a1 = fmaf(q1.y, f1.y, a1);
      a0 = fmaf(q2.x, f2.x, a0); a1 = fmaf(q2.y, f2.y, a1);
      a0 = fmaf(q3.x, f3.x, a0); a1 = fmaf(q3.y, f3.y, a1);
      a0 = fmaf(q4.x, f4.x, a0); a1 = fmaf(q4.y, f4.y, a1);
      a0 = fmaf(q5.x, f5.x, a0); a1 = fmaf(q5.y, f5.y, a1);
      a0 = fmaf(q6.x, f6.x, a0); a1 = fmaf(q6.y, f6.y, a1);
      a0 = fmaf(q7.x, f7.x, a0); a1 = fmaf(q7.y, f7.y, a1);
    }
  }
  float inv0 = 1.0f / fmaxf(s0, 1e-9f);
  float inv1 = 1.0f / fmaxf(s1, 1e-9f);
  float o0 = elu_f(a0 * inv0 + b[lane]);
  float o1 = elu_f(a1 * inv1 + b[64 + lane]);
  size_t base = (size_t)n * 128;
  unsigned short hh0 = f2bf(o0), hh1 = f2bf(o1);
  h1h[base + lane] = hh0;
  h1l[base + lane] = f2bf(o0 - bf2f(hh0));
  h1h[base + 64 + lane] = hh1;
  h1l[base + 64 + lane] = f2bf(o1 - bf2f(hh1));
}

// ---------------- fused GAT layer 2: softmax + aggregation -> d_out --------
__global__ __launch_bounds__(256) void gat2_agg(const unsigned short* __restrict__ feat,  // bf16 ld48
                                                const float* __restrict__ el,
                                                const float* __restrict__ er,
                                                const int* __restrict__ row_start,
                                                const unsigned short* __restrict__ csr_src,
                                                const float* __restrict__ b,
                                                float* __restrict__ out, int N) {
  __shared__ float2 pbuf[4][256];
  int wid = threadIdx.x >> 6;
  int lane = threadIdx.x & 63;
  int n = blockIdx.x * 4 + wid;
  if (n >= N) return;
  int beg = row_start[n], end = row_start[n + 1];
  float ern = er[n];
  int lidx = lane < 47 ? lane : 0;
  float m = -INFINITY, s = 0.f, acc = 0.f;
  for (int w = beg; w < end; w += 256) {
    int nv = min(end - w, 256);
    float ec[4];
    unsigned uc[4];
    float wm = -INFINITY;
#pragma unroll
    for (int c = 0; c < 4; ++c) {
      if (c * 64 < nv) {
        int i = w + c * 64 + lane;
        bool v = (c * 64 + lane < nv);
        unsigned u = v ? (unsigned)csr_src[i] : 0u;
        float e = el[u] + ern;
        e = e > 0.f ? e : 0.2f * e;
        if (!v) e = -INFINITY;
        uc[c] = u;
        ec[c] = e;
        wm = fmaxf(wm, e);
      }
    }
#pragma unroll
    for (int o = 32; o > 0; o >>= 1) wm = fmaxf(wm, __shfl_xor(wm, o, 64));
    float nm = fmaxf(m, wm);
    float sc = __expf(m - nm);
    float ls = 0.f;
#pragma unroll
    for (int c = 0; c < 4; ++c) {
      if (c * 64 < nv) {
        float p = __expf(ec[c] - nm);
        ls += p;
        pbuf[wid][c * 64 + lane] = make_float2(p, __uint_as_float(uc[c]));
      }
    }
    ls = wave_sum(ls);
    s = s * sc + ls;
    acc *= sc;
    m = nm;
    for (int j = 0; j < nv; j += 8) {
      float2 q0 = pbuf[wid][j + 0];
      float2 q1 = pbuf[wid][j + 1];
      float2 q2 = pbuf[wid][j + 2];
      float2 q3 = pbuf[wid][j + 3];
      float2 q4 = pbuf[wid][j + 4];
      float2 q5 = pbuf[wid][j + 5];
      float2 q6 = pbuf[wid][j + 6];
      float2 q7 = pbuf[wid][j + 7];
      float g0 = bf2f(feat[(size_t)__float_as_uint(q0.y) * 48 + lidx]);
      float g1 = bf2f(feat[(size_t)__float_as_uint(q1.y) * 48 + lidx]);
      float g2 = bf2f(feat[(size_t)__float_as_uint(q2.y) * 48 + lidx]);
      float g3 = bf2f(feat[(size_t)__float_as_uint(q3.y) * 48 + lidx]);
      float g4 = bf2f(feat[(size_t)__float_as_uint(q4.y) * 48 + lidx]);
      float g5 = bf2f(feat[(size_t)__float_as_uint(q5.y) * 48 + lidx]);
      float g6 = bf2f(feat[(size_t)__float_as_uint(q6.y) * 48 + lidx]);
      float g7 = bf2f(feat[(size_t)__float_as_uint(q7.y) * 48 + lidx]);
      acc = fmaf(q0.x, g0, acc);
      acc = fmaf(q1.x, g1, acc);
      acc = fmaf(q2.x, g2, acc);
      acc = fmaf(q3.x, g3, acc);
      acc = fmaf(q4.x, g4, acc);
      acc = fmaf(q5.x, g5, acc);
      acc = fmaf(q6.x, g6, acc);
      acc = fmaf(q7.x, g7, acc);
    }
  }
  if (lane < 47) {
    out[(size_t)n * 47 + lane] = acc / fmaxf(s, 1e-9f) + b[lane];
  }
}

// ---------------------------------------------------------------------------
extern "C" void kernel_launch(void* const* d_in, const int* in_sizes, int n_in,
                              void* d_out, int out_size, void* d_ws, size_t ws_size,
                              hipStream_t stream) {
  const float* x = (const float*)d_in[0];
  const int* src = (const int*)d_in[1];
  const int* dst = (const int*)d_in[2];
  const float* sage_w_self = (const float*)d_in[3];
  const float* sage_w_neigh = (const float*)d_in[4];
  const float* sage_b = (const float*)d_in[5];
  const float* gat1_w = (const float*)d_in[6];
  const float* gat1_al = (const float*)d_in[7];
  const float* gat1_ar = (const float*)d_in[8];
  const float* gat1_b = (const float*)d_in[9];
  const float* gat2_w = (const float*)d_in[10];
  const float* gat2_al = (const float*)d_in[11];
  const float* gat2_ar = (const float*)d_in[12];
  const float* gat2_b = (const float*)d_in[13];
  float* out = (float*)d_out;

  const int N = in_sizes[0] / 256;
  const int E = in_sizes[1];

  char* ws = (char*)d_ws;
  size_t off = 0;
  auto alloc = [&](size_t bytes) {
    size_t o = off;
    off += (bytes + 255) & ~(size_t)255;
    return o;
  };
  int* deg_i = (int*)(ws + alloc((size_t)N * 4));
  int* row_start = (int*)(ws + alloc((size_t)(N + 1) * 4));
  int* cursor = (int*)(ws + alloc((size_t)N * 4));
  unsigned short* csr_src = (unsigned short*)(ws + alloc((size_t)E * 2));
  int* psum = (int*)(ws + alloc(((size_t)N / 1024 + 2) * 4));
  float* bufA = (float*)(ws + alloc((size_t)N * 128 * 4));       // z
  unsigned* bufG = (unsigned*)(ws + alloc((size_t)N * 64 * 4));  // yI -> feat1I -> feat2b
  unsigned short* bufX = (unsigned short*)(ws + alloc((size_t)N * 256 * 2));  // h0 | h1
  unsigned short* wt_sh = (unsigned short*)(ws + alloc(128 * 256 * 2));
  unsigned short* wt_sl = (unsigned short*)(ws + alloc(128 * 256 * 2));
  unsigned short* wt_nh = (unsigned short*)(ws + alloc(128 * 256 * 2));
  unsigned short* wt_nl = (unsigned short*)(ws + alloc(128 * 256 * 2));
  unsigned short* wt_1h = (unsigned short*)(ws + alloc(128 * 128 * 2));
  unsigned short* wt_1l = (unsigned short*)(ws + alloc(128 * 128 * 2));
  unsigned short* wt_2h = (unsigned short*)(ws + alloc(48 * 128 * 2));
  unsigned short* wt_2l = (unsigned short*)(ws + alloc(48 * 128 * 2));
  float2* el1 = (float2*)(ws + alloc((size_t)N * 8));
  float2* er1 = (float2*)(ws + alloc((size_t)N * 8));
  float* el2 = (float*)(ws + alloc((size_t)N * 4));
  float* er2 = (float*)(ws + alloc((size_t)N * 4));
  (void)ws_size;
  (void)n_in;
  (void)out_size;

  // lifetimes:
  float* z = bufA;                                  // dead after sage_agg
  unsigned* yI = bufG;                              // dead after sage_agg
  unsigned short* h0h = bufX;                       // dead after L1 gemm
  unsigned short* h0l = bufX + (size_t)N * 128;
  unsigned* feat1I = bufG;                          // reuse yI; dead after gat1_agg
  unsigned short* h1h = bufX;                       // reuse h0 region (dead)
  unsigned short* h1l = bufX + (size_t)N * 128;
  unsigned short* feat2b = (unsigned short*)bufG;   // reuse feat1I

  hipMemsetAsync(deg_i, 0, (size_t)N * 4, stream);

  const int eb = (E + 255) / 256;
  const int eb2 = (E + 511) / 512;
  const int nb4 = (N + 3) / 4;
  const int gx = (N + 127) / 128;
  const int PB = (N + 1023) / 1024;

  prep_w<<<(128 * 256 + 255) / 256, 256, 0, stream>>>(sage_w_self, 128, 256, 128, wt_sh, wt_sl);
  prep_w<<<(128 * 256 + 255) / 256, 256, 0, stream>>>(sage_w_neigh, 128, 256, 128, wt_nh, wt_nl);
  prep_w<<<(128 * 128 + 255) / 256, 256, 0, stream>>>(gat1_w, 128, 128, 128, wt_1h, wt_1l);
  prep_w<<<(48 * 128 + 255) / 256, 256, 0, stream>>>(gat2_w, 47, 128, 48, wt_2h, wt_2l);

  deg_kernel<<<eb, 256, 0, stream>>>(dst, deg_i, E);
  scan_partial<<<PB, 256, 0, stream>>>(deg_i, psum, N);
  scan_psum<<<1, 64, 0, stream>>>(psum, PB);
  scan_final<<<PB, 256, 0, stream>>>(deg_i, psum, row_start, cursor, N, E);
  scatter_kernel<<<eb2, 256, 0, stream>>>(src, dst, cursor, csr_src, E);

  // layer 0 (AF32: reads x f32 directly, in-register hi/lo split):
  //   y=0 -> z = x@W_self (f32, ldc=128 floats)
  //   y=1 -> yI = x@W_neigh (packed bf16 ilv, ldu=64 uints)
  {
    dim3 grid(gx, 2);
    gemm_mfma<256, 8, 1><<<grid, 256, 0, stream>>>(
        x, nullptr, wt_sh, wt_sl, wt_nh, wt_nl, z, yI, 128, N, 128, 0, 1,
        nullptr, nullptr, nullptr, nullptr, 0);
  }
  sage_agg<<<nb4, 256, 0, stream>>>(z, yI, row_start, csr_src, sage_b, h0h, h0l, N);

  // GAT layer 1: feat1I = h0 @ gat1_w (packed bf16 ilv) + fused elr1
  {
    dim3 grid(gx, 1);
    gemm_mfma<128, 8, 0><<<grid, 256, 0, stream>>>(
        h0h, h0l, wt_1h, wt_1l, wt_1h, wt_1l, feat1I, feat1I, 128, N, 128, 1, 1,
        gat1_al, gat1_ar, el1, er1, 1);
  }
  gat1_agg<<<nb4, 256, 0, stream>>>(feat1I, el1, er1, row_start, csr_src, gat1_b,
                                    h1h, h1l, N);

  // GAT layer 2: feat2b = h1 @ gat2_w (bf16 std, ldc=48) + fused elr2
  {
    dim3 grid(gx, 1);
    gemm_mfma<128, 3, 0><<<grid, 256, 0, stream>>>(
        h1h, h1l, wt_2h, wt_2l, wt_2h, wt_2l, feat2b, feat2b, 48, N, 47, 2, 2,
        gat2_al, gat2_ar, el2, er2, 2);
  }
  gat2_agg<<<nb4, 256, 0, stream>>>(feat2b, el2, er2, row_start, csr_src, gat2_b, out, N);
}